// Round 1
// baseline (5486.935 us; speedup 1.0000x reference)
//
#include <hip/hip_runtime.h>
#include <math.h>

#define N_NODES 20000
#define N_EDGES 320000
#define N_GRAPHS 32
#define CDIM 256
#define IN_DIMV 739
#define ED_DIM 518
#define NLAYERS 4
#define LN_EPS 1e-5f

__device__ __forceinline__ float gelu_exact(float x) {
    return 0.5f * x * (1.f + erff(x * 0.7071067811865475f));
}

__global__ void zero_kernel(float* __restrict__ p, int n) {
    int i = blockIdx.x * blockDim.x + threadIdx.x;
    int stride = gridDim.x * blockDim.x;
    for (; i < n; i += stride) p[i] = 0.f;
}

// Precompute per-layer: cw[i][c] = ln1_g[i] * w1_w[i][c]  (combined LN-scale+matmul weight)
// Sg[c] = sum_i g_i*w1[i][c], Sb[c] = sum_i b_i*w1[i][c]  (affine-LN folding constants)
__global__ void precompute_kernel(const float* __restrict__ ln1_g, const float* __restrict__ ln1_b,
                                  const float* __restrict__ w1_w,
                                  float* __restrict__ cw, float* __restrict__ SgSb) {
    int l = blockIdx.x, tid = threadIdx.x;
    float sg[4] = {0, 0, 0, 0}, sb[4] = {0, 0, 0, 0};
    for (int i = tid; i < ED_DIM; i += 256) {
        float g = ln1_g[l * ED_DIM + i];
        float b = ln1_b[l * ED_DIM + i];
        float4 w = *(const float4*)&w1_w[(size_t)(l * ED_DIM + i) * 4];
        float4 c = make_float4(g * w.x, g * w.y, g * w.z, g * w.w);
        *(float4*)&cw[(size_t)(l * ED_DIM + i) * 4] = c;
        sg[0] += c.x; sg[1] += c.y; sg[2] += c.z; sg[3] += c.w;
        sb[0] += b * w.x; sb[1] += b * w.y; sb[2] += b * w.z; sb[3] += b * w.w;
    }
    __shared__ float red[256][8];
    for (int c = 0; c < 4; c++) { red[tid][c] = sg[c]; red[tid][4 + c] = sb[c]; }
    __syncthreads();
    for (int s = 128; s > 0; s >>= 1) {
        if (tid < s)
            for (int c = 0; c < 8; c++) red[tid][c] += red[tid + s][c];
        __syncthreads();
    }
    if (tid < 8) SgSb[l * 8 + tid] = red[0][tid];
}

// C[M,256] = act(A[M,K] @ B[K,256] + bias). BM=128 BN=64 BK=16, 256 thr, 8x4 microtile.
template <bool GELU>
__global__ __launch_bounds__(256)
void gemm_bias_act(const float* __restrict__ A, const float* __restrict__ B,
                   const float* __restrict__ bias, float* __restrict__ C,
                   int M, int K) {
    const int N = 256;
    __shared__ __align__(16) float As[16][132];  // [k][row], +4 pad breaks store-side conflicts
    __shared__ __align__(16) float Bs[16][64];
    int row0 = blockIdx.x * 128, col0 = blockIdx.y * 64;
    int tid = threadIdx.x;
    int tc = tid & 15, tr = tid >> 4;
    float acc[8][4];
#pragma unroll
    for (int i = 0; i < 8; i++)
#pragma unroll
        for (int j = 0; j < 4; j++) acc[i][j] = 0.f;
    int kiters = (K + 15) >> 4;
    for (int kt = 0; kt < kiters; ++kt) {
        int k0 = kt << 4;
#pragma unroll
        for (int i = 0; i < 8; i++) {  // A tile: 128x16, coalesced along k
            int e = tid + i * 256;
            int r = e >> 4, kk = e & 15;
            int gr = row0 + r, gk = k0 + kk;
            float v = 0.f;
            if (gr < M && gk < K) v = A[(size_t)gr * K + gk];
            As[kk][r] = v;
        }
#pragma unroll
        for (int i = 0; i < 4; i++) {  // B tile: 16x64, coalesced along col
            int e = tid + i * 256;
            int kk = e >> 6, c = e & 63;
            int gk = k0 + kk;
            float v = 0.f;
            if (gk < K) v = B[(size_t)gk * N + col0 + c];
            Bs[kk][c] = v;
        }
        __syncthreads();
#pragma unroll
        for (int kk = 0; kk < 16; ++kk) {
            float4 a0 = *(const float4*)&As[kk][tr * 8];
            float4 a1 = *(const float4*)&As[kk][tr * 8 + 4];
            float4 b0 = *(const float4*)&Bs[kk][tc * 4];
            float av[8] = {a0.x, a0.y, a0.z, a0.w, a1.x, a1.y, a1.z, a1.w};
            float bv[4] = {b0.x, b0.y, b0.z, b0.w};
#pragma unroll
            for (int i = 0; i < 8; i++)
#pragma unroll
                for (int j = 0; j < 4; j++) acc[i][j] = fmaf(av[i], bv[j], acc[i][j]);
        }
        __syncthreads();
    }
    float4 b4 = *(const float4*)&bias[col0 + tc * 4];
    float bv[4] = {b4.x, b4.y, b4.z, b4.w};
#pragma unroll
    for (int i = 0; i < 8; i++) {
        int gr = row0 + tr * 8 + i;
        if (gr >= M) continue;
        float o[4];
#pragma unroll
        for (int j = 0; j < 4; j++) {
            float v = acc[i][j] + bv[j];
            o[j] = GELU ? gelu_exact(v) : v;
        }
        *(float4*)&C[(size_t)gr * N + col0 + tc * 4] = make_float4(o[0], o[1], o[2], o[3]);
    }
}

// One wave per edge. Computes the whole edge MLP without materializing e[518],
// then scatters w_e * m[src] into agg[dst] via atomics.
__global__ __launch_bounds__(256)
void edge_kernel(const float* __restrict__ m, const float* __restrict__ x_pos,
                 const int* __restrict__ ei,
                 const float* __restrict__ cw,    // [518][4] this layer (g*w1)
                 const float* __restrict__ SgSb,  // [8] this layer
                 const float* __restrict__ w1_b, const float* __restrict__ ln2_g,
                 const float* __restrict__ ln2_b, const float* __restrict__ w2_w,
                 const float* __restrict__ w2_b, float* __restrict__ agg) {
    __shared__ __align__(16) float4 s_cw[ED_DIM];
    int tid = threadIdx.x;
    for (int i = tid; i < ED_DIM; i += 256) s_cw[i] = *(const float4*)&cw[(size_t)i * 4];
    __syncthreads();
    int e = blockIdx.x * 4 + (tid >> 6);
    if (e >= N_EDGES) return;
    int lane = tid & 63;
    int s = ei[e], d = ei[N_EDGES + e];
    float4 a4 = *(const float4*)&m[(size_t)s * CDIM + lane * 4];
    float4 b4 = *(const float4*)&m[(size_t)d * CDIM + lane * 4];
    float av[4] = {a4.x, a4.y, a4.z, a4.w};
    float bv[4] = {b4.x, b4.y, b4.z, b4.w};
    float S1 = 0.f, S2 = 0.f;
    float D[4] = {0, 0, 0, 0};
#pragma unroll
    for (int j = 0; j < 4; j++) {
        S1 += av[j] + bv[j];
        S2 += av[j] * av[j] + bv[j] * bv[j];
        float4 c0 = s_cw[lane * 4 + j];
        float4 c1 = s_cw[256 + lane * 4 + j];
        D[0] += av[j] * c0.x + bv[j] * c1.x;
        D[1] += av[j] * c0.y + bv[j] * c1.y;
        D[2] += av[j] * c0.z + bv[j] * c1.z;
        D[3] += av[j] * c0.w + bv[j] * c1.w;
    }
    if (lane < 6) {  // positions occupy e[512..517]: [pos_src(3), pos_dst(3)]
        float p = (lane < 3) ? x_pos[(size_t)s * 3 + lane] : x_pos[(size_t)d * 3 + lane - 3];
        S1 += p; S2 += p * p;
        float4 c = s_cw[512 + lane];
        D[0] += p * c.x; D[1] += p * c.y; D[2] += p * c.z; D[3] += p * c.w;
    }
#pragma unroll
    for (int off = 1; off < 64; off <<= 1) {
        S1 += __shfl_xor(S1, off, 64);
        S2 += __shfl_xor(S2, off, 64);
        D[0] += __shfl_xor(D[0], off, 64);
        D[1] += __shfl_xor(D[1], off, 64);
        D[2] += __shfl_xor(D[2], off, 64);
        D[3] += __shfl_xor(D[3], off, 64);
    }
    const float inv = 1.f / 518.f;
    float mu = S1 * inv;
    float var = fmaf(-mu, mu, S2 * inv);
    float rstd = rsqrtf(var + LN_EPS);
    float t[4];
#pragma unroll
    for (int c = 0; c < 4; c++)
        t[c] = gelu_exact(rstd * (D[c] - mu * SgSb[c]) + SgSb[4 + c] + w1_b[c]);
    float mu2 = 0.25f * (t[0] + t[1] + t[2] + t[3]);
    float var2 = 0.25f * ((t[0] - mu2) * (t[0] - mu2) + (t[1] - mu2) * (t[1] - mu2) +
                          (t[2] - mu2) * (t[2] - mu2) + (t[3] - mu2) * (t[3] - mu2));
    float r2 = rsqrtf(var2 + LN_EPS);
    float z = w2_b[0];
#pragma unroll
    for (int c = 0; c < 4; c++)
        z += ((t[c] - mu2) * r2 * ln2_g[c] + ln2_b[c]) * w2_w[c];
    float we = 1.f / (1.f + expf(-z));
    float* ap = &agg[(size_t)d * CDIM + lane * 4];
    atomicAdd(ap + 0, av[0] * we);
    atomicAdd(ap + 1, av[1] * we);
    atomicAdd(ap + 2, av[2] * we);
    atomicAdd(ap + 3, av[3] * we);
}

__global__ __launch_bounds__(256)
void pool_kernel(const float* __restrict__ h, const int* __restrict__ batch,
                 float* __restrict__ sums, int* __restrict__ cnt) {
    int node = (blockIdx.x * 256 + threadIdx.x) >> 6;
    int lane = threadIdx.x & 63;
    if (node >= N_NODES) return;
    int g = batch[node];
    float4 v = *(const float4*)&h[(size_t)node * CDIM + lane * 4];
    float* sp = &sums[(size_t)g * CDIM + lane * 4];
    atomicAdd(sp + 0, v.x);
    atomicAdd(sp + 1, v.y);
    atomicAdd(sp + 2, v.z);
    atomicAdd(sp + 3, v.w);
    if (lane == 0) atomicAdd(&cnt[g], 1);
}

__global__ void head_kernel(const float* __restrict__ sums, const int* __restrict__ cnt,
                            const float* __restrict__ head_w, const float* __restrict__ head_b,
                            float* __restrict__ out) {
    int g = blockIdx.x;
    int lane = threadIdx.x;  // 64 threads
    float4 s = *(const float4*)&sums[(size_t)g * CDIM + lane * 4];
    float4 w = *(const float4*)&head_w[lane * 4];
    float p = s.x * w.x + s.y * w.y + s.z * w.z + s.w * w.w;
#pragma unroll
    for (int off = 1; off < 64; off <<= 1) p += __shfl_xor(p, off, 64);
    if (lane == 0) {
        float c = fmaxf((float)cnt[g], 1.f);
        out[g] = p / c + head_b[0];
    }
}

extern "C" void kernel_launch(void* const* d_in, const int* in_sizes, int n_in,
                              void* d_out, int out_size, void* d_ws, size_t ws_size,
                              hipStream_t stream) {
    const float* x       = (const float*)d_in[0];
    const float* x_pos   = (const float*)d_in[1];
    const int*   ei      = (const int*)d_in[2];
    const int*   batch   = (const int*)d_in[3];
    const float* dense_w = (const float*)d_in[4];
    const float* dense_b = (const float*)d_in[5];
    const float* d1_w    = (const float*)d_in[6];
    const float* d1_b    = (const float*)d_in[7];
    const float* ln1_g   = (const float*)d_in[8];
    const float* ln1_b   = (const float*)d_in[9];
    const float* w1_w    = (const float*)d_in[10];
    const float* w1_b    = (const float*)d_in[11];
    const float* ln2_g   = (const float*)d_in[12];
    const float* ln2_b   = (const float*)d_in[13];
    const float* w2_w    = (const float*)d_in[14];
    const float* w2_b    = (const float*)d_in[15];
    const float* d2_w    = (const float*)d_in[16];
    const float* d2_b    = (const float*)d_in[17];
    const float* head_w  = (const float*)d_in[18];
    const float* head_b  = (const float*)d_in[19];
    float* out = (float*)d_out;

    float* buf0 = (float*)d_ws;
    float* buf1 = buf0 + (size_t)N_NODES * CDIM;
    float* cw   = buf1 + (size_t)N_NODES * CDIM;   // [L][518][4]
    float* SgSb = cw + (size_t)NLAYERS * ED_DIM * 4;  // [L][8]
    float* psums = SgSb + NLAYERS * 8;             // [32][256]
    int*   pcnt  = (int*)(psums + N_GRAPHS * CDIM);  // [32]

    precompute_kernel<<<NLAYERS, 256, 0, stream>>>(ln1_g, ln1_b, w1_w, cw, SgSb);

    dim3 ggrid((N_NODES + 127) / 128, 4);
    gemm_bias_act<false><<<ggrid, 256, 0, stream>>>(x, dense_w, dense_b, buf0, N_NODES, IN_DIMV);

    float* h = buf0;
    float* other = buf1;
    for (int l = 0; l < NLAYERS; l++) {
        // m = gelu(h @ d1_w + d1_b) -> other
        gemm_bias_act<true><<<ggrid, 256, 0, stream>>>(h, d1_w + (size_t)l * CDIM * CDIM,
                                                       d1_b + l * CDIM, other, N_NODES, CDIM);
        // h buffer becomes agg: zero it
        zero_kernel<<<2048, 256, 0, stream>>>(h, N_NODES * CDIM);
        edge_kernel<<<N_EDGES / 4, 256, 0, stream>>>(other, x_pos, ei,
            cw + (size_t)l * ED_DIM * 4, SgSb + l * 8, w1_b + l * 4,
            ln2_g + l * 4, ln2_b + l * 4, w2_w + l * 4, w2_b + l, h);
        // h_new = gelu(agg @ d2_w + d2_b) -> other (m is dead)
        gemm_bias_act<true><<<ggrid, 256, 0, stream>>>(h, d2_w + (size_t)l * CDIM * CDIM,
                                                       d2_b + l * CDIM, other, N_NODES, CDIM);
        float* tmp = h; h = other; other = tmp;
    }

    zero_kernel<<<33, 256, 0, stream>>>(psums, N_GRAPHS * CDIM + N_GRAPHS);
    pool_kernel<<<(N_NODES * 64 + 255) / 256, 256, 0, stream>>>(h, batch, psums, pcnt);
    head_kernel<<<N_GRAPHS, 64, 0, stream>>>(psums, pcnt, head_w, head_b, out);
}

// Round 3
// 1540.070 us; speedup vs baseline: 3.5628x; 3.5628x over previous
//
#include <hip/hip_runtime.h>
#include <math.h>

#define N_NODES 20000
#define N_EDGES 320000
#define N_GRAPHS 32
#define CDIM 256
#define IN_DIMV 739
#define ED_DIM 518
#define NLAYERS 4
#define LN_EPS 1e-5f

__device__ __forceinline__ float gelu_exact(float x) {
    return 0.5f * x * (1.f + erff(x * 0.7071067811865475f));
}

__global__ void zero_kernel(float* __restrict__ p, int n) {
    int i = blockIdx.x * blockDim.x + threadIdx.x;
    int stride = gridDim.x * blockDim.x;
    for (; i < n; i += stride) p[i] = 0.f;
}

// Precompute per-layer: cw[i][c] = ln1_g[i] * w1_w[i][c]  (combined LN-scale+matmul weight)
// Sg[c] = sum_i g_i*w1[i][c], Sb[c] = sum_i b_i*w1[i][c]  (affine-LN folding constants)
__global__ void precompute_kernel(const float* __restrict__ ln1_g, const float* __restrict__ ln1_b,
                                  const float* __restrict__ w1_w,
                                  float* __restrict__ cw, float* __restrict__ SgSb) {
    int l = blockIdx.x, tid = threadIdx.x;
    float sg[4] = {0, 0, 0, 0}, sb[4] = {0, 0, 0, 0};
    for (int i = tid; i < ED_DIM; i += 256) {
        float g = ln1_g[l * ED_DIM + i];
        float b = ln1_b[l * ED_DIM + i];
        float4 w = *(const float4*)&w1_w[(size_t)(l * ED_DIM + i) * 4];
        float4 c = make_float4(g * w.x, g * w.y, g * w.z, g * w.w);
        *(float4*)&cw[(size_t)(l * ED_DIM + i) * 4] = c;
        sg[0] += c.x; sg[1] += c.y; sg[2] += c.z; sg[3] += c.w;
        sb[0] += b * w.x; sb[1] += b * w.y; sb[2] += b * w.z; sb[3] += b * w.w;
    }
    __shared__ float red[256][8];
    for (int c = 0; c < 4; c++) { red[tid][c] = sg[c]; red[tid][4 + c] = sb[c]; }
    __syncthreads();
    for (int s = 128; s > 0; s >>= 1) {
        if (tid < s)
            for (int c = 0; c < 8; c++) red[tid][c] += red[tid + s][c];
        __syncthreads();
    }
    if (tid < 8) SgSb[l * 8 + tid] = red[0][tid];
}

// ---- CSR build (edges are identical across layers; built once per launch) ----
__global__ void hist_kernel(const int* __restrict__ ei, int* __restrict__ deg) {
    int e = blockIdx.x * 256 + threadIdx.x;
    if (e < N_EDGES) atomicAdd(&deg[ei[N_EDGES + e]], 1);
}

__global__ __launch_bounds__(512)
void scan_kernel(const int* __restrict__ deg, int* __restrict__ row_start,
                 int* __restrict__ cursor) {
    __shared__ int sdata[512];
    int t = threadIdx.x;
    const int CHUNK = (N_NODES + 511) / 512;  // 40
    int base = t * CHUNK;
    int s = 0;
    for (int i = 0; i < CHUNK; i++) {
        int idx = base + i;
        if (idx < N_NODES) s += deg[idx];
    }
    sdata[t] = s;
    __syncthreads();
    for (int off = 1; off < 512; off <<= 1) {
        int other = (t >= off) ? sdata[t - off] : 0;
        __syncthreads();
        sdata[t] += other;
        __syncthreads();
    }
    int excl = sdata[t] - s;
    int run = excl;
    for (int i = 0; i < CHUNK; i++) {
        int idx = base + i;
        if (idx < N_NODES) {
            row_start[idx] = run;
            cursor[idx] = run;
            run += deg[idx];
        }
    }
    if (t == 511) row_start[N_NODES] = run;
}

__global__ void scatter_kernel(const int* __restrict__ ei, int* __restrict__ cursor,
                               int* __restrict__ csr_src, int* __restrict__ slot) {
    int e = blockIdx.x * 256 + threadIdx.x;
    if (e < N_EDGES) {
        int d = ei[N_EDGES + e];
        int pos = atomicAdd(&cursor[d], 1);
        csr_src[pos] = ei[e];
        slot[e] = pos;
    }
}

// C[M,256] = act(A[M,K] @ B[K,256] + bias). BM=128 BN=64 BK=16, 256 thr, 8x4 microtile.
template <bool GELU>
__global__ __launch_bounds__(256)
void gemm_bias_act(const float* __restrict__ A, const float* __restrict__ B,
                   const float* __restrict__ bias, float* __restrict__ C,
                   int M, int K) {
    const int N = 256;
    __shared__ __align__(16) float As[16][132];
    __shared__ __align__(16) float Bs[16][64];
    int row0 = blockIdx.x * 128, col0 = blockIdx.y * 64;
    int tid = threadIdx.x;
    int tc = tid & 15, tr = tid >> 4;
    float acc[8][4];
#pragma unroll
    for (int i = 0; i < 8; i++)
#pragma unroll
        for (int j = 0; j < 4; j++) acc[i][j] = 0.f;
    int kiters = (K + 15) >> 4;
    for (int kt = 0; kt < kiters; ++kt) {
        int k0 = kt << 4;
#pragma unroll
        for (int i = 0; i < 8; i++) {
            int e = tid + i * 256;
            int r = e >> 4, kk = e & 15;
            int gr = row0 + r, gk = k0 + kk;
            float v = 0.f;
            if (gr < M && gk < K) v = A[(size_t)gr * K + gk];
            As[kk][r] = v;
        }
#pragma unroll
        for (int i = 0; i < 4; i++) {
            int e = tid + i * 256;
            int kk = e >> 6, c = e & 63;
            int gk = k0 + kk;
            float v = 0.f;
            if (gk < K) v = B[(size_t)gk * N + col0 + c];
            Bs[kk][c] = v;
        }
        __syncthreads();
#pragma unroll
        for (int kk = 0; kk < 16; ++kk) {
            float4 a0 = *(const float4*)&As[kk][tr * 8];
            float4 a1 = *(const float4*)&As[kk][tr * 8 + 4];
            float4 b0 = *(const float4*)&Bs[kk][tc * 4];
            float av[8] = {a0.x, a0.y, a0.z, a0.w, a1.x, a1.y, a1.z, a1.w};
            float bv[4] = {b0.x, b0.y, b0.z, b0.w};
#pragma unroll
            for (int i = 0; i < 8; i++)
#pragma unroll
                for (int j = 0; j < 4; j++) acc[i][j] = fmaf(av[i], bv[j], acc[i][j]);
        }
        __syncthreads();
    }
    float4 b4 = *(const float4*)&bias[col0 + tc * 4];
    float bv[4] = {b4.x, b4.y, b4.z, b4.w};
#pragma unroll
    for (int i = 0; i < 8; i++) {
        int gr = row0 + tr * 8 + i;
        if (gr >= M) continue;
        float o[4];
#pragma unroll
        for (int j = 0; j < 4; j++) {
            float v = acc[i][j] + bv[j];
            o[j] = GELU ? gelu_exact(v) : v;
        }
        *(float4*)&C[(size_t)gr * N + col0 + tc * 4] = make_float4(o[0], o[1], o[2], o[3]);
    }
}

// Per-node summaries: P1[c]=sum_i m[n][i]*cw[i][c], P2[c]=sum_i m[n][i]*cw[256+i][c],
// Q1=sum m, Q2=sum m^2.  ns row = 12 floats: [P1(4), P2(4), Q1, Q2, pad, pad]
__global__ __launch_bounds__(256)
void node_summary_kernel(const float* __restrict__ m, const float* __restrict__ cw,
                         float* __restrict__ ns) {
    __shared__ __align__(16) float4 s_cw[512];
    int tid = threadIdx.x;
    for (int i = tid; i < 512; i += 256) s_cw[i] = *(const float4*)&cw[(size_t)i * 4];
    __syncthreads();
    int n = blockIdx.x * 4 + (tid >> 6);
    if (n >= N_NODES) return;
    int lane = tid & 63;
    float4 a4 = *(const float4*)&m[(size_t)n * CDIM + lane * 4];
    float av[4] = {a4.x, a4.y, a4.z, a4.w};
    float Q1 = 0.f, Q2 = 0.f, P1[4] = {0, 0, 0, 0}, P2[4] = {0, 0, 0, 0};
#pragma unroll
    for (int j = 0; j < 4; j++) {
        Q1 += av[j];
        Q2 += av[j] * av[j];
        float4 c0 = s_cw[lane * 4 + j];
        float4 c1 = s_cw[256 + lane * 4 + j];
        P1[0] += av[j] * c0.x; P1[1] += av[j] * c0.y; P1[2] += av[j] * c0.z; P1[3] += av[j] * c0.w;
        P2[0] += av[j] * c1.x; P2[1] += av[j] * c1.y; P2[2] += av[j] * c1.z; P2[3] += av[j] * c1.w;
    }
#pragma unroll
    for (int off = 1; off < 64; off <<= 1) {
        Q1 += __shfl_xor(Q1, off, 64);
        Q2 += __shfl_xor(Q2, off, 64);
        P1[0] += __shfl_xor(P1[0], off, 64);
        P1[1] += __shfl_xor(P1[1], off, 64);
        P1[2] += __shfl_xor(P1[2], off, 64);
        P1[3] += __shfl_xor(P1[3], off, 64);
        P2[0] += __shfl_xor(P2[0], off, 64);
        P2[1] += __shfl_xor(P2[1], off, 64);
        P2[2] += __shfl_xor(P2[2], off, 64);
        P2[3] += __shfl_xor(P2[3], off, 64);
    }
    if (lane == 0) {
        float* p = &ns[(size_t)n * 12];
        *(float4*)p = make_float4(P1[0], P1[1], P1[2], P1[3]);
        *(float4*)(p + 4) = make_float4(P2[0], P2[1], P2[2], P2[3]);
        p[8] = Q1;
        p[9] = Q2;
    }
}

// One thread per edge: full edge MLP from node summaries; writes w into CSR slot.
__global__ __launch_bounds__(256)
void edge_weight_kernel(const float* __restrict__ ns, const float* __restrict__ x_pos,
                        const int* __restrict__ ei, const float* __restrict__ cw,
                        const float* __restrict__ SgSb, const float* __restrict__ w1_b,
                        const float* __restrict__ ln2_g, const float* __restrict__ ln2_b,
                        const float* __restrict__ w2_w, const float* __restrict__ w2_b,
                        const int* __restrict__ slot, float* __restrict__ w_csr) {
    int e = blockIdx.x * 256 + threadIdx.x;
    if (e >= N_EDGES) return;
    int s = ei[e], d = ei[N_EDGES + e];
    const float* nss = &ns[(size_t)s * 12];
    const float* nsd = &ns[(size_t)d * 12];
    float4 p1 = *(const float4*)nss;
    float4 p2 = *(const float4*)(nsd + 4);
    float S1 = nss[8] + nsd[8];
    float S2 = nss[9] + nsd[9];
    float D[4] = {p1.x + p2.x, p1.y + p2.y, p1.z + p2.z, p1.w + p2.w};
    float ps[6];
    ps[0] = x_pos[(size_t)s * 3 + 0];
    ps[1] = x_pos[(size_t)s * 3 + 1];
    ps[2] = x_pos[(size_t)s * 3 + 2];
    ps[3] = x_pos[(size_t)d * 3 + 0];
    ps[4] = x_pos[(size_t)d * 3 + 1];
    ps[5] = x_pos[(size_t)d * 3 + 2];
#pragma unroll
    for (int k = 0; k < 6; k++) {
        S1 += ps[k];
        S2 += ps[k] * ps[k];
        float4 c = *(const float4*)&cw[(size_t)(512 + k) * 4];
        D[0] += ps[k] * c.x; D[1] += ps[k] * c.y; D[2] += ps[k] * c.z; D[3] += ps[k] * c.w;
    }
    const float inv = 1.f / 518.f;
    float mu = S1 * inv;
    float var = fmaf(-mu, mu, S2 * inv);
    float rstd = rsqrtf(var + LN_EPS);
    float t[4];
#pragma unroll
    for (int c = 0; c < 4; c++)
        t[c] = gelu_exact(rstd * (D[c] - mu * SgSb[c]) + SgSb[4 + c] + w1_b[c]);
    float mu2 = 0.25f * (t[0] + t[1] + t[2] + t[3]);
    float var2 = 0.25f * ((t[0] - mu2) * (t[0] - mu2) + (t[1] - mu2) * (t[1] - mu2) +
                          (t[2] - mu2) * (t[2] - mu2) + (t[3] - mu2) * (t[3] - mu2));
    float r2 = rsqrtf(var2 + LN_EPS);
    float z = w2_b[0];
#pragma unroll
    for (int c = 0; c < 4; c++)
        z += ((t[c] - mu2) * r2 * ln2_g[c] + ln2_b[c]) * w2_w[c];
    w_csr[slot[e]] = 1.f / (1.f + expf(-z));
}

// CSR SpMM: agg[n] = sum_{j in row n} w_csr[j] * m[csr_src[j]]. No atomics.
__global__ __launch_bounds__(256)
void agg_kernel(const float* __restrict__ m, const int* __restrict__ csr_src,
                const float* __restrict__ w_csr, const int* __restrict__ row_start,
                float* __restrict__ agg) {
    int n = blockIdx.x * 4 + (threadIdx.x >> 6);
    if (n >= N_NODES) return;
    int lane = threadIdx.x & 63;
    int beg = row_start[n], end = row_start[n + 1];
    float4 acc = make_float4(0.f, 0.f, 0.f, 0.f);
    for (int j = beg; j < end; j++) {
        int s = csr_src[j];
        float w = w_csr[j];
        float4 v = *(const float4*)&m[(size_t)s * CDIM + lane * 4];
        acc.x = fmaf(w, v.x, acc.x);
        acc.y = fmaf(w, v.y, acc.y);
        acc.z = fmaf(w, v.z, acc.z);
        acc.w = fmaf(w, v.w, acc.w);
    }
    *(float4*)&agg[(size_t)n * CDIM + lane * 4] = acc;
}

__global__ __launch_bounds__(256)
void pool_kernel(const float* __restrict__ h, const int* __restrict__ batch,
                 float* __restrict__ sums, int* __restrict__ cnt) {
    int node = (blockIdx.x * 256 + threadIdx.x) >> 6;
    int lane = threadIdx.x & 63;
    if (node >= N_NODES) return;
    int g = batch[node];
    float4 v = *(const float4*)&h[(size_t)node * CDIM + lane * 4];
    float* sp = &sums[(size_t)g * CDIM + lane * 4];
    atomicAdd(sp + 0, v.x);
    atomicAdd(sp + 1, v.y);
    atomicAdd(sp + 2, v.z);
    atomicAdd(sp + 3, v.w);
    if (lane == 0) atomicAdd(&cnt[g], 1);
}

__global__ void head_kernel(const float* __restrict__ sums, const int* __restrict__ cnt,
                            const float* __restrict__ head_w, const float* __restrict__ head_b,
                            float* __restrict__ out) {
    int g = blockIdx.x;
    int lane = threadIdx.x;  // 64 threads
    float4 s = *(const float4*)&sums[(size_t)g * CDIM + lane * 4];
    float4 w = *(const float4*)&head_w[lane * 4];
    float p = s.x * w.x + s.y * w.y + s.z * w.z + s.w * w.w;
#pragma unroll
    for (int off = 1; off < 64; off <<= 1) p += __shfl_xor(p, off, 64);
    if (lane == 0) {
        float c = fmaxf((float)cnt[g], 1.f);
        out[g] = p / c + head_b[0];
    }
}

extern "C" void kernel_launch(void* const* d_in, const int* in_sizes, int n_in,
                              void* d_out, int out_size, void* d_ws, size_t ws_size,
                              hipStream_t stream) {
    const float* x       = (const float*)d_in[0];
    const float* x_pos   = (const float*)d_in[1];
    const int*   ei      = (const int*)d_in[2];
    const int*   batch   = (const int*)d_in[3];
    const float* dense_w = (const float*)d_in[4];
    const float* dense_b = (const float*)d_in[5];
    const float* d1_w    = (const float*)d_in[6];
    const float* d1_b    = (const float*)d_in[7];
    const float* ln1_g   = (const float*)d_in[8];
    const float* ln1_b   = (const float*)d_in[9];
    const float* w1_w    = (const float*)d_in[10];
    const float* w1_b    = (const float*)d_in[11];
    const float* ln2_g   = (const float*)d_in[12];
    const float* ln2_b   = (const float*)d_in[13];
    const float* w2_w    = (const float*)d_in[14];
    const float* w2_b    = (const float*)d_in[15];
    const float* d2_w    = (const float*)d_in[16];
    const float* d2_b    = (const float*)d_in[17];
    const float* head_w  = (const float*)d_in[18];
    const float* head_b  = (const float*)d_in[19];
    float* out = (float*)d_out;

    float* buf0  = (float*)d_ws;                               // [N, C]
    float* buf1  = buf0 + (size_t)N_NODES * CDIM;              // [N, C]
    float* cw    = buf1 + (size_t)N_NODES * CDIM;              // [L][518][4]
    float* SgSb  = cw + (size_t)NLAYERS * ED_DIM * 4;          // [L][8]
    float* ns    = SgSb + NLAYERS * 8;                         // [N][12]
    float* psums = ns + (size_t)N_NODES * 12;                  // [32][256]
    int* pcnt      = (int*)(psums + N_GRAPHS * CDIM);          // [32]  (adjacent: zeroed with psums!)
    float* w_csr = (float*)(pcnt + N_GRAPHS);                  // [E]
    int* deg       = (int*)(w_csr + N_EDGES);                  // [N]
    int* row_start = deg + N_NODES;                            // [N+1]
    int* cursor    = row_start + N_NODES + 1;                  // [N]
    int* csr_src   = cursor + N_NODES;                         // [E]
    int* slot      = csr_src + N_EDGES;                        // [E]

    precompute_kernel<<<NLAYERS, 256, 0, stream>>>(ln1_g, ln1_b, w1_w, cw, SgSb);

    // CSR build (once; edge_index is layer-invariant)
    zero_kernel<<<80, 256, 0, stream>>>((float*)deg, N_NODES);
    hist_kernel<<<(N_EDGES + 255) / 256, 256, 0, stream>>>(ei, deg);
    scan_kernel<<<1, 512, 0, stream>>>(deg, row_start, cursor);
    scatter_kernel<<<(N_EDGES + 255) / 256, 256, 0, stream>>>(ei, cursor, csr_src, slot);

    dim3 ggrid((N_NODES + 127) / 128, 4);
    gemm_bias_act<false><<<ggrid, 256, 0, stream>>>(x, dense_w, dense_b, buf0, N_NODES, IN_DIMV);

    float* h = buf0;
    float* other = buf1;
    for (int l = 0; l < NLAYERS; l++) {
        // m = gelu(h @ d1_w + d1_b) -> other
        gemm_bias_act<true><<<ggrid, 256, 0, stream>>>(h, d1_w + (size_t)l * CDIM * CDIM,
                                                       d1_b + l * CDIM, other, N_NODES, CDIM);
        node_summary_kernel<<<(N_NODES + 3) / 4, 256, 0, stream>>>(
            other, cw + (size_t)l * ED_DIM * 4, ns);
        edge_weight_kernel<<<(N_EDGES + 255) / 256, 256, 0, stream>>>(
            ns, x_pos, ei, cw + (size_t)l * ED_DIM * 4, SgSb + l * 8, w1_b + l * 4,
            ln2_g + l * 4, ln2_b + l * 4, w2_w + l * 4, w2_b + l, slot, w_csr);
        // agg (into h buffer; fully overwritten, no zeroing needed)
        agg_kernel<<<(N_NODES + 3) / 4, 256, 0, stream>>>(other, csr_src, w_csr, row_start, h);
        // h_new = gelu(agg @ d2_w + d2_b) -> other (m is dead)
        gemm_bias_act<true><<<ggrid, 256, 0, stream>>>(h, d2_w + (size_t)l * CDIM * CDIM,
                                                       d2_b + l * CDIM, other, N_NODES, CDIM);
        float* tmp = h; h = other; other = tmp;
    }

    zero_kernel<<<33, 256, 0, stream>>>(psums, N_GRAPHS * CDIM + N_GRAPHS);
    pool_kernel<<<(N_NODES * 64 + 255) / 256, 256, 0, stream>>>(h, batch, psums, pcnt);
    head_kernel<<<N_GRAPHS, 64, 0, stream>>>(psums, pcnt, head_w, head_b, out);
}

// Round 4
// 1297.833 us; speedup vs baseline: 4.2278x; 1.1866x over previous
//
#include <hip/hip_runtime.h>
#include <math.h>

#define N_NODES 20000
#define N_EDGES 320000
#define N_GRAPHS 32
#define CDIM 256
#define IN_DIMV 739
#define ED_DIM 518
#define NLAYERS 4
#define LN_EPS 1e-5f

__device__ __forceinline__ float gelu_exact(float x) {
    return 0.5f * x * (1.f + erff(x * 0.7071067811865475f));
}

__global__ void zero_kernel(float* __restrict__ p, int n) {
    int i = blockIdx.x * blockDim.x + threadIdx.x;
    int stride = gridDim.x * blockDim.x;
    for (; i < n; i += stride) p[i] = 0.f;
}

// Precompute per-layer: cw[i][c] = ln1_g[i] * w1_w[i][c]
// Sg[c] = sum_i g_i*w1[i][c], Sb[c] = sum_i b_i*w1[i][c]
__global__ void precompute_kernel(const float* __restrict__ ln1_g, const float* __restrict__ ln1_b,
                                  const float* __restrict__ w1_w,
                                  float* __restrict__ cw, float* __restrict__ SgSb) {
    int l = blockIdx.x, tid = threadIdx.x;
    float sg[4] = {0, 0, 0, 0}, sb[4] = {0, 0, 0, 0};
    for (int i = tid; i < ED_DIM; i += 256) {
        float g = ln1_g[l * ED_DIM + i];
        float b = ln1_b[l * ED_DIM + i];
        float4 w = *(const float4*)&w1_w[(size_t)(l * ED_DIM + i) * 4];
        float4 c = make_float4(g * w.x, g * w.y, g * w.z, g * w.w);
        *(float4*)&cw[(size_t)(l * ED_DIM + i) * 4] = c;
        sg[0] += c.x; sg[1] += c.y; sg[2] += c.z; sg[3] += c.w;
        sb[0] += b * w.x; sb[1] += b * w.y; sb[2] += b * w.z; sb[3] += b * w.w;
    }
    __shared__ float red[256][8];
    for (int c = 0; c < 4; c++) { red[tid][c] = sg[c]; red[tid][4 + c] = sb[c]; }
    __syncthreads();
    for (int s = 128; s > 0; s >>= 1) {
        if (tid < s)
            for (int c = 0; c < 8; c++) red[tid][c] += red[tid + s][c];
        __syncthreads();
    }
    if (tid < 8) SgSb[l * 8 + tid] = red[0][tid];
}

// ---- CSR build ----
__global__ void hist_kernel(const int* __restrict__ ei, int* __restrict__ deg) {
    int e = blockIdx.x * 256 + threadIdx.x;
    if (e < N_EDGES) atomicAdd(&deg[ei[N_EDGES + e]], 1);
}

__global__ __launch_bounds__(512)
void scan_kernel(const int* __restrict__ deg, int* __restrict__ row_start,
                 int* __restrict__ cursor) {
    __shared__ int sdata[512];
    int t = threadIdx.x;
    const int CHUNK = (N_NODES + 511) / 512;
    int base = t * CHUNK;
    int s = 0;
    for (int i = 0; i < CHUNK; i++) {
        int idx = base + i;
        if (idx < N_NODES) s += deg[idx];
    }
    sdata[t] = s;
    __syncthreads();
    for (int off = 1; off < 512; off <<= 1) {
        int other = (t >= off) ? sdata[t - off] : 0;
        __syncthreads();
        sdata[t] += other;
        __syncthreads();
    }
    int excl = sdata[t] - s;
    int run = excl;
    for (int i = 0; i < CHUNK; i++) {
        int idx = base + i;
        if (idx < N_NODES) {
            row_start[idx] = run;
            cursor[idx] = run;
            run += deg[idx];
        }
    }
    if (t == 511) row_start[N_NODES] = run;
}

__global__ void scatter_kernel(const int* __restrict__ ei, int* __restrict__ cursor,
                               int* __restrict__ csr_src, int* __restrict__ slot) {
    int e = blockIdx.x * 256 + threadIdx.x;
    if (e < N_EDGES) {
        int d = ei[N_EDGES + e];
        int pos = atomicAdd(&cursor[d], 1);
        csr_src[pos] = ei[e];
        slot[e] = pos;
    }
}

// C[M,256] = act(A[M,K] @ B[K,256] + bias).
// BM=32, BN=256 (full width: A read exactly once), BK=32, 256 threads.
// Register-prefetch of tile k+1 overlaps the 32-step FMA burst.
// AVEC: K%4==0 and A rows 16B-alignable -> float4 A loads.
template <bool GELU, bool AVEC>
__global__ __launch_bounds__(256)
void gemm_bias_act(const float* __restrict__ A, const float* __restrict__ B,
                   const float* __restrict__ bias, float* __restrict__ C,
                   int M, int K) {
    __shared__ __align__(16) float As[32][33];   // [k][row], +1 pad
    __shared__ __align__(16) float Bs[32][256];  // [k][col]
    int row0 = blockIdx.x * 32;
    int tid = threadIdx.x;
    int tr = tid >> 5;   // 0..7  -> rows tr*4..tr*4+3
    int tc = tid & 31;   // 0..31 -> cols tc*4..+3 and 128+tc*4..+3

    // prefetch registers
    int arow = tid >> 3;          // 0..31
    int ak4 = (tid & 7) * 4;      // 0,4,...,28
    float areg[4];
    float4 breg[8];

    int ntiles = (K + 31) >> 5;
    const float* Arow = &A[(size_t)(row0 + arow) * K];

    // load tile 0
    {
        int k0 = 0;
        if (AVEC) {
            if (ak4 < K) *(float4*)areg = *(const float4*)&Arow[k0 + ak4];
            else { areg[0] = areg[1] = areg[2] = areg[3] = 0.f; }
        } else {
#pragma unroll
            for (int j = 0; j < 4; j++) {
                int gk = k0 + ak4 + j;
                areg[j] = (gk < K) ? Arow[gk] : 0.f;
            }
        }
#pragma unroll
        for (int j = 0; j < 8; j++) {
            int idx = tid + j * 256;
            int krow = idx >> 6, c4 = idx & 63;
            int gk = k0 + krow;
            breg[j] = (gk < K) ? *(const float4*)&B[(size_t)gk * 256 + c4 * 4]
                               : make_float4(0.f, 0.f, 0.f, 0.f);
        }
    }

    float acc[4][8];
#pragma unroll
    for (int i = 0; i < 4; i++)
#pragma unroll
        for (int j = 0; j < 8; j++) acc[i][j] = 0.f;

    for (int kt = 0; kt < ntiles; ++kt) {
        // regs -> LDS
#pragma unroll
        for (int j = 0; j < 4; j++) As[ak4 + j][arow] = areg[j];
#pragma unroll
        for (int j = 0; j < 8; j++) {
            int idx = tid + j * 256;
            int krow = idx >> 6, c4 = idx & 63;
            *(float4*)&Bs[krow][c4 * 4] = breg[j];
        }
        __syncthreads();

        // prefetch next tile
        if (kt + 1 < ntiles) {
            int k0 = (kt + 1) << 5;
            if (AVEC) {
                if (k0 + ak4 < K) *(float4*)areg = *(const float4*)&Arow[k0 + ak4];
                else { areg[0] = areg[1] = areg[2] = areg[3] = 0.f; }
            } else {
#pragma unroll
                for (int j = 0; j < 4; j++) {
                    int gk = k0 + ak4 + j;
                    areg[j] = (gk < K) ? Arow[gk] : 0.f;
                }
            }
#pragma unroll
            for (int j = 0; j < 8; j++) {
                int idx = tid + j * 256;
                int krow = idx >> 6, c4 = idx & 63;
                int gk = k0 + krow;
                breg[j] = (gk < K) ? *(const float4*)&B[(size_t)gk * 256 + c4 * 4]
                                   : make_float4(0.f, 0.f, 0.f, 0.f);
            }
        }

#pragma unroll
        for (int kk = 0; kk < 32; ++kk) {
            float4 af = *(const float4*)&As[kk][tr * 4];
            float4 b0 = *(const float4*)&Bs[kk][tc * 4];
            float4 b1 = *(const float4*)&Bs[kk][128 + tc * 4];
            float av[4] = {af.x, af.y, af.z, af.w};
            float b[8] = {b0.x, b0.y, b0.z, b0.w, b1.x, b1.y, b1.z, b1.w};
#pragma unroll
            for (int i = 0; i < 4; i++)
#pragma unroll
                for (int j = 0; j < 8; j++) acc[i][j] = fmaf(av[i], b[j], acc[i][j]);
        }
        __syncthreads();
    }

    float4 bb0 = *(const float4*)&bias[tc * 4];
    float4 bb1 = *(const float4*)&bias[128 + tc * 4];
    float bv[8] = {bb0.x, bb0.y, bb0.z, bb0.w, bb1.x, bb1.y, bb1.z, bb1.w};
#pragma unroll
    for (int i = 0; i < 4; i++) {
        int gr = row0 + tr * 4 + i;
        float o[8];
#pragma unroll
        for (int j = 0; j < 8; j++) {
            float v = acc[i][j] + bv[j];
            o[j] = GELU ? gelu_exact(v) : v;
        }
        *(float4*)&C[(size_t)gr * 256 + tc * 4] = make_float4(o[0], o[1], o[2], o[3]);
        *(float4*)&C[(size_t)gr * 256 + 128 + tc * 4] = make_float4(o[4], o[5], o[6], o[7]);
    }
}

// Per-node summaries: P1, P2, Q1, Q2 (12 floats/node)
__global__ __launch_bounds__(256)
void node_summary_kernel(const float* __restrict__ m, const float* __restrict__ cw,
                         float* __restrict__ ns) {
    __shared__ __align__(16) float4 s_cw[512];
    int tid = threadIdx.x;
    for (int i = tid; i < 512; i += 256) s_cw[i] = *(const float4*)&cw[(size_t)i * 4];
    __syncthreads();
    int n = blockIdx.x * 4 + (tid >> 6);
    if (n >= N_NODES) return;
    int lane = tid & 63;
    float4 a4 = *(const float4*)&m[(size_t)n * CDIM + lane * 4];
    float av[4] = {a4.x, a4.y, a4.z, a4.w};
    float Q1 = 0.f, Q2 = 0.f, P1[4] = {0, 0, 0, 0}, P2[4] = {0, 0, 0, 0};
#pragma unroll
    for (int j = 0; j < 4; j++) {
        Q1 += av[j];
        Q2 += av[j] * av[j];
        float4 c0 = s_cw[lane * 4 + j];
        float4 c1 = s_cw[256 + lane * 4 + j];
        P1[0] += av[j] * c0.x; P1[1] += av[j] * c0.y; P1[2] += av[j] * c0.z; P1[3] += av[j] * c0.w;
        P2[0] += av[j] * c1.x; P2[1] += av[j] * c1.y; P2[2] += av[j] * c1.z; P2[3] += av[j] * c1.w;
    }
#pragma unroll
    for (int off = 1; off < 64; off <<= 1) {
        Q1 += __shfl_xor(Q1, off, 64);
        Q2 += __shfl_xor(Q2, off, 64);
        P1[0] += __shfl_xor(P1[0], off, 64);
        P1[1] += __shfl_xor(P1[1], off, 64);
        P1[2] += __shfl_xor(P1[2], off, 64);
        P1[3] += __shfl_xor(P1[3], off, 64);
        P2[0] += __shfl_xor(P2[0], off, 64);
        P2[1] += __shfl_xor(P2[1], off, 64);
        P2[2] += __shfl_xor(P2[2], off, 64);
        P2[3] += __shfl_xor(P2[3], off, 64);
    }
    if (lane == 0) {
        float* p = &ns[(size_t)n * 12];
        *(float4*)p = make_float4(P1[0], P1[1], P1[2], P1[3]);
        *(float4*)(p + 4) = make_float4(P2[0], P2[1], P2[2], P2[3]);
        p[8] = Q1;
        p[9] = Q2;
    }
}

// One thread per edge: edge MLP from node summaries; writes w into CSR slot.
__global__ __launch_bounds__(256)
void edge_weight_kernel(const float* __restrict__ ns, const float* __restrict__ x_pos,
                        const int* __restrict__ ei, const float* __restrict__ cw,
                        const float* __restrict__ SgSb, const float* __restrict__ w1_b,
                        const float* __restrict__ ln2_g, const float* __restrict__ ln2_b,
                        const float* __restrict__ w2_w, const float* __restrict__ w2_b,
                        const int* __restrict__ slot, float* __restrict__ w_csr) {
    int e = blockIdx.x * 256 + threadIdx.x;
    if (e >= N_EDGES) return;
    int s = ei[e], d = ei[N_EDGES + e];
    const float* nss = &ns[(size_t)s * 12];
    const float* nsd = &ns[(size_t)d * 12];
    float4 p1 = *(const float4*)nss;
    float4 p2 = *(const float4*)(nsd + 4);
    float S1 = nss[8] + nsd[8];
    float S2 = nss[9] + nsd[9];
    float D[4] = {p1.x + p2.x, p1.y + p2.y, p1.z + p2.z, p1.w + p2.w};
    float ps[6];
    ps[0] = x_pos[(size_t)s * 3 + 0];
    ps[1] = x_pos[(size_t)s * 3 + 1];
    ps[2] = x_pos[(size_t)s * 3 + 2];
    ps[3] = x_pos[(size_t)d * 3 + 0];
    ps[4] = x_pos[(size_t)d * 3 + 1];
    ps[5] = x_pos[(size_t)d * 3 + 2];
#pragma unroll
    for (int k = 0; k < 6; k++) {
        S1 += ps[k];
        S2 += ps[k] * ps[k];
        float4 c = *(const float4*)&cw[(size_t)(512 + k) * 4];
        D[0] += ps[k] * c.x; D[1] += ps[k] * c.y; D[2] += ps[k] * c.z; D[3] += ps[k] * c.w;
    }
    const float inv = 1.f / 518.f;
    float mu = S1 * inv;
    float var = fmaf(-mu, mu, S2 * inv);
    float rstd = rsqrtf(var + LN_EPS);
    float t[4];
#pragma unroll
    for (int c = 0; c < 4; c++)
        t[c] = gelu_exact(rstd * (D[c] - mu * SgSb[c]) + SgSb[4 + c] + w1_b[c]);
    float mu2 = 0.25f * (t[0] + t[1] + t[2] + t[3]);
    float var2 = 0.25f * ((t[0] - mu2) * (t[0] - mu2) + (t[1] - mu2) * (t[1] - mu2) +
                          (t[2] - mu2) * (t[2] - mu2) + (t[3] - mu2) * (t[3] - mu2));
    float r2 = rsqrtf(var2 + LN_EPS);
    float z = w2_b[0];
#pragma unroll
    for (int c = 0; c < 4; c++)
        z += ((t[c] - mu2) * r2 * ln2_g[c] + ln2_b[c]) * w2_w[c];
    w_csr[slot[e]] = 1.f / (1.f + expf(-z));
}

// CSR SpMM: agg[n] = sum_{j in row n} w_csr[j] * m[csr_src[j]].
__global__ __launch_bounds__(256)
void agg_kernel(const float* __restrict__ m, const int* __restrict__ csr_src,
                const float* __restrict__ w_csr, const int* __restrict__ row_start,
                float* __restrict__ agg) {
    int n = blockIdx.x * 4 + (threadIdx.x >> 6);
    if (n >= N_NODES) return;
    int lane = threadIdx.x & 63;
    int beg = row_start[n], end = row_start[n + 1];
    float4 acc = make_float4(0.f, 0.f, 0.f, 0.f);
    for (int j = beg; j < end; j++) {
        int s = csr_src[j];
        float w = w_csr[j];
        float4 v = *(const float4*)&m[(size_t)s * CDIM + lane * 4];
        acc.x = fmaf(w, v.x, acc.x);
        acc.y = fmaf(w, v.y, acc.y);
        acc.z = fmaf(w, v.z, acc.z);
        acc.w = fmaf(w, v.w, acc.w);
    }
    *(float4*)&agg[(size_t)n * CDIM + lane * 4] = acc;
}

__global__ __launch_bounds__(256)
void pool_kernel(const float* __restrict__ h, const int* __restrict__ batch,
                 float* __restrict__ sums, int* __restrict__ cnt) {
    int node = (blockIdx.x * 256 + threadIdx.x) >> 6;
    int lane = threadIdx.x & 63;
    if (node >= N_NODES) return;
    int g = batch[node];
    float4 v = *(const float4*)&h[(size_t)node * CDIM + lane * 4];
    float* sp = &sums[(size_t)g * CDIM + lane * 4];
    atomicAdd(sp + 0, v.x);
    atomicAdd(sp + 1, v.y);
    atomicAdd(sp + 2, v.z);
    atomicAdd(sp + 3, v.w);
    if (lane == 0) atomicAdd(&cnt[g], 1);
}

__global__ void head_kernel(const float* __restrict__ sums, const int* __restrict__ cnt,
                            const float* __restrict__ head_w, const float* __restrict__ head_b,
                            float* __restrict__ out) {
    int g = blockIdx.x;
    int lane = threadIdx.x;  // 64 threads
    float4 s = *(const float4*)&sums[(size_t)g * CDIM + lane * 4];
    float4 w = *(const float4*)&head_w[lane * 4];
    float p = s.x * w.x + s.y * w.y + s.z * w.z + s.w * w.w;
#pragma unroll
    for (int off = 1; off < 64; off <<= 1) p += __shfl_xor(p, off, 64);
    if (lane == 0) {
        float c = fmaxf((float)cnt[g], 1.f);
        out[g] = p / c + head_b[0];
    }
}

extern "C" void kernel_launch(void* const* d_in, const int* in_sizes, int n_in,
                              void* d_out, int out_size, void* d_ws, size_t ws_size,
                              hipStream_t stream) {
    const float* x       = (const float*)d_in[0];
    const float* x_pos   = (const float*)d_in[1];
    const int*   ei      = (const int*)d_in[2];
    const int*   batch   = (const int*)d_in[3];
    const float* dense_w = (const float*)d_in[4];
    const float* dense_b = (const float*)d_in[5];
    const float* d1_w    = (const float*)d_in[6];
    const float* d1_b    = (const float*)d_in[7];
    const float* ln1_g   = (const float*)d_in[8];
    const float* ln1_b   = (const float*)d_in[9];
    const float* w1_w    = (const float*)d_in[10];
    const float* w1_b    = (const float*)d_in[11];
    const float* ln2_g   = (const float*)d_in[12];
    const float* ln2_b   = (const float*)d_in[13];
    const float* w2_w    = (const float*)d_in[14];
    const float* w2_b    = (const float*)d_in[15];
    const float* d2_w    = (const float*)d_in[16];
    const float* d2_b    = (const float*)d_in[17];
    const float* head_w  = (const float*)d_in[18];
    const float* head_b  = (const float*)d_in[19];
    float* out = (float*)d_out;

    float* buf0  = (float*)d_ws;                               // [N, C]
    float* buf1  = buf0 + (size_t)N_NODES * CDIM;              // [N, C]
    float* cw    = buf1 + (size_t)N_NODES * CDIM;              // [L][518][4]
    float* SgSb  = cw + (size_t)NLAYERS * ED_DIM * 4;          // [L][8]
    float* ns    = SgSb + NLAYERS * 8;                         // [N][12]
    float* psums = ns + (size_t)N_NODES * 12;                  // [32][256]
    int* pcnt      = (int*)(psums + N_GRAPHS * CDIM);          // [32] (zeroed with psums)
    float* w_csr = (float*)(pcnt + N_GRAPHS);                  // [E]
    int* deg       = (int*)(w_csr + N_EDGES);                  // [N]
    int* row_start = deg + N_NODES;                            // [N+1]
    int* cursor    = row_start + N_NODES + 1;                  // [N]
    int* csr_src   = cursor + N_NODES;                         // [E]
    int* slot      = csr_src + N_EDGES;                        // [E]

    precompute_kernel<<<NLAYERS, 256, 0, stream>>>(ln1_g, ln1_b, w1_w, cw, SgSb);

    zero_kernel<<<80, 256, 0, stream>>>((float*)deg, N_NODES);
    hist_kernel<<<(N_EDGES + 255) / 256, 256, 0, stream>>>(ei, deg);
    scan_kernel<<<1, 512, 0, stream>>>(deg, row_start, cursor);
    scatter_kernel<<<(N_EDGES + 255) / 256, 256, 0, stream>>>(ei, cursor, csr_src, slot);

    const int GBLOCKS = N_NODES / 32;  // 625
    gemm_bias_act<false, false><<<GBLOCKS, 256, 0, stream>>>(x, dense_w, dense_b, buf0,
                                                             N_NODES, IN_DIMV);

    float* h = buf0;
    float* other = buf1;
    for (int l = 0; l < NLAYERS; l++) {
        gemm_bias_act<true, true><<<GBLOCKS, 256, 0, stream>>>(
            h, d1_w + (size_t)l * CDIM * CDIM, d1_b + l * CDIM, other, N_NODES, CDIM);
        node_summary_kernel<<<(N_NODES + 3) / 4, 256, 0, stream>>>(
            other, cw + (size_t)l * ED_DIM * 4, ns);
        edge_weight_kernel<<<(N_EDGES + 255) / 256, 256, 0, stream>>>(
            ns, x_pos, ei, cw + (size_t)l * ED_DIM * 4, SgSb + l * 8, w1_b + l * 4,
            ln2_g + l * 4, ln2_b + l * 4, w2_w + l * 4, w2_b + l, slot, w_csr);
        agg_kernel<<<(N_NODES + 3) / 4, 256, 0, stream>>>(other, csr_src, w_csr, row_start, h);
        gemm_bias_act<true, true><<<GBLOCKS, 256, 0, stream>>>(
            h, d2_w + (size_t)l * CDIM * CDIM, d2_b + l * CDIM, other, N_NODES, CDIM);
        float* tmp = h; h = other; other = tmp;
    }

    zero_kernel<<<33, 256, 0, stream>>>(psums, N_GRAPHS * CDIM + N_GRAPHS);
    pool_kernel<<<(N_NODES * 64 + 255) / 256, 256, 0, stream>>>(h, batch, psums, pcnt);
    head_kernel<<<N_GRAPHS, 64, 0, stream>>>(psums, pcnt, head_w, head_b, out);
}

// Round 5
// 1084.849 us; speedup vs baseline: 5.0578x; 1.1963x over previous
//
#include <hip/hip_runtime.h>
#include <math.h>

#define N_NODES 20000
#define N_EDGES 320000
#define N_GRAPHS 32
#define CDIM 256
#define IN_DIMV 739
#define ED_DIM 518
#define NLAYERS 4
#define LN_EPS 1e-5f

__device__ __forceinline__ float gelu_exact(float x) {
    return 0.5f * x * (1.f + erff(x * 0.7071067811865475f));
}

__global__ void zero_kernel(float* __restrict__ p, int n) {
    int i = blockIdx.x * blockDim.x + threadIdx.x;
    int stride = gridDim.x * blockDim.x;
    for (; i < n; i += stride) p[i] = 0.f;
}

// Precompute per-layer: cw[i][c] = ln1_g[i] * w1_w[i][c]
// Sg[c] = sum_i g_i*w1[i][c], Sb[c] = sum_i b_i*w1[i][c]
__global__ void precompute_kernel(const float* __restrict__ ln1_g, const float* __restrict__ ln1_b,
                                  const float* __restrict__ w1_w,
                                  float* __restrict__ cw, float* __restrict__ SgSb) {
    int l = blockIdx.x, tid = threadIdx.x;
    float sg[4] = {0, 0, 0, 0}, sb[4] = {0, 0, 0, 0};
    for (int i = tid; i < ED_DIM; i += 256) {
        float g = ln1_g[l * ED_DIM + i];
        float b = ln1_b[l * ED_DIM + i];
        float4 w = *(const float4*)&w1_w[(size_t)(l * ED_DIM + i) * 4];
        float4 c = make_float4(g * w.x, g * w.y, g * w.z, g * w.w);
        *(float4*)&cw[(size_t)(l * ED_DIM + i) * 4] = c;
        sg[0] += c.x; sg[1] += c.y; sg[2] += c.z; sg[3] += c.w;
        sb[0] += b * w.x; sb[1] += b * w.y; sb[2] += b * w.z; sb[3] += b * w.w;
    }
    __shared__ float red[256][8];
    for (int c = 0; c < 4; c++) { red[tid][c] = sg[c]; red[tid][4 + c] = sb[c]; }
    __syncthreads();
    for (int s = 128; s > 0; s >>= 1) {
        if (tid < s)
            for (int c = 0; c < 8; c++) red[tid][c] += red[tid + s][c];
        __syncthreads();
    }
    if (tid < 8) SgSb[l * 8 + tid] = red[0][tid];
}

// ---- CSR build ----
__global__ void hist_kernel(const int* __restrict__ ei, int* __restrict__ deg) {
    int e = blockIdx.x * 256 + threadIdx.x;
    if (e < N_EDGES) atomicAdd(&deg[ei[N_EDGES + e]], 1);
}

__global__ __launch_bounds__(512)
void scan_kernel(const int* __restrict__ deg, int* __restrict__ row_start,
                 int* __restrict__ cursor) {
    __shared__ int sdata[512];
    int t = threadIdx.x;
    const int CHUNK = (N_NODES + 511) / 512;
    int base = t * CHUNK;
    int s = 0;
    for (int i = 0; i < CHUNK; i++) {
        int idx = base + i;
        if (idx < N_NODES) s += deg[idx];
    }
    sdata[t] = s;
    __syncthreads();
    for (int off = 1; off < 512; off <<= 1) {
        int other = (t >= off) ? sdata[t - off] : 0;
        __syncthreads();
        sdata[t] += other;
        __syncthreads();
    }
    int excl = sdata[t] - s;
    int run = excl;
    for (int i = 0; i < CHUNK; i++) {
        int idx = base + i;
        if (idx < N_NODES) {
            row_start[idx] = run;
            cursor[idx] = run;
            run += deg[idx];
        }
    }
    if (t == 511) row_start[N_NODES] = run;
}

__global__ void scatter_kernel(const int* __restrict__ ei, int* __restrict__ cursor,
                               int* __restrict__ csr_src, int* __restrict__ slot) {
    int e = blockIdx.x * 256 + threadIdx.x;
    if (e < N_EDGES) {
        int d = ei[N_EDGES + e];
        int pos = atomicAdd(&cursor[d], 1);
        csr_src[pos] = ei[e];
        slot[e] = pos;
    }
}

// Graph boundaries from sorted batch: gstart[g] = first node of graph g; gstart[32]=N.
__global__ void gstart_kernel(const int* __restrict__ batch, int* __restrict__ gstart) {
    int n = blockIdx.x * 256 + threadIdx.x;
    if (n >= N_NODES) return;
    int b = batch[n];
    int bprev = (n == 0) ? -1 : batch[n - 1];
    for (int g = bprev + 1; g <= b; g++) gstart[g] = n;
    if (n == N_NODES - 1)
        for (int g = b + 1; g <= N_GRAPHS; g++) gstart[g] = N_NODES;
}

// C[M,256] = act(A[M,K] @ B[K,256] + bias).
// BM=32, BN=256 (full width: A read exactly once), BK=32, 256 threads.
// Register-prefetch of tile k+1 overlaps the 32-step FMA burst.
template <bool GELU, bool AVEC>
__global__ __launch_bounds__(256)
void gemm_bias_act(const float* __restrict__ A, const float* __restrict__ B,
                   const float* __restrict__ bias, float* __restrict__ C,
                   int M, int K) {
    __shared__ __align__(16) float As[32][33];   // [k][row], +1 pad
    __shared__ __align__(16) float Bs[32][256];  // [k][col]
    int row0 = blockIdx.x * 32;
    int tid = threadIdx.x;
    int tr = tid >> 5;   // 0..7  -> rows tr*4..tr*4+3
    int tc = tid & 31;   // 0..31 -> cols tc*4..+3 and 128+tc*4..+3

    int arow = tid >> 3;          // 0..31
    int ak4 = (tid & 7) * 4;      // 0,4,...,28
    float areg[4];
    float4 breg[8];

    int ntiles = (K + 31) >> 5;
    const float* Arow = &A[(size_t)(row0 + arow) * K];

    {
        int k0 = 0;
        if (AVEC) {
            if (ak4 < K) *(float4*)areg = *(const float4*)&Arow[k0 + ak4];
            else { areg[0] = areg[1] = areg[2] = areg[3] = 0.f; }
        } else {
#pragma unroll
            for (int j = 0; j < 4; j++) {
                int gk = k0 + ak4 + j;
                areg[j] = (gk < K) ? Arow[gk] : 0.f;
            }
        }
#pragma unroll
        for (int j = 0; j < 8; j++) {
            int idx = tid + j * 256;
            int krow = idx >> 6, c4 = idx & 63;
            int gk = k0 + krow;
            breg[j] = (gk < K) ? *(const float4*)&B[(size_t)gk * 256 + c4 * 4]
                               : make_float4(0.f, 0.f, 0.f, 0.f);
        }
    }

    float acc[4][8];
#pragma unroll
    for (int i = 0; i < 4; i++)
#pragma unroll
        for (int j = 0; j < 8; j++) acc[i][j] = 0.f;

    for (int kt = 0; kt < ntiles; ++kt) {
#pragma unroll
        for (int j = 0; j < 4; j++) As[ak4 + j][arow] = areg[j];
#pragma unroll
        for (int j = 0; j < 8; j++) {
            int idx = tid + j * 256;
            int krow = idx >> 6, c4 = idx & 63;
            *(float4*)&Bs[krow][c4 * 4] = breg[j];
        }
        __syncthreads();

        if (kt + 1 < ntiles) {
            int k0 = (kt + 1) << 5;
            if (AVEC) {
                if (k0 + ak4 < K) *(float4*)areg = *(const float4*)&Arow[k0 + ak4];
                else { areg[0] = areg[1] = areg[2] = areg[3] = 0.f; }
            } else {
#pragma unroll
                for (int j = 0; j < 4; j++) {
                    int gk = k0 + ak4 + j;
                    areg[j] = (gk < K) ? Arow[gk] : 0.f;
                }
            }
#pragma unroll
            for (int j = 0; j < 8; j++) {
                int idx = tid + j * 256;
                int krow = idx >> 6, c4 = idx & 63;
                int gk = k0 + krow;
                breg[j] = (gk < K) ? *(const float4*)&B[(size_t)gk * 256 + c4 * 4]
                                   : make_float4(0.f, 0.f, 0.f, 0.f);
            }
        }

#pragma unroll
        for (int kk = 0; kk < 32; ++kk) {
            float4 af = *(const float4*)&As[kk][tr * 4];
            float4 b0 = *(const float4*)&Bs[kk][tc * 4];
            float4 b1 = *(const float4*)&Bs[kk][128 + tc * 4];
            float av[4] = {af.x, af.y, af.z, af.w};
            float b[8] = {b0.x, b0.y, b0.z, b0.w, b1.x, b1.y, b1.z, b1.w};
#pragma unroll
            for (int i = 0; i < 4; i++)
#pragma unroll
                for (int j = 0; j < 8; j++) acc[i][j] = fmaf(av[i], b[j], acc[i][j]);
        }
        __syncthreads();
    }

    float4 bb0 = *(const float4*)&bias[tc * 4];
    float4 bb1 = *(const float4*)&bias[128 + tc * 4];
    float bv[8] = {bb0.x, bb0.y, bb0.z, bb0.w, bb1.x, bb1.y, bb1.z, bb1.w};
#pragma unroll
    for (int i = 0; i < 4; i++) {
        int gr = row0 + tr * 4 + i;
        float o[8];
#pragma unroll
        for (int j = 0; j < 8; j++) {
            float v = acc[i][j] + bv[j];
            o[j] = GELU ? gelu_exact(v) : v;
        }
        *(float4*)&C[(size_t)gr * 256 + tc * 4] = make_float4(o[0], o[1], o[2], o[3]);
        *(float4*)&C[(size_t)gr * 256 + 128 + tc * 4] = make_float4(o[4], o[5], o[6], o[7]);
    }
}

// Per-node summaries: P1, P2, Q1, Q2 (12 floats/node)
__global__ __launch_bounds__(256)
void node_summary_kernel(const float* __restrict__ m, const float* __restrict__ cw,
                         float* __restrict__ ns) {
    __shared__ __align__(16) float4 s_cw[512];
    int tid = threadIdx.x;
    for (int i = tid; i < 512; i += 256) s_cw[i] = *(const float4*)&cw[(size_t)i * 4];
    __syncthreads();
    int n = blockIdx.x * 4 + (tid >> 6);
    if (n >= N_NODES) return;
    int lane = tid & 63;
    float4 a4 = *(const float4*)&m[(size_t)n * CDIM + lane * 4];
    float av[4] = {a4.x, a4.y, a4.z, a4.w};
    float Q1 = 0.f, Q2 = 0.f, P1[4] = {0, 0, 0, 0}, P2[4] = {0, 0, 0, 0};
#pragma unroll
    for (int j = 0; j < 4; j++) {
        Q1 += av[j];
        Q2 += av[j] * av[j];
        float4 c0 = s_cw[lane * 4 + j];
        float4 c1 = s_cw[256 + lane * 4 + j];
        P1[0] += av[j] * c0.x; P1[1] += av[j] * c0.y; P1[2] += av[j] * c0.z; P1[3] += av[j] * c0.w;
        P2[0] += av[j] * c1.x; P2[1] += av[j] * c1.y; P2[2] += av[j] * c1.z; P2[3] += av[j] * c1.w;
    }
#pragma unroll
    for (int off = 1; off < 64; off <<= 1) {
        Q1 += __shfl_xor(Q1, off, 64);
        Q2 += __shfl_xor(Q2, off, 64);
        P1[0] += __shfl_xor(P1[0], off, 64);
        P1[1] += __shfl_xor(P1[1], off, 64);
        P1[2] += __shfl_xor(P1[2], off, 64);
        P1[3] += __shfl_xor(P1[3], off, 64);
        P2[0] += __shfl_xor(P2[0], off, 64);
        P2[1] += __shfl_xor(P2[1], off, 64);
        P2[2] += __shfl_xor(P2[2], off, 64);
        P2[3] += __shfl_xor(P2[3], off, 64);
    }
    if (lane == 0) {
        float* p = &ns[(size_t)n * 12];
        *(float4*)p = make_float4(P1[0], P1[1], P1[2], P1[3]);
        *(float4*)(p + 4) = make_float4(P2[0], P2[1], P2[2], P2[3]);
        p[8] = Q1;
        p[9] = Q2;
    }
}

// One thread per edge: edge MLP from node summaries; writes w into CSR slot.
__global__ __launch_bounds__(256)
void edge_weight_kernel(const float* __restrict__ ns, const float* __restrict__ x_pos,
                        const int* __restrict__ ei, const float* __restrict__ cw,
                        const float* __restrict__ SgSb, const float* __restrict__ w1_b,
                        const float* __restrict__ ln2_g, const float* __restrict__ ln2_b,
                        const float* __restrict__ w2_w, const float* __restrict__ w2_b,
                        const int* __restrict__ slot, float* __restrict__ w_csr) {
    int e = blockIdx.x * 256 + threadIdx.x;
    if (e >= N_EDGES) return;
    int s = ei[e], d = ei[N_EDGES + e];
    const float* nss = &ns[(size_t)s * 12];
    const float* nsd = &ns[(size_t)d * 12];
    float4 p1 = *(const float4*)nss;
    float4 p2 = *(const float4*)(nsd + 4);
    float S1 = nss[8] + nsd[8];
    float S2 = nss[9] + nsd[9];
    float D[4] = {p1.x + p2.x, p1.y + p2.y, p1.z + p2.z, p1.w + p2.w};
    float ps[6];
    ps[0] = x_pos[(size_t)s * 3 + 0];
    ps[1] = x_pos[(size_t)s * 3 + 1];
    ps[2] = x_pos[(size_t)s * 3 + 2];
    ps[3] = x_pos[(size_t)d * 3 + 0];
    ps[4] = x_pos[(size_t)d * 3 + 1];
    ps[5] = x_pos[(size_t)d * 3 + 2];
#pragma unroll
    for (int k = 0; k < 6; k++) {
        S1 += ps[k];
        S2 += ps[k] * ps[k];
        float4 c = *(const float4*)&cw[(size_t)(512 + k) * 4];
        D[0] += ps[k] * c.x; D[1] += ps[k] * c.y; D[2] += ps[k] * c.z; D[3] += ps[k] * c.w;
    }
    const float inv = 1.f / 518.f;
    float mu = S1 * inv;
    float var = fmaf(-mu, mu, S2 * inv);
    float rstd = rsqrtf(var + LN_EPS);
    float t[4];
#pragma unroll
    for (int c = 0; c < 4; c++)
        t[c] = gelu_exact(rstd * (D[c] - mu * SgSb[c]) + SgSb[4 + c] + w1_b[c]);
    float mu2 = 0.25f * (t[0] + t[1] + t[2] + t[3]);
    float var2 = 0.25f * ((t[0] - mu2) * (t[0] - mu2) + (t[1] - mu2) * (t[1] - mu2) +
                          (t[2] - mu2) * (t[2] - mu2) + (t[3] - mu2) * (t[3] - mu2));
    float r2 = rsqrtf(var2 + LN_EPS);
    float z = w2_b[0];
#pragma unroll
    for (int c = 0; c < 4; c++)
        z += ((t[c] - mu2) * r2 * ln2_g[c] + ln2_b[c]) * w2_w[c];
    w_csr[slot[e]] = 1.f / (1.f + expf(-z));
}

// CSR SpMM: agg[n] = sum_{j in row n} w_csr[j] * m[csr_src[j]].
__global__ __launch_bounds__(256)
void agg_kernel(const float* __restrict__ m, const int* __restrict__ csr_src,
                const float* __restrict__ w_csr, const int* __restrict__ row_start,
                float* __restrict__ agg) {
    int n = blockIdx.x * 4 + (threadIdx.x >> 6);
    if (n >= N_NODES) return;
    int lane = threadIdx.x & 63;
    int beg = row_start[n], end = row_start[n + 1];
    float4 acc = make_float4(0.f, 0.f, 0.f, 0.f);
    for (int j = beg; j < end; j++) {
        int s = csr_src[j];
        float w = w_csr[j];
        float4 v = *(const float4*)&m[(size_t)s * CDIM + lane * 4];
        acc.x = fmaf(w, v.x, acc.x);
        acc.y = fmaf(w, v.y, acc.y);
        acc.z = fmaf(w, v.z, acc.z);
        acc.w = fmaf(w, v.w, acc.w);
    }
    *(float4*)&agg[(size_t)n * CDIM + lane * 4] = acc;
}

// Per-node dot with head_w: sdot[n] = h[n] . head_w  (one wave per node)
__global__ __launch_bounds__(256)
void node_dot_kernel(const float* __restrict__ h, const float* __restrict__ head_w,
                     float* __restrict__ sdot) {
    int n = blockIdx.x * 4 + (threadIdx.x >> 6);
    if (n >= N_NODES) return;
    int lane = threadIdx.x & 63;
    float4 v = *(const float4*)&h[(size_t)n * CDIM + lane * 4];
    float4 w = *(const float4*)&head_w[lane * 4];
    float p = v.x * w.x + v.y * w.y + v.z * w.z + v.w * w.w;
#pragma unroll
    for (int off = 1; off < 64; off <<= 1) p += __shfl_xor(p, off, 64);
    if (lane == 0) sdot[n] = p;
}

// Segment-sum of sdot per graph using gstart; out[g] = sum/cnt + head_b.
__global__ __launch_bounds__(256)
void final_head_kernel(const float* __restrict__ sdot, const int* __restrict__ gstart,
                       const float* __restrict__ head_b, float* __restrict__ out) {
    int g = blockIdx.x;
    int t = threadIdx.x;
    int beg = gstart[g], end = gstart[g + 1];
    float s = 0.f;
    for (int i = beg + t; i < end; i += 256) s += sdot[i];
    __shared__ float red[256];
    red[t] = s;
    __syncthreads();
    for (int k = 128; k > 0; k >>= 1) {
        if (t < k) red[t] += red[t + k];
        __syncthreads();
    }
    if (t == 0) out[g] = red[0] / fmaxf((float)(end - beg), 1.f) + head_b[0];
}

extern "C" void kernel_launch(void* const* d_in, const int* in_sizes, int n_in,
                              void* d_out, int out_size, void* d_ws, size_t ws_size,
                              hipStream_t stream) {
    const float* x       = (const float*)d_in[0];
    const float* x_pos   = (const float*)d_in[1];
    const int*   ei      = (const int*)d_in[2];
    const int*   batch   = (const int*)d_in[3];
    const float* dense_w = (const float*)d_in[4];
    const float* dense_b = (const float*)d_in[5];
    const float* d1_w    = (const float*)d_in[6];
    const float* d1_b    = (const float*)d_in[7];
    const float* ln1_g   = (const float*)d_in[8];
    const float* ln1_b   = (const float*)d_in[9];
    const float* w1_w    = (const float*)d_in[10];
    const float* w1_b    = (const float*)d_in[11];
    const float* ln2_g   = (const float*)d_in[12];
    const float* ln2_b   = (const float*)d_in[13];
    const float* w2_w    = (const float*)d_in[14];
    const float* w2_b    = (const float*)d_in[15];
    const float* d2_w    = (const float*)d_in[16];
    const float* d2_b    = (const float*)d_in[17];
    const float* head_w  = (const float*)d_in[18];
    const float* head_b  = (const float*)d_in[19];
    float* out = (float*)d_out;

    float* buf0  = (float*)d_ws;                               // [N, C]
    float* buf1  = buf0 + (size_t)N_NODES * CDIM;              // [N, C]
    float* cw    = buf1 + (size_t)N_NODES * CDIM;              // [L][518][4]
    float* SgSb  = cw + (size_t)NLAYERS * ED_DIM * 4;          // [L][8]
    float* ns    = SgSb + NLAYERS * 8;                         // [N][12]
    float* sdot  = ns + (size_t)N_NODES * 12;                  // [N]
    float* w_csr = sdot + N_NODES;                             // [E]
    int* gstart    = (int*)(w_csr + N_EDGES);                  // [33]
    int* deg       = gstart + N_GRAPHS + 1;                    // [N]
    int* row_start = deg + N_NODES;                            // [N+1]
    int* cursor    = row_start + N_NODES + 1;                  // [N]
    int* csr_src   = cursor + N_NODES;                         // [E]
    int* slot      = csr_src + N_EDGES;                        // [E]

    precompute_kernel<<<NLAYERS, 256, 0, stream>>>(ln1_g, ln1_b, w1_w, cw, SgSb);

    zero_kernel<<<80, 256, 0, stream>>>((float*)deg, N_NODES);
    hist_kernel<<<(N_EDGES + 255) / 256, 256, 0, stream>>>(ei, deg);
    scan_kernel<<<1, 512, 0, stream>>>(deg, row_start, cursor);
    scatter_kernel<<<(N_EDGES + 255) / 256, 256, 0, stream>>>(ei, cursor, csr_src, slot);
    gstart_kernel<<<(N_NODES + 255) / 256, 256, 0, stream>>>(batch, gstart);

    const int GBLOCKS = N_NODES / 32;  // 625
    gemm_bias_act<false, false><<<GBLOCKS, 256, 0, stream>>>(x, dense_w, dense_b, buf0,
                                                             N_NODES, IN_DIMV);

    float* h = buf0;
    float* other = buf1;
    for (int l = 0; l < NLAYERS; l++) {
        gemm_bias_act<true, true><<<GBLOCKS, 256, 0, stream>>>(
            h, d1_w + (size_t)l * CDIM * CDIM, d1_b + l * CDIM, other, N_NODES, CDIM);
        node_summary_kernel<<<(N_NODES + 3) / 4, 256, 0, stream>>>(
            other, cw + (size_t)l * ED_DIM * 4, ns);
        edge_weight_kernel<<<(N_EDGES + 255) / 256, 256, 0, stream>>>(
            ns, x_pos, ei, cw + (size_t)l * ED_DIM * 4, SgSb + l * 8, w1_b + l * 4,
            ln2_g + l * 4, ln2_b + l * 4, w2_w + l * 4, w2_b + l, slot, w_csr);
        agg_kernel<<<(N_NODES + 3) / 4, 256, 0, stream>>>(other, csr_src, w_csr, row_start, h);
        gemm_bias_act<true, true><<<GBLOCKS, 256, 0, stream>>>(
            h, d2_w + (size_t)l * CDIM * CDIM, d2_b + l * CDIM, other, N_NODES, CDIM);
        float* tmp = h; h = other; other = tmp;
    }

    node_dot_kernel<<<(N_NODES + 3) / 4, 256, 0, stream>>>(h, head_w, sdot);
    final_head_kernel<<<N_GRAPHS, 256, 0, stream>>>(sdot, gstart, head_b, out);
}

// Round 6
// 855.296 us; speedup vs baseline: 6.4152x; 1.2684x over previous
//
#include <hip/hip_runtime.h>
#include <math.h>

#define N_NODES 20000
#define N_EDGES 320000
#define N_GRAPHS 32
#define CDIM 256
#define IN_DIMV 739
#define KPAD_DENSE 768
#define ED_DIM 518
#define NLAYERS 4
#define LN_EPS 1e-5f

typedef _Float16 f16x8 __attribute__((ext_vector_type(8)));
typedef float f32x4 __attribute__((ext_vector_type(4)));

__device__ __forceinline__ float gelu_exact(float x) {
    return 0.5f * x * (1.f + erff(x * 0.7071067811865475f));
}

__global__ void zero_kernel(float* __restrict__ p, int n) {
    int i = blockIdx.x * blockDim.x + threadIdx.x;
    int stride = gridDim.x * blockDim.x;
    for (; i < n; i += stride) p[i] = 0.f;
}

// Precompute per-layer: cw[i][c] = ln1_g[i] * w1_w[i][c]
__global__ void precompute_kernel(const float* __restrict__ ln1_g, const float* __restrict__ ln1_b,
                                  const float* __restrict__ w1_w,
                                  float* __restrict__ cw, float* __restrict__ SgSb) {
    int l = blockIdx.x, tid = threadIdx.x;
    float sg[4] = {0, 0, 0, 0}, sb[4] = {0, 0, 0, 0};
    for (int i = tid; i < ED_DIM; i += 256) {
        float g = ln1_g[l * ED_DIM + i];
        float b = ln1_b[l * ED_DIM + i];
        float4 w = *(const float4*)&w1_w[(size_t)(l * ED_DIM + i) * 4];
        float4 c = make_float4(g * w.x, g * w.y, g * w.z, g * w.w);
        *(float4*)&cw[(size_t)(l * ED_DIM + i) * 4] = c;
        sg[0] += c.x; sg[1] += c.y; sg[2] += c.z; sg[3] += c.w;
        sb[0] += b * w.x; sb[1] += b * w.y; sb[2] += b * w.z; sb[3] += b * w.w;
    }
    __shared__ float red[256][8];
    for (int c = 0; c < 4; c++) { red[tid][c] = sg[c]; red[tid][4 + c] = sb[c]; }
    __syncthreads();
    for (int s = 128; s > 0; s >>= 1) {
        if (tid < s)
            for (int c = 0; c < 8; c++) red[tid][c] += red[tid + s][c];
        __syncthreads();
    }
    if (tid < 8) SgSb[l * 8 + tid] = red[0][tid];
}

// ---- CSR build ----
__global__ void hist_kernel(const int* __restrict__ ei, int* __restrict__ deg) {
    int e = blockIdx.x * 256 + threadIdx.x;
    if (e < N_EDGES) atomicAdd(&deg[ei[N_EDGES + e]], 1);
}

__global__ __launch_bounds__(512)
void scan_kernel(const int* __restrict__ deg, int* __restrict__ row_start,
                 int* __restrict__ cursor) {
    __shared__ int sdata[512];
    int t = threadIdx.x;
    const int CHUNK = (N_NODES + 511) / 512;
    int base = t * CHUNK;
    int s = 0;
    for (int i = 0; i < CHUNK; i++) {
        int idx = base + i;
        if (idx < N_NODES) s += deg[idx];
    }
    sdata[t] = s;
    __syncthreads();
    for (int off = 1; off < 512; off <<= 1) {
        int other = (t >= off) ? sdata[t - off] : 0;
        __syncthreads();
        sdata[t] += other;
        __syncthreads();
    }
    int excl = sdata[t] - s;
    int run = excl;
    for (int i = 0; i < CHUNK; i++) {
        int idx = base + i;
        if (idx < N_NODES) {
            row_start[idx] = run;
            cursor[idx] = run;
            run += deg[idx];
        }
    }
    if (t == 511) row_start[N_NODES] = run;
}

__global__ void scatter_kernel(const int* __restrict__ ei, int* __restrict__ cursor,
                               int* __restrict__ csr_src, int* __restrict__ slot) {
    int e = blockIdx.x * 256 + threadIdx.x;
    if (e < N_EDGES) {
        int d = ei[N_EDGES + e];
        int pos = atomicAdd(&cursor[d], 1);
        csr_src[pos] = ei[e];
        slot[e] = pos;
    }
}

__global__ void gstart_kernel(const int* __restrict__ batch, int* __restrict__ gstart) {
    int n = blockIdx.x * 256 + threadIdx.x;
    if (n >= N_NODES) return;
    int b = batch[n];
    int bprev = (n == 0) ? -1 : batch[n - 1];
    for (int g = bprev + 1; g <= b; g++) gstart[g] = n;
    if (n == N_NODES - 1)
        for (int g = b + 1; g <= N_GRAPHS; g++) gstart[g] = N_NODES;
}

// Transpose+convert W[K][256] fp32 -> Wt[256][Kpad] fp16 (zero-padded k>=K).
__global__ __launch_bounds__(256)
void prep_weight(const float* __restrict__ W, _Float16* __restrict__ Wt, int K, int Kpad) {
    __shared__ float T[32][33];
    int kt = blockIdx.x, nt = blockIdx.y;
    int tid = threadIdx.x;
    int i = tid >> 5, j = tid & 31;
#pragma unroll
    for (int ii = 0; ii < 4; ii++) {
        int k = kt * 32 + i + ii * 8;
        T[i + ii * 8][j] = (k < K) ? W[(size_t)k * 256 + nt * 32 + j] : 0.f;
    }
    __syncthreads();
#pragma unroll
    for (int ii = 0; ii < 4; ii++) {
        int n = nt * 32 + i + ii * 8;
        Wt[(size_t)n * Kpad + kt * 32 + j] = (_Float16)T[j][i + ii * 8];
    }
}

// Same, batched over the 8 square layer weights (z<4: d1_w[z], else d2_w[z-4]).
__global__ __launch_bounds__(256)
void prep_weight_sq(const float* __restrict__ d1_w, const float* __restrict__ d2_w,
                    _Float16* __restrict__ Wt) {
    __shared__ float T[32][33];
    int kt = blockIdx.x, nt = blockIdx.y, z = blockIdx.z;
    const float* W = (z < 4) ? d1_w + (size_t)z * 65536 : d2_w + (size_t)(z - 4) * 65536;
    _Float16* O = Wt + (size_t)z * 65536;
    int tid = threadIdx.x;
    int i = tid >> 5, j = tid & 31;
#pragma unroll
    for (int ii = 0; ii < 4; ii++)
        T[i + ii * 8][j] = W[(size_t)(kt * 32 + i + ii * 8) * 256 + nt * 32 + j];
    __syncthreads();
#pragma unroll
    for (int ii = 0; ii < 4; ii++)
        O[(size_t)(nt * 32 + i + ii * 8) * 256 + kt * 32 + j] = (_Float16)T[j][i + ii * 8];
}

// C[M,256] = act(A @ W + bias) via fp16 MFMA 16x16x32, fp32 accumulate.
// Block: 256 thr / 4 waves. Tile BM=64, BN=128, BK=32. Wave w: rows 16w..16w+15,
// 8 col-tiles of 16. Bt is [256][Kpad] fp16 (transposed weights). A converted
// fp32->fp16 during staging. LDS rows padded to 40 fp16 (80 B: 16B-aligned, 2-way banks).
template <bool GELU, bool AVEC>
__global__ __launch_bounds__(256)
void gemm_mfma(const float* __restrict__ A, const _Float16* __restrict__ Bt,
               const float* __restrict__ bias, float* __restrict__ C,
               int M, int K, int Kpad) {
    __shared__ __align__(16) _Float16 As[64 * 40];
    __shared__ __align__(16) _Float16 Bs[128 * 40];
    int tid = threadIdx.x;
    int row0 = blockIdx.x * 64;
    int col0 = blockIdx.y * 128;
    int wave = tid >> 6, lane = tid & 63;
    int quad = lane >> 4, lrow = lane & 15;

    int ar = tid >> 2;        // 0..63  (A stage row)
    int ak8 = (tid & 3) * 8;  // 0,8,16,24
    int bn = tid >> 1;        // 0..127 (B stage n)
    int bh = (tid & 1) * 16;  // 0 or 16 elements

    const float* Arow = &A[(size_t)(row0 + ar) * K];
    bool arOK = (row0 + ar) < M;
    const _Float16* Brow = &Bt[(size_t)(col0 + bn) * Kpad];

    int ntiles = (K + 31) >> 5;

    float a_f[8];
    uint4 b_raw[2];

    // stage-0 loads
    {
        if (AVEC) {
            if (arOK) {
                float4 v0 = *(const float4*)&Arow[ak8];
                float4 v1 = *(const float4*)&Arow[ak8 + 4];
                a_f[0] = v0.x; a_f[1] = v0.y; a_f[2] = v0.z; a_f[3] = v0.w;
                a_f[4] = v1.x; a_f[5] = v1.y; a_f[6] = v1.z; a_f[7] = v1.w;
            } else {
#pragma unroll
                for (int j = 0; j < 8; j++) a_f[j] = 0.f;
            }
        } else {
#pragma unroll
            for (int j = 0; j < 8; j++) {
                int gk = ak8 + j;
                a_f[j] = (arOK && gk < K) ? Arow[gk] : 0.f;
            }
        }
        const _Float16* p = &Brow[bh];
        b_raw[0] = *(const uint4*)p;
        b_raw[1] = *(const uint4*)(p + 8);
    }

    f32x4 acc[8];
#pragma unroll
    for (int t = 0; t < 8; t++) acc[t] = (f32x4){0.f, 0.f, 0.f, 0.f};

    for (int kt = 0; kt < ntiles; ++kt) {
        f16x8 ah;
#pragma unroll
        for (int j = 0; j < 8; j++) ah[j] = (_Float16)a_f[j];
        *(f16x8*)&As[ar * 40 + ak8] = ah;
        *(uint4*)&Bs[bn * 40 + bh] = b_raw[0];
        *(uint4*)&Bs[bn * 40 + bh + 8] = b_raw[1];
        __syncthreads();

        if (kt + 1 < ntiles) {
            int k0 = (kt + 1) << 5;
            if (AVEC) {
                if (arOK) {
                    float4 v0 = *(const float4*)&Arow[k0 + ak8];
                    float4 v1 = *(const float4*)&Arow[k0 + ak8 + 4];
                    a_f[0] = v0.x; a_f[1] = v0.y; a_f[2] = v0.z; a_f[3] = v0.w;
                    a_f[4] = v1.x; a_f[5] = v1.y; a_f[6] = v1.z; a_f[7] = v1.w;
                }
            } else {
#pragma unroll
                for (int j = 0; j < 8; j++) {
                    int gk = k0 + ak8 + j;
                    a_f[j] = (arOK && gk < K) ? Arow[gk] : 0.f;
                }
            }
            const _Float16* p = &Brow[k0 + bh];
            b_raw[0] = *(const uint4*)p;
            b_raw[1] = *(const uint4*)(p + 8);
        }

        f16x8 af = *(const f16x8*)&As[(wave * 16 + lrow) * 40 + quad * 8];
#pragma unroll
        for (int t = 0; t < 8; t++) {
            f16x8 bf = *(const f16x8*)&Bs[(t * 16 + lrow) * 40 + quad * 8];
            acc[t] = __builtin_amdgcn_mfma_f32_16x16x32_f16(af, bf, acc[t], 0, 0, 0);
        }
        __syncthreads();
    }

    // epilogue: C/D layout col=lane&15, row=quad*4+reg (HW-verified)
    int orow = row0 + wave * 16 + quad * 4;
#pragma unroll
    for (int t = 0; t < 8; t++) {
        int col = col0 + t * 16 + lrow;
        float bv = bias[col];
#pragma unroll
        for (int r = 0; r < 4; r++) {
            int gr = orow + r;
            if (gr < M) {
                float v = acc[t][r] + bv;
                C[(size_t)gr * 256 + col] = GELU ? gelu_exact(v) : v;
            }
        }
    }
}

// Per-node summaries: P1, P2, Q1, Q2 (12 floats/node)
__global__ __launch_bounds__(256)
void node_summary_kernel(const float* __restrict__ m, const float* __restrict__ cw,
                         float* __restrict__ ns) {
    __shared__ __align__(16) float4 s_cw[512];
    int tid = threadIdx.x;
    for (int i = tid; i < 512; i += 256) s_cw[i] = *(const float4*)&cw[(size_t)i * 4];
    __syncthreads();
    int n = blockIdx.x * 4 + (tid >> 6);
    if (n >= N_NODES) return;
    int lane = tid & 63;
    float4 a4 = *(const float4*)&m[(size_t)n * CDIM + lane * 4];
    float av[4] = {a4.x, a4.y, a4.z, a4.w};
    float Q1 = 0.f, Q2 = 0.f, P1[4] = {0, 0, 0, 0}, P2[4] = {0, 0, 0, 0};
#pragma unroll
    for (int j = 0; j < 4; j++) {
        Q1 += av[j];
        Q2 += av[j] * av[j];
        float4 c0 = s_cw[lane * 4 + j];
        float4 c1 = s_cw[256 + lane * 4 + j];
        P1[0] += av[j] * c0.x; P1[1] += av[j] * c0.y; P1[2] += av[j] * c0.z; P1[3] += av[j] * c0.w;
        P2[0] += av[j] * c1.x; P2[1] += av[j] * c1.y; P2[2] += av[j] * c1.z; P2[3] += av[j] * c1.w;
    }
#pragma unroll
    for (int off = 1; off < 64; off <<= 1) {
        Q1 += __shfl_xor(Q1, off, 64);
        Q2 += __shfl_xor(Q2, off, 64);
        P1[0] += __shfl_xor(P1[0], off, 64);
        P1[1] += __shfl_xor(P1[1], off, 64);
        P1[2] += __shfl_xor(P1[2], off, 64);
        P1[3] += __shfl_xor(P1[3], off, 64);
        P2[0] += __shfl_xor(P2[0], off, 64);
        P2[1] += __shfl_xor(P2[1], off, 64);
        P2[2] += __shfl_xor(P2[2], off, 64);
        P2[3] += __shfl_xor(P2[3], off, 64);
    }
    if (lane == 0) {
        float* p = &ns[(size_t)n * 12];
        *(float4*)p = make_float4(P1[0], P1[1], P1[2], P1[3]);
        *(float4*)(p + 4) = make_float4(P2[0], P2[1], P2[2], P2[3]);
        p[8] = Q1;
        p[9] = Q2;
    }
}

// One thread per edge: edge MLP from node summaries; writes w into CSR slot.
__global__ __launch_bounds__(256)
void edge_weight_kernel(const float* __restrict__ ns, const float* __restrict__ x_pos,
                        const int* __restrict__ ei, const float* __restrict__ cw,
                        const float* __restrict__ SgSb, const float* __restrict__ w1_b,
                        const float* __restrict__ ln2_g, const float* __restrict__ ln2_b,
                        const float* __restrict__ w2_w, const float* __restrict__ w2_b,
                        const int* __restrict__ slot, float* __restrict__ w_csr) {
    int e = blockIdx.x * 256 + threadIdx.x;
    if (e >= N_EDGES) return;
    int s = ei[e], d = ei[N_EDGES + e];
    const float* nss = &ns[(size_t)s * 12];
    const float* nsd = &ns[(size_t)d * 12];
    float4 p1 = *(const float4*)nss;
    float4 p2 = *(const float4*)(nsd + 4);
    float S1 = nss[8] + nsd[8];
    float S2 = nss[9] + nsd[9];
    float D[4] = {p1.x + p2.x, p1.y + p2.y, p1.z + p2.z, p1.w + p2.w};
    float ps[6];
    ps[0] = x_pos[(size_t)s * 3 + 0];
    ps[1] = x_pos[(size_t)s * 3 + 1];
    ps[2] = x_pos[(size_t)s * 3 + 2];
    ps[3] = x_pos[(size_t)d * 3 + 0];
    ps[4] = x_pos[(size_t)d * 3 + 1];
    ps[5] = x_pos[(size_t)d * 3 + 2];
#pragma unroll
    for (int k = 0; k < 6; k++) {
        S1 += ps[k];
        S2 += ps[k] * ps[k];
        float4 c = *(const float4*)&cw[(size_t)(512 + k) * 4];
        D[0] += ps[k] * c.x; D[1] += ps[k] * c.y; D[2] += ps[k] * c.z; D[3] += ps[k] * c.w;
    }
    const float inv = 1.f / 518.f;
    float mu = S1 * inv;
    float var = fmaf(-mu, mu, S2 * inv);
    float rstd = rsqrtf(var + LN_EPS);
    float t[4];
#pragma unroll
    for (int c = 0; c < 4; c++)
        t[c] = gelu_exact(rstd * (D[c] - mu * SgSb[c]) + SgSb[4 + c] + w1_b[c]);
    float mu2 = 0.25f * (t[0] + t[1] + t[2] + t[3]);
    float var2 = 0.25f * ((t[0] - mu2) * (t[0] - mu2) + (t[1] - mu2) * (t[1] - mu2) +
                          (t[2] - mu2) * (t[2] - mu2) + (t[3] - mu2) * (t[3] - mu2));
    float r2 = rsqrtf(var2 + LN_EPS);
    float z = w2_b[0];
#pragma unroll
    for (int c = 0; c < 4; c++)
        z += ((t[c] - mu2) * r2 * ln2_g[c] + ln2_b[c]) * w2_w[c];
    w_csr[slot[e]] = 1.f / (1.f + expf(-z));
}

// CSR SpMM: agg[n] = sum_{j in row n} w_csr[j] * m[csr_src[j]].
__global__ __launch_bounds__(256)
void agg_kernel(const float* __restrict__ m, const int* __restrict__ csr_src,
                const float* __restrict__ w_csr, const int* __restrict__ row_start,
                float* __restrict__ agg) {
    int n = blockIdx.x * 4 + (threadIdx.x >> 6);
    if (n >= N_NODES) return;
    int lane = threadIdx.x & 63;
    int beg = row_start[n], end = row_start[n + 1];
    float4 acc = make_float4(0.f, 0.f, 0.f, 0.f);
    for (int j = beg; j < end; j++) {
        int s = csr_src[j];
        float w = w_csr[j];
        float4 v = *(const float4*)&m[(size_t)s * CDIM + lane * 4];
        acc.x = fmaf(w, v.x, acc.x);
        acc.y = fmaf(w, v.y, acc.y);
        acc.z = fmaf(w, v.z, acc.z);
        acc.w = fmaf(w, v.w, acc.w);
    }
    *(float4*)&agg[(size_t)n * CDIM + lane * 4] = acc;
}

__global__ __launch_bounds__(256)
void node_dot_kernel(const float* __restrict__ h, const float* __restrict__ head_w,
                     float* __restrict__ sdot) {
    int n = blockIdx.x * 4 + (threadIdx.x >> 6);
    if (n >= N_NODES) return;
    int lane = threadIdx.x & 63;
    float4 v = *(const float4*)&h[(size_t)n * CDIM + lane * 4];
    float4 w = *(const float4*)&head_w[lane * 4];
    float p = v.x * w.x + v.y * w.y + v.z * w.z + v.w * w.w;
#pragma unroll
    for (int off = 1; off < 64; off <<= 1) p += __shfl_xor(p, off, 64);
    if (lane == 0) sdot[n] = p;
}

__global__ __launch_bounds__(256)
void final_head_kernel(const float* __restrict__ sdot, const int* __restrict__ gstart,
                       const float* __restrict__ head_b, float* __restrict__ out) {
    int g = blockIdx.x;
    int t = threadIdx.x;
    int beg = gstart[g], end = gstart[g + 1];
    float s = 0.f;
    for (int i = beg + t; i < end; i += 256) s += sdot[i];
    __shared__ float red[256];
    red[t] = s;
    __syncthreads();
    for (int k = 128; k > 0; k >>= 1) {
        if (t < k) red[t] += red[t + k];
        __syncthreads();
    }
    if (t == 0) out[g] = red[0] / fmaxf((float)(end - beg), 1.f) + head_b[0];
}

extern "C" void kernel_launch(void* const* d_in, const int* in_sizes, int n_in,
                              void* d_out, int out_size, void* d_ws, size_t ws_size,
                              hipStream_t stream) {
    const float* x       = (const float*)d_in[0];
    const float* x_pos   = (const float*)d_in[1];
    const int*   ei      = (const int*)d_in[2];
    const int*   batch   = (const int*)d_in[3];
    const float* dense_w = (const float*)d_in[4];
    const float* dense_b = (const float*)d_in[5];
    const float* d1_w    = (const float*)d_in[6];
    const float* d1_b    = (const float*)d_in[7];
    const float* ln1_g   = (const float*)d_in[8];
    const float* ln1_b   = (const float*)d_in[9];
    const float* w1_w    = (const float*)d_in[10];
    const float* w1_b    = (const float*)d_in[11];
    const float* ln2_g   = (const float*)d_in[12];
    const float* ln2_b   = (const float*)d_in[13];
    const float* w2_w    = (const float*)d_in[14];
    const float* w2_b    = (const float*)d_in[15];
    const float* d2_w    = (const float*)d_in[16];
    const float* d2_b    = (const float*)d_in[17];
    const float* head_w  = (const float*)d_in[18];
    const float* head_b  = (const float*)d_in[19];
    float* out = (float*)d_out;

    float* buf0  = (float*)d_ws;                               // [N, C]
    float* buf1  = buf0 + (size_t)N_NODES * CDIM;              // [N, C]
    float* cw    = buf1 + (size_t)N_NODES * CDIM;              // [L][518][4]
    float* SgSb  = cw + (size_t)NLAYERS * ED_DIM * 4;          // [L][8]
    float* ns    = SgSb + NLAYERS * 8;                         // [N][12]
    float* sdot  = ns + (size_t)N_NODES * 12;                  // [N]
    float* w_csr = sdot + N_NODES;                             // [E]
    _Float16* wt_dense = (_Float16*)(w_csr + N_EDGES);         // [256][768]
    _Float16* wt_sq    = wt_dense + (size_t)256 * KPAD_DENSE;  // [8][256][256]
    int* gstart    = (int*)(wt_sq + (size_t)8 * 256 * 256);    // [33]
    int* deg       = gstart + N_GRAPHS + 1;                    // [N]
    int* row_start = deg + N_NODES;                            // [N+1]
    int* cursor    = row_start + N_NODES + 1;                  // [N]
    int* csr_src   = cursor + N_NODES;                         // [E]
    int* slot      = csr_src + N_EDGES;                        // [E]

    precompute_kernel<<<NLAYERS, 256, 0, stream>>>(ln1_g, ln1_b, w1_w, cw, SgSb);

    zero_kernel<<<80, 256, 0, stream>>>((float*)deg, N_NODES);
    hist_kernel<<<(N_EDGES + 255) / 256, 256, 0, stream>>>(ei, deg);
    scan_kernel<<<1, 512, 0, stream>>>(deg, row_start, cursor);
    scatter_kernel<<<(N_EDGES + 255) / 256, 256, 0, stream>>>(ei, cursor, csr_src, slot);
    gstart_kernel<<<(N_NODES + 255) / 256, 256, 0, stream>>>(batch, gstart);

    // weights -> fp16 transposed
    prep_weight<<<dim3(24, 8), 256, 0, stream>>>(dense_w, wt_dense, IN_DIMV, KPAD_DENSE);
    prep_weight_sq<<<dim3(8, 8, 8), 256, 0, stream>>>(d1_w, d2_w, wt_sq);

    const dim3 GGRID((N_NODES + 63) / 64, 2);
    gemm_mfma<false, false><<<GGRID, 256, 0, stream>>>(x, wt_dense, dense_b, buf0,
                                                       N_NODES, IN_DIMV, KPAD_DENSE);

    float* h = buf0;
    float* other = buf1;
    for (int l = 0; l < NLAYERS; l++) {
        gemm_mfma<true, true><<<GGRID, 256, 0, stream>>>(
            h, wt_sq + (size_t)l * 65536, d1_b + l * CDIM, other, N_NODES, CDIM, CDIM);
        node_summary_kernel<<<(N_NODES + 3) / 4, 256, 0, stream>>>(
            other, cw + (size_t)l * ED_DIM * 4, ns);
        edge_weight_kernel<<<(N_EDGES + 255) / 256, 256, 0, stream>>>(
            ns, x_pos, ei, cw + (size_t)l * ED_DIM * 4, SgSb + l * 8, w1_b + l * 4,
            ln2_g + l * 4, ln2_b + l * 4, w2_w + l * 4, w2_b + l, slot, w_csr);
        agg_kernel<<<(N_NODES + 3) / 4, 256, 0, stream>>>(other, csr_src, w_csr, row_start, h);
        gemm_mfma<true, true><<<GGRID, 256, 0, stream>>>(
            h, wt_sq + (size_t)(4 + l) * 65536, d2_b + l * CDIM, other, N_NODES, CDIM, CDIM);
        float* tmp = h; h = other; other = tmp;
    }

    node_dot_kernel<<<(N_NODES + 3) / 4, 256, 0, stream>>>(h, head_w, sdot);
    final_head_kernel<<<N_GRAPHS, 256, 0, stream>>>(sdot, gstart, head_b, out);
}

// Round 7
// 786.879 us; speedup vs baseline: 6.9730x; 1.0869x over previous
//
#include <hip/hip_runtime.h>
#include <math.h>

#define N_NODES 20000
#define N_EDGES 320000
#define N_GRAPHS 32
#define CDIM 256
#define IN_DIMV 739
#define KPAD_DENSE 768
#define ED_DIM 518
#define NLAYERS 4
#define LN_EPS 1e-5f

typedef _Float16 f16x8 __attribute__((ext_vector_type(8)));
typedef _Float16 f16x4 __attribute__((ext_vector_type(4)));
typedef float f32x4 __attribute__((ext_vector_type(4)));

__device__ __forceinline__ float gelu_exact(float x) {
    return 0.5f * x * (1.f + erff(x * 0.7071067811865475f));
}

__global__ void zero_kernel(float* __restrict__ p, int n) {
    int i = blockIdx.x * blockDim.x + threadIdx.x;
    int stride = gridDim.x * blockDim.x;
    for (; i < n; i += stride) p[i] = 0.f;
}

// Precompute per-layer: cw[i][c] = ln1_g[i] * w1_w[i][c]
__global__ void precompute_kernel(const float* __restrict__ ln1_g, const float* __restrict__ ln1_b,
                                  const float* __restrict__ w1_w,
                                  float* __restrict__ cw, float* __restrict__ SgSb) {
    int l = blockIdx.x, tid = threadIdx.x;
    float sg[4] = {0, 0, 0, 0}, sb[4] = {0, 0, 0, 0};
    for (int i = tid; i < ED_DIM; i += 256) {
        float g = ln1_g[l * ED_DIM + i];
        float b = ln1_b[l * ED_DIM + i];
        float4 w = *(const float4*)&w1_w[(size_t)(l * ED_DIM + i) * 4];
        float4 c = make_float4(g * w.x, g * w.y, g * w.z, g * w.w);
        *(float4*)&cw[(size_t)(l * ED_DIM + i) * 4] = c;
        sg[0] += c.x; sg[1] += c.y; sg[2] += c.z; sg[3] += c.w;
        sb[0] += b * w.x; sb[1] += b * w.y; sb[2] += b * w.z; sb[3] += b * w.w;
    }
    __shared__ float red[256][8];
    for (int c = 0; c < 4; c++) { red[tid][c] = sg[c]; red[tid][4 + c] = sb[c]; }
    __syncthreads();
    for (int s = 128; s > 0; s >>= 1) {
        if (tid < s)
            for (int c = 0; c < 8; c++) red[tid][c] += red[tid + s][c];
        __syncthreads();
    }
    if (tid < 8) SgSb[l * 8 + tid] = red[0][tid];
}

// ---- CSR build ----
__global__ void hist_kernel(const int* __restrict__ ei, int* __restrict__ deg) {
    int e = blockIdx.x * 256 + threadIdx.x;
    if (e < N_EDGES) atomicAdd(&deg[ei[N_EDGES + e]], 1);
}

__global__ __launch_bounds__(512)
void scan_kernel(const int* __restrict__ deg, int* __restrict__ row_start,
                 int* __restrict__ cursor) {
    __shared__ int sdata[512];
    int t = threadIdx.x;
    const int CHUNK = (N_NODES + 511) / 512;
    int base = t * CHUNK;
    int s = 0;
    for (int i = 0; i < CHUNK; i++) {
        int idx = base + i;
        if (idx < N_NODES) s += deg[idx];
    }
    sdata[t] = s;
    __syncthreads();
    for (int off = 1; off < 512; off <<= 1) {
        int other = (t >= off) ? sdata[t - off] : 0;
        __syncthreads();
        sdata[t] += other;
        __syncthreads();
    }
    int excl = sdata[t] - s;
    int run = excl;
    for (int i = 0; i < CHUNK; i++) {
        int idx = base + i;
        if (idx < N_NODES) {
            row_start[idx] = run;
            cursor[idx] = run;
            run += deg[idx];
        }
    }
    if (t == 511) row_start[N_NODES] = run;
}

__global__ void scatter_kernel(const int* __restrict__ ei, int* __restrict__ cursor,
                               int* __restrict__ csr_src, int* __restrict__ slot) {
    int e = blockIdx.x * 256 + threadIdx.x;
    if (e < N_EDGES) {
        int d = ei[N_EDGES + e];
        int pos = atomicAdd(&cursor[d], 1);
        csr_src[pos] = ei[e];
        slot[e] = pos;
    }
}

__global__ void gstart_kernel(const int* __restrict__ batch, int* __restrict__ gstart) {
    int n = blockIdx.x * 256 + threadIdx.x;
    if (n >= N_NODES) return;
    int b = batch[n];
    int bprev = (n == 0) ? -1 : batch[n - 1];
    for (int g = bprev + 1; g <= b; g++) gstart[g] = n;
    if (n == N_NODES - 1)
        for (int g = b + 1; g <= N_GRAPHS; g++) gstart[g] = N_NODES;
}

// x[N][739] fp32 -> xh[N][768] fp16, zero-padded.
__global__ __launch_bounds__(256)
void convert_x(const float* __restrict__ x, _Float16* __restrict__ xh) {
    int n = blockIdx.x;
    int k = blockIdx.y * 256 + threadIdx.x;
    xh[(size_t)n * KPAD_DENSE + k] = (k < IN_DIMV) ? (_Float16)x[(size_t)n * IN_DIMV + k]
                                                   : (_Float16)0.f;
}

// Transpose+convert W[K][256] fp32 -> Wt[256][Kpad] fp16 (zero-padded k>=K).
__global__ __launch_bounds__(256)
void prep_weight(const float* __restrict__ W, _Float16* __restrict__ Wt, int K, int Kpad) {
    __shared__ float T[32][33];
    int kt = blockIdx.x, nt = blockIdx.y;
    int tid = threadIdx.x;
    int i = tid >> 5, j = tid & 31;
#pragma unroll
    for (int ii = 0; ii < 4; ii++) {
        int k = kt * 32 + i + ii * 8;
        T[i + ii * 8][j] = (k < K) ? W[(size_t)k * 256 + nt * 32 + j] : 0.f;
    }
    __syncthreads();
#pragma unroll
    for (int ii = 0; ii < 4; ii++) {
        int n = nt * 32 + i + ii * 8;
        Wt[(size_t)n * Kpad + kt * 32 + j] = (_Float16)T[j][i + ii * 8];
    }
}

// Same, batched over the 8 square layer weights (z<4: d1_w[z], else d2_w[z-4]).
__global__ __launch_bounds__(256)
void prep_weight_sq(const float* __restrict__ d1_w, const float* __restrict__ d2_w,
                    _Float16* __restrict__ Wt) {
    __shared__ float T[32][33];
    int kt = blockIdx.x, nt = blockIdx.y, z = blockIdx.z;
    const float* W = (z < 4) ? d1_w + (size_t)z * 65536 : d2_w + (size_t)(z - 4) * 65536;
    _Float16* O = Wt + (size_t)z * 65536;
    int tid = threadIdx.x;
    int i = tid >> 5, j = tid & 31;
#pragma unroll
    for (int ii = 0; ii < 4; ii++)
        T[i + ii * 8][j] = W[(size_t)(kt * 32 + i + ii * 8) * 256 + nt * 32 + j];
    __syncthreads();
#pragma unroll
    for (int ii = 0; ii < 4; ii++)
        O[(size_t)(nt * 32 + i + ii * 8) * 256 + kt * 32 + j] = (_Float16)T[j][i + ii * 8];
}

// C[M,256] = act(A @ W + bias), A fp16 [M][Kpad], Wt fp16 [256][Kpad], C fp16.
// fp32 accumulate in MFMA. Tile BM=64 BN=128 BK=32, 256 thr / 4 waves.
template <bool GELU>
__global__ __launch_bounds__(256)
void gemm_mfma(const _Float16* __restrict__ A, const _Float16* __restrict__ Bt,
               const float* __restrict__ bias, _Float16* __restrict__ C,
               int M, int Kpad) {
    __shared__ __align__(16) _Float16 As[64 * 40];
    __shared__ __align__(16) _Float16 Bs[128 * 40];
    int tid = threadIdx.x;
    int row0 = blockIdx.x * 64;
    int col0 = blockIdx.y * 128;
    int wave = tid >> 6, lane = tid & 63;
    int quad = lane >> 4, lrow = lane & 15;

    int ar = tid >> 2;        // 0..63
    int ak8 = (tid & 3) * 8;  // 0,8,16,24
    int bn = tid >> 1;        // 0..127
    int bh = (tid & 1) * 16;  // 0 or 16

    int arow = row0 + ar;
    if (arow >= M) arow = M - 1;  // clamp: safe reads, rows >= M never stored
    const _Float16* Arow = &A[(size_t)arow * Kpad];
    const _Float16* Brow = &Bt[(size_t)(col0 + bn) * Kpad];

    int ntiles = Kpad >> 5;

    uint4 a_raw, b_raw[2];
    a_raw = *(const uint4*)&Arow[ak8];
    b_raw[0] = *(const uint4*)&Brow[bh];
    b_raw[1] = *(const uint4*)&Brow[bh + 8];

    f32x4 acc[8];
#pragma unroll
    for (int t = 0; t < 8; t++) acc[t] = (f32x4){0.f, 0.f, 0.f, 0.f};

    for (int kt = 0; kt < ntiles; ++kt) {
        *(uint4*)&As[ar * 40 + ak8] = a_raw;
        *(uint4*)&Bs[bn * 40 + bh] = b_raw[0];
        *(uint4*)&Bs[bn * 40 + bh + 8] = b_raw[1];
        __syncthreads();

        if (kt + 1 < ntiles) {
            int k0 = (kt + 1) << 5;
            a_raw = *(const uint4*)&Arow[k0 + ak8];
            b_raw[0] = *(const uint4*)&Brow[k0 + bh];
            b_raw[1] = *(const uint4*)&Brow[k0 + bh + 8];
        }

        f16x8 af = *(const f16x8*)&As[(wave * 16 + lrow) * 40 + quad * 8];
#pragma unroll
        for (int t = 0; t < 8; t++) {
            f16x8 bf = *(const f16x8*)&Bs[(t * 16 + lrow) * 40 + quad * 8];
            acc[t] = __builtin_amdgcn_mfma_f32_16x16x32_f16(af, bf, acc[t], 0, 0, 0);
        }
        __syncthreads();
    }

    // C/D layout: col=lane&15, row=quad*4+reg (HW-verified)
    int orow = row0 + wave * 16 + quad * 4;
#pragma unroll
    for (int t = 0; t < 8; t++) {
        int col = col0 + t * 16 + lrow;
        float bv = bias[col];
#pragma unroll
        for (int r = 0; r < 4; r++) {
            int gr = orow + r;
            if (gr < M) {
                float v = acc[t][r] + bv;
                C[(size_t)gr * 256 + col] = (_Float16)(GELU ? gelu_exact(v) : v);
            }
        }
    }
}

// Per-node summaries from fp16 m: P1, P2, Q1, Q2 (12 floats/node)
__global__ __launch_bounds__(256)
void node_summary_kernel(const _Float16* __restrict__ m, const float* __restrict__ cw,
                         float* __restrict__ ns) {
    __shared__ __align__(16) float4 s_cw[512];
    int tid = threadIdx.x;
    for (int i = tid; i < 512; i += 256) s_cw[i] = *(const float4*)&cw[(size_t)i * 4];
    __syncthreads();
    int n = blockIdx.x * 4 + (tid >> 6);
    if (n >= N_NODES) return;
    int lane = tid & 63;
    f16x4 a4 = *(const f16x4*)&m[(size_t)n * CDIM + lane * 4];
    float av[4] = {(float)a4[0], (float)a4[1], (float)a4[2], (float)a4[3]};
    float Q1 = 0.f, Q2 = 0.f, P1[4] = {0, 0, 0, 0}, P2[4] = {0, 0, 0, 0};
#pragma unroll
    for (int j = 0; j < 4; j++) {
        Q1 += av[j];
        Q2 += av[j] * av[j];
        float4 c0 = s_cw[lane * 4 + j];
        float4 c1 = s_cw[256 + lane * 4 + j];
        P1[0] += av[j] * c0.x; P1[1] += av[j] * c0.y; P1[2] += av[j] * c0.z; P1[3] += av[j] * c0.w;
        P2[0] += av[j] * c1.x; P2[1] += av[j] * c1.y; P2[2] += av[j] * c1.z; P2[3] += av[j] * c1.w;
    }
#pragma unroll
    for (int off = 1; off < 64; off <<= 1) {
        Q1 += __shfl_xor(Q1, off, 64);
        Q2 += __shfl_xor(Q2, off, 64);
        P1[0] += __shfl_xor(P1[0], off, 64);
        P1[1] += __shfl_xor(P1[1], off, 64);
        P1[2] += __shfl_xor(P1[2], off, 64);
        P1[3] += __shfl_xor(P1[3], off, 64);
        P2[0] += __shfl_xor(P2[0], off, 64);
        P2[1] += __shfl_xor(P2[1], off, 64);
        P2[2] += __shfl_xor(P2[2], off, 64);
        P2[3] += __shfl_xor(P2[3], off, 64);
    }
    if (lane == 0) {
        float* p = &ns[(size_t)n * 12];
        *(float4*)p = make_float4(P1[0], P1[1], P1[2], P1[3]);
        *(float4*)(p + 4) = make_float4(P2[0], P2[1], P2[2], P2[3]);
        p[8] = Q1;
        p[9] = Q2;
    }
}

// One thread per edge: edge MLP from node summaries; writes w into CSR slot.
__global__ __launch_bounds__(256)
void edge_weight_kernel(const float* __restrict__ ns, const float* __restrict__ x_pos,
                        const int* __restrict__ ei, const float* __restrict__ cw,
                        const float* __restrict__ SgSb, const float* __restrict__ w1_b,
                        const float* __restrict__ ln2_g, const float* __restrict__ ln2_b,
                        const float* __restrict__ w2_w, const float* __restrict__ w2_b,
                        const int* __restrict__ slot, float* __restrict__ w_csr) {
    int e = blockIdx.x * 256 + threadIdx.x;
    if (e >= N_EDGES) return;
    int s = ei[e], d = ei[N_EDGES + e];
    const float* nss = &ns[(size_t)s * 12];
    const float* nsd = &ns[(size_t)d * 12];
    float4 p1 = *(const float4*)nss;
    float4 p2 = *(const float4*)(nsd + 4);
    float S1 = nss[8] + nsd[8];
    float S2 = nss[9] + nsd[9];
    float D[4] = {p1.x + p2.x, p1.y + p2.y, p1.z + p2.z, p1.w + p2.w};
    float ps[6];
    ps[0] = x_pos[(size_t)s * 3 + 0];
    ps[1] = x_pos[(size_t)s * 3 + 1];
    ps[2] = x_pos[(size_t)s * 3 + 2];
    ps[3] = x_pos[(size_t)d * 3 + 0];
    ps[4] = x_pos[(size_t)d * 3 + 1];
    ps[5] = x_pos[(size_t)d * 3 + 2];
#pragma unroll
    for (int k = 0; k < 6; k++) {
        S1 += ps[k];
        S2 += ps[k] * ps[k];
        float4 c = *(const float4*)&cw[(size_t)(512 + k) * 4];
        D[0] += ps[k] * c.x; D[1] += ps[k] * c.y; D[2] += ps[k] * c.z; D[3] += ps[k] * c.w;
    }
    const float inv = 1.f / 518.f;
    float mu = S1 * inv;
    float var = fmaf(-mu, mu, S2 * inv);
    float rstd = rsqrtf(var + LN_EPS);
    float t[4];
#pragma unroll
    for (int c = 0; c < 4; c++)
        t[c] = gelu_exact(rstd * (D[c] - mu * SgSb[c]) + SgSb[4 + c] + w1_b[c]);
    float mu2 = 0.25f * (t[0] + t[1] + t[2] + t[3]);
    float var2 = 0.25f * ((t[0] - mu2) * (t[0] - mu2) + (t[1] - mu2) * (t[1] - mu2) +
                          (t[2] - mu2) * (t[2] - mu2) + (t[3] - mu2) * (t[3] - mu2));
    float r2 = rsqrtf(var2 + LN_EPS);
    float z = w2_b[0];
#pragma unroll
    for (int c = 0; c < 4; c++)
        z += ((t[c] - mu2) * r2 * ln2_g[c] + ln2_b[c]) * w2_w[c];
    w_csr[slot[e]] = 1.f / (1.f + expf(-z));
}

// CSR SpMM over fp16 m: agg[n] = sum_j w_csr[j] * m[csr_src[j]], fp32 acc, fp16 out.
__global__ __launch_bounds__(256)
void agg_kernel(const _Float16* __restrict__ m, const int* __restrict__ csr_src,
                const float* __restrict__ w_csr, const int* __restrict__ row_start,
                _Float16* __restrict__ agg) {
    int n = blockIdx.x * 4 + (threadIdx.x >> 6);
    if (n >= N_NODES) return;
    int lane = threadIdx.x & 63;
    int beg = row_start[n], end = row_start[n + 1];
    float a0 = 0.f, a1 = 0.f, a2 = 0.f, a3 = 0.f;
    for (int j = beg; j < end; j++) {
        int s = csr_src[j];
        float w = w_csr[j];
        f16x4 v = *(const f16x4*)&m[(size_t)s * CDIM + lane * 4];
        a0 = fmaf(w, (float)v[0], a0);
        a1 = fmaf(w, (float)v[1], a1);
        a2 = fmaf(w, (float)v[2], a2);
        a3 = fmaf(w, (float)v[3], a3);
    }
    f16x4 o;
    o[0] = (_Float16)a0; o[1] = (_Float16)a1; o[2] = (_Float16)a2; o[3] = (_Float16)a3;
    *(f16x4*)&agg[(size_t)n * CDIM + lane * 4] = o;
}

__global__ __launch_bounds__(256)
void node_dot_kernel(const _Float16* __restrict__ h, const float* __restrict__ head_w,
                     float* __restrict__ sdot) {
    int n = blockIdx.x * 4 + (threadIdx.x >> 6);
    if (n >= N_NODES) return;
    int lane = threadIdx.x & 63;
    f16x4 v = *(const f16x4*)&h[(size_t)n * CDIM + lane * 4];
    float4 w = *(const float4*)&head_w[lane * 4];
    float p = (float)v[0] * w.x + (float)v[1] * w.y + (float)v[2] * w.z + (float)v[3] * w.w;
#pragma unroll
    for (int off = 1; off < 64; off <<= 1) p += __shfl_xor(p, off, 64);
    if (lane == 0) sdot[n] = p;
}

__global__ __launch_bounds__(256)
void final_head_kernel(const float* __restrict__ sdot, const int* __restrict__ gstart,
                       const float* __restrict__ head_b, float* __restrict__ out) {
    int g = blockIdx.x;
    int t = threadIdx.x;
    int beg = gstart[g], end = gstart[g + 1];
    float s = 0.f;
    for (int i = beg + t; i < end; i += 256) s += sdot[i];
    __shared__ float red[256];
    red[t] = s;
    __syncthreads();
    for (int k = 128; k > 0; k >>= 1) {
        if (t < k) red[t] += red[t + k];
        __syncthreads();
    }
    if (t == 0) out[g] = red[0] / fmaxf((float)(end - beg), 1.f) + head_b[0];
}

extern "C" void kernel_launch(void* const* d_in, const int* in_sizes, int n_in,
                              void* d_out, int out_size, void* d_ws, size_t ws_size,
                              hipStream_t stream) {
    const float* x       = (const float*)d_in[0];
    const float* x_pos   = (const float*)d_in[1];
    const int*   ei      = (const int*)d_in[2];
    const int*   batch   = (const int*)d_in[3];
    const float* dense_w = (const float*)d_in[4];
    const float* dense_b = (const float*)d_in[5];
    const float* d1_w    = (const float*)d_in[6];
    const float* d1_b    = (const float*)d_in[7];
    const float* ln1_g   = (const float*)d_in[8];
    const float* ln1_b   = (const float*)d_in[9];
    const float* w1_w    = (const float*)d_in[10];
    const float* w1_b    = (const float*)d_in[11];
    const float* ln2_g   = (const float*)d_in[12];
    const float* ln2_b   = (const float*)d_in[13];
    const float* w2_w    = (const float*)d_in[14];
    const float* w2_b    = (const float*)d_in[15];
    const float* d2_w    = (const float*)d_in[16];
    const float* d2_b    = (const float*)d_in[17];
    const float* head_w  = (const float*)d_in[18];
    const float* head_b  = (const float*)d_in[19];
    float* out = (float*)d_out;

    _Float16* hbuf0 = (_Float16*)d_ws;                          // [N][256] fp16
    _Float16* hbuf1 = hbuf0 + (size_t)N_NODES * CDIM;           // [N][256] fp16
    _Float16* xh    = hbuf1 + (size_t)N_NODES * CDIM;           // [N][768] fp16
    _Float16* wt_dense = xh + (size_t)N_NODES * KPAD_DENSE;     // [256][768] fp16
    _Float16* wt_sq    = wt_dense + (size_t)256 * KPAD_DENSE;   // [8][256][256] fp16
    float* cw    = (float*)(wt_sq + (size_t)8 * 256 * 256);     // [L][518][4]
    float* SgSb  = cw + (size_t)NLAYERS * ED_DIM * 4;           // [L][8]
    float* ns    = SgSb + NLAYERS * 8;                          // [N][12]
    float* sdot  = ns + (size_t)N_NODES * 12;                   // [N]
    float* w_csr = sdot + N_NODES;                              // [E]
    int* gstart    = (int*)(w_csr + N_EDGES);                   // [33]
    int* deg       = gstart + N_GRAPHS + 1;                     // [N]
    int* row_start = deg + N_NODES;                             // [N+1]
    int* cursor    = row_start + N_NODES + 1;                   // [N]
    int* csr_src   = cursor + N_NODES;                          // [E]
    int* slot      = csr_src + N_EDGES;                         // [E]

    precompute_kernel<<<NLAYERS, 256, 0, stream>>>(ln1_g, ln1_b, w1_w, cw, SgSb);

    zero_kernel<<<80, 256, 0, stream>>>((float*)deg, N_NODES);
    hist_kernel<<<(N_EDGES + 255) / 256, 256, 0, stream>>>(ei, deg);
    scan_kernel<<<1, 512, 0, stream>>>(deg, row_start, cursor);
    scatter_kernel<<<(N_EDGES + 255) / 256, 256, 0, stream>>>(ei, cursor, csr_src, slot);
    gstart_kernel<<<(N_NODES + 255) / 256, 256, 0, stream>>>(batch, gstart);

    convert_x<<<dim3(N_NODES, 3), 256, 0, stream>>>(x, xh);
    prep_weight<<<dim3(24, 8), 256, 0, stream>>>(dense_w, wt_dense, IN_DIMV, KPAD_DENSE);
    prep_weight_sq<<<dim3(8, 8, 8), 256, 0, stream>>>(d1_w, d2_w, wt_sq);

    const dim3 GGRID((N_NODES + 63) / 64, 2);
    gemm_mfma<false><<<GGRID, 256, 0, stream>>>(xh, wt_dense, dense_b, hbuf0,
                                                N_NODES, KPAD_DENSE);

    _Float16* h = hbuf0;
    _Float16* other = hbuf1;
    for (int l = 0; l < NLAYERS; l++) {
        gemm_mfma<true><<<GGRID, 256, 0, stream>>>(
            h, wt_sq + (size_t)l * 65536, d1_b + l * CDIM, other, N_NODES, CDIM);
        node_summary_kernel<<<(N_NODES + 3) / 4, 256, 0, stream>>>(
            other, cw + (size_t)l * ED_DIM * 4, ns);
        edge_weight_kernel<<<(N_EDGES + 255) / 256, 256, 0, stream>>>(
            ns, x_pos, ei, cw + (size_t)l * ED_DIM * 4, SgSb + l * 8, w1_b + l * 4,
            ln2_g + l * 4, ln2_b + l * 4, w2_w + l * 4, w2_b + l, slot, w_csr);
        agg_kernel<<<(N_NODES + 3) / 4, 256, 0, stream>>>(other, csr_src, w_csr, row_start, h);
        gemm_mfma<true><<<GGRID, 256, 0, stream>>>(
            h, wt_sq + (size_t)(4 + l) * 65536, d2_b + l * CDIM, other, N_NODES, CDIM);
        _Float16* tmp = h; h = other; other = tmp;
    }

    node_dot_kernel<<<(N_NODES + 3) / 4, 256, 0, stream>>>(h, head_w, sdot);
    final_head_kernel<<<N_GRAPHS, 256, 0, stream>>>(sdot, gstart, head_b, out);
}

// Round 8
// 659.314 us; speedup vs baseline: 8.3222x; 1.1935x over previous
//
#include <hip/hip_runtime.h>
#include <math.h>

#define N_NODES 20000
#define N_EDGES 320000
#define N_GRAPHS 32
#define CDIM 256
#define IN_DIMV 739
#define KPAD_DENSE 768
#define ED_DIM 518
#define NLAYERS 4
#define LN_EPS 1e-5f

typedef _Float16 f16x8 __attribute__((ext_vector_type(8)));
typedef _Float16 f16x4 __attribute__((ext_vector_type(4)));
typedef float f32x4 __attribute__((ext_vector_type(4)));

__device__ __forceinline__ float gelu_exact(float x) {
    return 0.5f * x * (1.f + erff(x * 0.7071067811865475f));
}

__global__ void zero_kernel(float* __restrict__ p, int n) {
    int i = blockIdx.x * blockDim.x + threadIdx.x;
    int stride = gridDim.x * blockDim.x;
    for (; i < n; i += stride) p[i] = 0.f;
}

// Precompute per-layer: cw[i][c] = ln1_g[i] * w1_w[i][c]
__global__ void precompute_kernel(const float* __restrict__ ln1_g, const float* __restrict__ ln1_b,
                                  const float* __restrict__ w1_w,
                                  float* __restrict__ cw, float* __restrict__ SgSb) {
    int l = blockIdx.x, tid = threadIdx.x;
    float sg[4] = {0, 0, 0, 0}, sb[4] = {0, 0, 0, 0};
    for (int i = tid; i < ED_DIM; i += 256) {
        float g = ln1_g[l * ED_DIM + i];
        float b = ln1_b[l * ED_DIM + i];
        float4 w = *(const float4*)&w1_w[(size_t)(l * ED_DIM + i) * 4];
        float4 c = make_float4(g * w.x, g * w.y, g * w.z, g * w.w);
        *(float4*)&cw[(size_t)(l * ED_DIM + i) * 4] = c;
        sg[0] += c.x; sg[1] += c.y; sg[2] += c.z; sg[3] += c.w;
        sb[0] += b * w.x; sb[1] += b * w.y; sb[2] += b * w.z; sb[3] += b * w.w;
    }
    __shared__ float red[256][8];
    for (int c = 0; c < 4; c++) { red[tid][c] = sg[c]; red[tid][4 + c] = sb[c]; }
    __syncthreads();
    for (int s = 128; s > 0; s >>= 1) {
        if (tid < s)
            for (int c = 0; c < 8; c++) red[tid][c] += red[tid + s][c];
        __syncthreads();
    }
    if (tid < 8) SgSb[l * 8 + tid] = red[0][tid];
}

// ---- CSR build ----
__global__ void hist_kernel(const int* __restrict__ ei, int* __restrict__ deg) {
    int e = blockIdx.x * 256 + threadIdx.x;
    if (e < N_EDGES) atomicAdd(&deg[ei[N_EDGES + e]], 1);
}

__global__ __launch_bounds__(512)
void scan_kernel(const int* __restrict__ deg, int* __restrict__ row_start,
                 int* __restrict__ cursor) {
    __shared__ int sdata[512];
    int t = threadIdx.x;
    const int CHUNK = (N_NODES + 511) / 512;
    int base = t * CHUNK;
    int s = 0;
    for (int i = 0; i < CHUNK; i++) {
        int idx = base + i;
        if (idx < N_NODES) s += deg[idx];
    }
    sdata[t] = s;
    __syncthreads();
    for (int off = 1; off < 512; off <<= 1) {
        int other = (t >= off) ? sdata[t - off] : 0;
        __syncthreads();
        sdata[t] += other;
        __syncthreads();
    }
    int excl = sdata[t] - s;
    int run = excl;
    for (int i = 0; i < CHUNK; i++) {
        int idx = base + i;
        if (idx < N_NODES) {
            row_start[idx] = run;
            cursor[idx] = run;
            run += deg[idx];
        }
    }
    if (t == 511) row_start[N_NODES] = run;
}

__global__ void scatter_kernel(const int* __restrict__ ei, int* __restrict__ cursor,
                               int* __restrict__ csr_src, int* __restrict__ slot) {
    int e = blockIdx.x * 256 + threadIdx.x;
    if (e < N_EDGES) {
        int d = ei[N_EDGES + e];
        int pos = atomicAdd(&cursor[d], 1);
        csr_src[pos] = ei[e];
        slot[e] = pos;
    }
}

__global__ void gstart_kernel(const int* __restrict__ batch, int* __restrict__ gstart) {
    int n = blockIdx.x * 256 + threadIdx.x;
    if (n >= N_NODES) return;
    int b = batch[n];
    int bprev = (n == 0) ? -1 : batch[n - 1];
    for (int g = bprev + 1; g <= b; g++) gstart[g] = n;
    if (n == N_NODES - 1)
        for (int g = b + 1; g <= N_GRAPHS; g++) gstart[g] = N_NODES;
}

// x[N][739] fp32 -> xh[N][768] fp16, zero-padded.
__global__ __launch_bounds__(256)
void convert_x(const float* __restrict__ x, _Float16* __restrict__ xh) {
    int n = blockIdx.x;
    int k = blockIdx.y * 256 + threadIdx.x;
    xh[(size_t)n * KPAD_DENSE + k] = (k < IN_DIMV) ? (_Float16)x[(size_t)n * IN_DIMV + k]
                                                   : (_Float16)0.f;
}

// Transpose+convert W[K][256] fp32 -> Wt[256][Kpad] fp16 (zero-padded k>=K).
__global__ __launch_bounds__(256)
void prep_weight(const float* __restrict__ W, _Float16* __restrict__ Wt, int K, int Kpad) {
    __shared__ float T[32][33];
    int kt = blockIdx.x, nt = blockIdx.y;
    int tid = threadIdx.x;
    int i = tid >> 5, j = tid & 31;
#pragma unroll
    for (int ii = 0; ii < 4; ii++) {
        int k = kt * 32 + i + ii * 8;
        T[i + ii * 8][j] = (k < K) ? W[(size_t)k * 256 + nt * 32 + j] : 0.f;
    }
    __syncthreads();
#pragma unroll
    for (int ii = 0; ii < 4; ii++) {
        int n = nt * 32 + i + ii * 8;
        Wt[(size_t)n * Kpad + kt * 32 + j] = (_Float16)T[j][i + ii * 8];
    }
}

// Same, batched over the 8 square layer weights (z<4: d1_w[z], else d2_w[z-4]).
__global__ __launch_bounds__(256)
void prep_weight_sq(const float* __restrict__ d1_w, const float* __restrict__ d2_w,
                    _Float16* __restrict__ Wt) {
    __shared__ float T[32][33];
    int kt = blockIdx.x, nt = blockIdx.y, z = blockIdx.z;
    const float* W = (z < 4) ? d1_w + (size_t)z * 65536 : d2_w + (size_t)(z - 4) * 65536;
    _Float16* O = Wt + (size_t)z * 65536;
    int tid = threadIdx.x;
    int i = tid >> 5, j = tid & 31;
#pragma unroll
    for (int ii = 0; ii < 4; ii++)
        T[i + ii * 8][j] = W[(size_t)(kt * 32 + i + ii * 8) * 256 + nt * 32 + j];
    __syncthreads();
#pragma unroll
    for (int ii = 0; ii < 4; ii++)
        O[(size_t)(nt * 32 + i + ii * 8) * 256 + kt * 32 + j] = (_Float16)T[j][i + ii * 8];
}

// C[M,256] = act(A @ W + bias), A fp16 [M][Kpad], Wt fp16 [256][Kpad], C fp16.
// Tile BM=32, BN=128, BK=64; 256 thr / 4 waves (2 row-groups x 2 col-halves).
// Grid (625, 2) = 1250 blocks for TLP; LDS 23 KB -> 6 blocks/CU ceiling.
// M == 20000 == 625*32 exactly: no row bounds checks anywhere.
template <bool GELU>
__global__ __launch_bounds__(256)
void gemm_mfma(const _Float16* __restrict__ A, const _Float16* __restrict__ Bt,
               const float* __restrict__ bias, _Float16* __restrict__ C,
               int Kpad) {
    __shared__ __align__(16) _Float16 As[32 * 72];   // rows padded to 72 el (144 B)
    __shared__ __align__(16) _Float16 Bs[128 * 72];
    int tid = threadIdx.x;
    int row0 = blockIdx.x * 32;
    int col0 = blockIdx.y * 128;
    int wave = tid >> 6, lane = tid & 63;
    int quad = lane >> 4, lrow = lane & 15;
    int wrow = wave >> 1, wcol = wave & 1;

    int ar = tid >> 3, ak8 = (tid & 7) * 8;   // A stage: 32 rows x 64 el, 8 el/thread
    int br = tid >> 1, bh = (tid & 1) * 32;   // B stage: 128 rows x 64 el, 32 el/thread

    const _Float16* Arow = &A[(size_t)(row0 + ar) * Kpad];
    const _Float16* Brow = &Bt[(size_t)(col0 + br) * Kpad];

    int ntiles = Kpad >> 6;
    uint4 a_raw = *(const uint4*)&Arow[ak8];
    uint4 b_raw0 = *(const uint4*)&Brow[bh];
    uint4 b_raw1 = *(const uint4*)&Brow[bh + 8];
    uint4 b_raw2 = *(const uint4*)&Brow[bh + 16];
    uint4 b_raw3 = *(const uint4*)&Brow[bh + 24];

    f32x4 acc[4];
#pragma unroll
    for (int t = 0; t < 4; t++) acc[t] = (f32x4){0.f, 0.f, 0.f, 0.f};

    for (int kt = 0; kt < ntiles; ++kt) {
        *(uint4*)&As[ar * 72 + ak8] = a_raw;
        *(uint4*)&Bs[br * 72 + bh] = b_raw0;
        *(uint4*)&Bs[br * 72 + bh + 8] = b_raw1;
        *(uint4*)&Bs[br * 72 + bh + 16] = b_raw2;
        *(uint4*)&Bs[br * 72 + bh + 24] = b_raw3;
        __syncthreads();

        if (kt + 1 < ntiles) {
            int k0 = (kt + 1) << 6;
            a_raw = *(const uint4*)&Arow[k0 + ak8];
            b_raw0 = *(const uint4*)&Brow[k0 + bh];
            b_raw1 = *(const uint4*)&Brow[k0 + bh + 8];
            b_raw2 = *(const uint4*)&Brow[k0 + bh + 16];
            b_raw3 = *(const uint4*)&Brow[k0 + bh + 24];
        }

#pragma unroll
        for (int h = 0; h < 2; h++) {
            f16x8 af = *(const f16x8*)&As[(wrow * 16 + lrow) * 72 + h * 32 + quad * 8];
#pragma unroll
            for (int t = 0; t < 4; t++) {
                f16x8 bf = *(const f16x8*)&Bs[((wcol * 4 + t) * 16 + lrow) * 72 + h * 32 + quad * 8];
                acc[t] = __builtin_amdgcn_mfma_f32_16x16x32_f16(af, bf, acc[t], 0, 0, 0);
            }
        }
        __syncthreads();
    }

    // C/D layout: col=lane&15, row=quad*4+reg (HW-verified)
    int orow = row0 + wrow * 16 + quad * 4;
#pragma unroll
    for (int t = 0; t < 4; t++) {
        int col = col0 + (wcol * 4 + t) * 16 + lrow;
        float bv = bias[col];
#pragma unroll
        for (int r = 0; r < 4; r++) {
            float v = acc[t][r] + bv;
            C[(size_t)(orow + r) * 256 + col] = (_Float16)(GELU ? gelu_exact(v) : v);
        }
    }
}

// Per-node summaries from fp16 m: P1, P2, Q1, Q2 (12 floats/node)
__global__ __launch_bounds__(256)
void node_summary_kernel(const _Float16* __restrict__ m, const float* __restrict__ cw,
                         float* __restrict__ ns) {
    __shared__ __align__(16) float4 s_cw[512];
    int tid = threadIdx.x;
    for (int i = tid; i < 512; i += 256) s_cw[i] = *(const float4*)&cw[(size_t)i * 4];
    __syncthreads();
    int n = blockIdx.x * 4 + (tid >> 6);
    if (n >= N_NODES) return;
    int lane = tid & 63;
    f16x4 a4 = *(const f16x4*)&m[(size_t)n * CDIM + lane * 4];
    float av[4] = {(float)a4[0], (float)a4[1], (float)a4[2], (float)a4[3]};
    float Q1 = 0.f, Q2 = 0.f, P1[4] = {0, 0, 0, 0}, P2[4] = {0, 0, 0, 0};
#pragma unroll
    for (int j = 0; j < 4; j++) {
        Q1 += av[j];
        Q2 += av[j] * av[j];
        float4 c0 = s_cw[lane * 4 + j];
        float4 c1 = s_cw[256 + lane * 4 + j];
        P1[0] += av[j] * c0.x; P1[1] += av[j] * c0.y; P1[2] += av[j] * c0.z; P1[3] += av[j] * c0.w;
        P2[0] += av[j] * c1.x; P2[1] += av[j] * c1.y; P2[2] += av[j] * c1.z; P2[3] += av[j] * c1.w;
    }
#pragma unroll
    for (int off = 1; off < 64; off <<= 1) {
        Q1 += __shfl_xor(Q1, off, 64);
        Q2 += __shfl_xor(Q2, off, 64);
        P1[0] += __shfl_xor(P1[0], off, 64);
        P1[1] += __shfl_xor(P1[1], off, 64);
        P1[2] += __shfl_xor(P1[2], off, 64);
        P1[3] += __shfl_xor(P1[3], off, 64);
        P2[0] += __shfl_xor(P2[0], off, 64);
        P2[1] += __shfl_xor(P2[1], off, 64);
        P2[2] += __shfl_xor(P2[2], off, 64);
        P2[3] += __shfl_xor(P2[3], off, 64);
    }
    if (lane == 0) {
        float* p = &ns[(size_t)n * 12];
        *(float4*)p = make_float4(P1[0], P1[1], P1[2], P1[3]);
        *(float4*)(p + 4) = make_float4(P2[0], P2[1], P2[2], P2[3]);
        p[8] = Q1;
        p[9] = Q2;
    }
}

// One thread per edge: edge MLP from node summaries; writes w into CSR slot.
__global__ __launch_bounds__(256)
void edge_weight_kernel(const float* __restrict__ ns, const float* __restrict__ x_pos,
                        const int* __restrict__ ei, const float* __restrict__ cw,
                        const float* __restrict__ SgSb, const float* __restrict__ w1_b,
                        const float* __restrict__ ln2_g, const float* __restrict__ ln2_b,
                        const float* __restrict__ w2_w, const float* __restrict__ w2_b,
                        const int* __restrict__ slot, float* __restrict__ w_csr) {
    int e = blockIdx.x * 256 + threadIdx.x;
    if (e >= N_EDGES) return;
    int s = ei[e], d = ei[N_EDGES + e];
    const float* nss = &ns[(size_t)s * 12];
    const float* nsd = &ns[(size_t)d * 12];
    float4 p1 = *(const float4*)nss;
    float4 p2 = *(const float4*)(nsd + 4);
    float S1 = nss[8] + nsd[8];
    float S2 = nss[9] + nsd[9];
    float D[4] = {p1.x + p2.x, p1.y + p2.y, p1.z + p2.z, p1.w + p2.w};
    float ps[6];
    ps[0] = x_pos[(size_t)s * 3 + 0];
    ps[1] = x_pos[(size_t)s * 3 + 1];
    ps[2] = x_pos[(size_t)s * 3 + 2];
    ps[3] = x_pos[(size_t)d * 3 + 0];
    ps[4] = x_pos[(size_t)d * 3 + 1];
    ps[5] = x_pos[(size_t)d * 3 + 2];
#pragma unroll
    for (int k = 0; k < 6; k++) {
        S1 += ps[k];
        S2 += ps[k] * ps[k];
        float4 c = *(const float4*)&cw[(size_t)(512 + k) * 4];
        D[0] += ps[k] * c.x; D[1] += ps[k] * c.y; D[2] += ps[k] * c.z; D[3] += ps[k] * c.w;
    }
    const float inv = 1.f / 518.f;
    float mu = S1 * inv;
    float var = fmaf(-mu, mu, S2 * inv);
    float rstd = rsqrtf(var + LN_EPS);
    float t[4];
#pragma unroll
    for (int c = 0; c < 4; c++)
        t[c] = gelu_exact(rstd * (D[c] - mu * SgSb[c]) + SgSb[4 + c] + w1_b[c]);
    float mu2 = 0.25f * (t[0] + t[1] + t[2] + t[3]);
    float var2 = 0.25f * ((t[0] - mu2) * (t[0] - mu2) + (t[1] - mu2) * (t[1] - mu2) +
                          (t[2] - mu2) * (t[2] - mu2) + (t[3] - mu2) * (t[3] - mu2));
    float r2 = rsqrtf(var2 + LN_EPS);
    float z = w2_b[0];
#pragma unroll
    for (int c = 0; c < 4; c++)
        z += ((t[c] - mu2) * r2 * ln2_g[c] + ln2_b[c]) * w2_w[c];
    w_csr[slot[e]] = 1.f / (1.f + expf(-z));
}

// CSR SpMM over fp16 m: agg[n] = sum_j w_csr[j] * m[csr_src[j]], fp32 acc, fp16 out.
__global__ __launch_bounds__(256)
void agg_kernel(const _Float16* __restrict__ m, const int* __restrict__ csr_src,
                const float* __restrict__ w_csr, const int* __restrict__ row_start,
                _Float16* __restrict__ agg) {
    int n = blockIdx.x * 4 + (threadIdx.x >> 6);
    if (n >= N_NODES) return;
    int lane = threadIdx.x & 63;
    int beg = row_start[n], end = row_start[n + 1];
    float a0 = 0.f, a1 = 0.f, a2 = 0.f, a3 = 0.f;
    for (int j = beg; j < end; j++) {
        int s = csr_src[j];
        float w = w_csr[j];
        f16x4 v = *(const f16x4*)&m[(size_t)s * CDIM + lane * 4];
        a0 = fmaf(w, (float)v[0], a0);
        a1 = fmaf(w, (float)v[1], a1);
        a2 = fmaf(w, (float)v[2], a2);
        a3 = fmaf(w, (float)v[3], a3);
    }
    f16x4 o;
    o[0] = (_Float16)a0; o[1] = (_Float16)a1; o[2] = (_Float16)a2; o[3] = (_Float16)a3;
    *(f16x4*)&agg[(size_t)n * CDIM + lane * 4] = o;
}

__global__ __launch_bounds__(256)
void node_dot_kernel(const _Float16* __restrict__ h, const float* __restrict__ head_w,
                     float* __restrict__ sdot) {
    int n = blockIdx.x * 4 + (threadIdx.x >> 6);
    if (n >= N_NODES) return;
    int lane = threadIdx.x & 63;
    f16x4 v = *(const f16x4*)&h[(size_t)n * CDIM + lane * 4];
    float4 w = *(const float4*)&head_w[lane * 4];
    float p = (float)v[0] * w.x + (float)v[1] * w.y + (float)v[2] * w.z + (float)v[3] * w.w;
#pragma unroll
    for (int off = 1; off < 64; off <<= 1) p += __shfl_xor(p, off, 64);
    if (lane == 0) sdot[n] = p;
}

__global__ __launch_bounds__(256)
void final_head_kernel(const float* __restrict__ sdot, const int* __restrict__ gstart,
                       const float* __restrict__ head_b, float* __restrict__ out) {
    int g = blockIdx.x;
    int t = threadIdx.x;
    int beg = gstart[g], end = gstart[g + 1];
    float s = 0.f;
    for (int i = beg + t; i < end; i += 256) s += sdot[i];
    __shared__ float red[256];
    red[t] = s;
    __syncthreads();
    for (int k = 128; k > 0; k >>= 1) {
        if (t < k) red[t] += red[t + k];
        __syncthreads();
    }
    if (t == 0) out[g] = red[0] / fmaxf((float)(end - beg), 1.f) + head_b[0];
}

extern "C" void kernel_launch(void* const* d_in, const int* in_sizes, int n_in,
                              void* d_out, int out_size, void* d_ws, size_t ws_size,
                              hipStream_t stream) {
    const float* x       = (const float*)d_in[0];
    const float* x_pos   = (const float*)d_in[1];
    const int*   ei      = (const int*)d_in[2];
    const int*   batch   = (const int*)d_in[3];
    const float* dense_w = (const float*)d_in[4];
    const float* dense_b = (const float*)d_in[5];
    const float* d1_w    = (const float*)d_in[6];
    const float* d1_b    = (const float*)d_in[7];
    const float* ln1_g   = (const float*)d_in[8];
    const float* ln1_b   = (const float*)d_in[9];
    const float* w1_w    = (const float*)d_in[10];
    const float* w1_b    = (const float*)d_in[11];
    const float* ln2_g   = (const float*)d_in[12];
    const float* ln2_b   = (const float*)d_in[13];
    const float* w2_w    = (const float*)d_in[14];
    const float* w2_b    = (const float*)d_in[15];
    const float* d2_w    = (const float*)d_in[16];
    const float* d2_b    = (const float*)d_in[17];
    const float* head_w  = (const float*)d_in[18];
    const float* head_b  = (const float*)d_in[19];
    float* out = (float*)d_out;

    _Float16* hbuf0 = (_Float16*)d_ws;                          // [N][256] fp16
    _Float16* hbuf1 = hbuf0 + (size_t)N_NODES * CDIM;           // [N][256] fp16
    _Float16* xh    = hbuf1 + (size_t)N_NODES * CDIM;           // [N][768] fp16
    _Float16* wt_dense = xh + (size_t)N_NODES * KPAD_DENSE;     // [256][768] fp16
    _Float16* wt_sq    = wt_dense + (size_t)256 * KPAD_DENSE;   // [8][256][256] fp16
    float* cw    = (float*)(wt_sq + (size_t)8 * 256 * 256);     // [L][518][4]
    float* SgSb  = cw + (size_t)NLAYERS * ED_DIM * 4;           // [L][8]
    float* ns    = SgSb + NLAYERS * 8;                          // [N][12]
    float* sdot  = ns + (size_t)N_NODES * 12;                   // [N]
    float* w_csr = sdot + N_NODES;                              // [E]
    int* gstart    = (int*)(w_csr + N_EDGES);                   // [33]
    int* deg       = gstart + N_GRAPHS + 1;                     // [N]
    int* row_start = deg + N_NODES;                             // [N+1]
    int* cursor    = row_start + N_NODES + 1;                   // [N]
    int* csr_src   = cursor + N_NODES;                          // [E]
    int* slot      = csr_src + N_EDGES;                         // [E]

    precompute_kernel<<<NLAYERS, 256, 0, stream>>>(ln1_g, ln1_b, w1_w, cw, SgSb);

    zero_kernel<<<80, 256, 0, stream>>>((float*)deg, N_NODES);
    hist_kernel<<<(N_EDGES + 255) / 256, 256, 0, stream>>>(ei, deg);
    scan_kernel<<<1, 512, 0, stream>>>(deg, row_start, cursor);
    scatter_kernel<<<(N_EDGES + 255) / 256, 256, 0, stream>>>(ei, cursor, csr_src, slot);
    gstart_kernel<<<(N_NODES + 255) / 256, 256, 0, stream>>>(batch, gstart);

    convert_x<<<dim3(N_NODES, 3), 256, 0, stream>>>(x, xh);
    prep_weight<<<dim3(24, 8), 256, 0, stream>>>(dense_w, wt_dense, IN_DIMV, KPAD_DENSE);
    prep_weight_sq<<<dim3(8, 8, 8), 256, 0, stream>>>(d1_w, d2_w, wt_sq);

    const dim3 GGRID(N_NODES / 32, 2);  // (625, 2) = 1250 blocks
    gemm_mfma<false><<<GGRID, 256, 0, stream>>>(xh, wt_dense, dense_b, hbuf0, KPAD_DENSE);

    _Float16* h = hbuf0;
    _Float16* other = hbuf1;
    for (int l = 0; l < NLAYERS; l++) {
        gemm_mfma<true><<<GGRID, 256, 0, stream>>>(
            h, wt_sq + (size_t)l * 65536, d1_b + l * CDIM, other, CDIM);
        node_summary_kernel<<<(N_NODES + 3) / 4, 256, 0, stream>>>(
            other, cw + (size_t)l * ED_DIM * 4, ns);
        edge_weight_kernel<<<(N_EDGES + 255) / 256, 256, 0, stream>>>(
            ns, x_pos, ei, cw + (size_t)l * ED_DIM * 4, SgSb + l * 8, w1_b + l * 4,
            ln2_g + l * 4, ln2_b + l * 4, w2_w + l * 4, w2_b + l, slot, w_csr);
        agg_kernel<<<(N_NODES + 3) / 4, 256, 0, stream>>>(other, csr_src, w_csr, row_start, h);
        gemm_mfma<true><<<GGRID, 256, 0, stream>>>(
            h, wt_sq + (size_t)(4 + l) * 65536, d2_b + l * CDIM, other, CDIM);
        _Float16* tmp = h; h = other; other = tmp;
    }

    node_dot_kernel<<<(N_NODES + 3) / 4, 256, 0, stream>>>(h, head_w, sdot);
    final_head_kernel<<<N_GRAPHS, 256, 0, stream>>>(sdot, gstart, head_b, out);
}

// Round 9
// 617.403 us; speedup vs baseline: 8.8871x; 1.0679x over previous
//
#include <hip/hip_runtime.h>
#include <math.h>

#define N_NODES 20000
#define N_EDGES 320000
#define N_GRAPHS 32
#define CDIM 256
#define IN_DIMV 739
#define KPAD_DENSE 768
#define ED_DIM 518
#define NLAYERS 4
#define LN_EPS 1e-5f
#define SCAN_BLOCKS ((N_NODES + 255) / 256)  // 79

typedef _Float16 f16x8 __attribute__((ext_vector_type(8)));
typedef _Float16 f16x4 __attribute__((ext_vector_type(4)));
typedef float f32x4 __attribute__((ext_vector_type(4)));

__device__ __forceinline__ float gelu_exact(float x) {
    return 0.5f * x * (1.f + erff(x * 0.7071067811865475f));
}

__global__ void zero_kernel(float* __restrict__ p, int n) {
    int i = blockIdx.x * blockDim.x + threadIdx.x;
    int stride = gridDim.x * blockDim.x;
    for (; i < n; i += stride) p[i] = 0.f;
}

// Precompute per-layer: cw[i][c] = ln1_g[i] * w1_w[i][c]
__global__ void precompute_kernel(const float* __restrict__ ln1_g, const float* __restrict__ ln1_b,
                                  const float* __restrict__ w1_w,
                                  float* __restrict__ cw, float* __restrict__ SgSb) {
    int l = blockIdx.x, tid = threadIdx.x;
    float sg[4] = {0, 0, 0, 0}, sb[4] = {0, 0, 0, 0};
    for (int i = tid; i < ED_DIM; i += 256) {
        float g = ln1_g[l * ED_DIM + i];
        float b = ln1_b[l * ED_DIM + i];
        float4 w = *(const float4*)&w1_w[(size_t)(l * ED_DIM + i) * 4];
        float4 c = make_float4(g * w.x, g * w.y, g * w.z, g * w.w);
        *(float4*)&cw[(size_t)(l * ED_DIM + i) * 4] = c;
        sg[0] += c.x; sg[1] += c.y; sg[2] += c.z; sg[3] += c.w;
        sb[0] += b * w.x; sb[1] += b * w.y; sb[2] += b * w.z; sb[3] += b * w.w;
    }
    __shared__ float red[256][8];
    for (int c = 0; c < 4; c++) { red[tid][c] = sg[c]; red[tid][4 + c] = sb[c]; }
    __syncthreads();
    for (int s = 128; s > 0; s >>= 1) {
        if (tid < s)
            for (int c = 0; c < 8; c++) red[tid][c] += red[tid + s][c];
        __syncthreads();
    }
    if (tid < 8) SgSb[l * 8 + tid] = red[0][tid];
}

// ---- CSR build ----
__global__ void hist_kernel(const int* __restrict__ ei, int* __restrict__ deg) {
    int e = blockIdx.x * 256 + threadIdx.x;
    if (e < N_EDGES) atomicAdd(&deg[ei[N_EDGES + e]], 1);
}

// Phase 1: per-block sum of deg (256 elements/block).
__global__ __launch_bounds__(256)
void scan1_kernel(const int* __restrict__ deg, int* __restrict__ bsum) {
    __shared__ int red[256];
    int t = threadIdx.x;
    int i = blockIdx.x * 256 + t;
    red[t] = (i < N_NODES) ? deg[i] : 0;
    __syncthreads();
    for (int s = 128; s > 0; s >>= 1) {
        if (t < s) red[t] += red[t + s];
        __syncthreads();
    }
    if (t == 0) bsum[blockIdx.x] = red[0];
}

// Phase 2: exclusive scan of the SCAN_BLOCKS partials (single tiny block).
__global__ __launch_bounds__(128)
void scan2_kernel(const int* __restrict__ bsum, int* __restrict__ boff) {
    __shared__ int s[128];
    int t = threadIdx.x;
    int v = (t < SCAN_BLOCKS) ? bsum[t] : 0;
    s[t] = v;
    __syncthreads();
    for (int off = 1; off < 128; off <<= 1) {
        int o = (t >= off) ? s[t - off] : 0;
        __syncthreads();
        s[t] += o;
        __syncthreads();
    }
    if (t < SCAN_BLOCKS) boff[t] = s[t] - v;  // exclusive
}

// Phase 3: in-block exclusive scan + block offset; writes row_start & cursor.
__global__ __launch_bounds__(256)
void scan3_kernel(const int* __restrict__ deg, const int* __restrict__ boff,
                  int* __restrict__ row_start, int* __restrict__ cursor) {
    __shared__ int s[256];
    int t = threadIdx.x;
    int i = blockIdx.x * 256 + t;
    int v = (i < N_NODES) ? deg[i] : 0;
    s[t] = v;
    __syncthreads();
    for (int off = 1; off < 256; off <<= 1) {
        int o = (t >= off) ? s[t - off] : 0;
        __syncthreads();
        s[t] += o;
        __syncthreads();
    }
    int base = boff[blockIdx.x];
    int excl = base + s[t] - v;
    if (i < N_NODES) {
        row_start[i] = excl;
        cursor[i] = excl;
    }
    if (i == N_NODES - 1) row_start[N_NODES] = base + s[t];
}

__global__ void scatter_kernel(const int* __restrict__ ei, int* __restrict__ cursor,
                               int* __restrict__ csr_src, int* __restrict__ slot) {
    int e = blockIdx.x * 256 + threadIdx.x;
    if (e < N_EDGES) {
        int d = ei[N_EDGES + e];
        int pos = atomicAdd(&cursor[d], 1);
        csr_src[pos] = ei[e];
        slot[e] = pos;
    }
}

__global__ void gstart_kernel(const int* __restrict__ batch, int* __restrict__ gstart) {
    int n = blockIdx.x * 256 + threadIdx.x;
    if (n >= N_NODES) return;
    int b = batch[n];
    int bprev = (n == 0) ? -1 : batch[n - 1];
    for (int g = bprev + 1; g <= b; g++) gstart[g] = n;
    if (n == N_NODES - 1)
        for (int g = b + 1; g <= N_GRAPHS; g++) gstart[g] = N_NODES;
}

// x[N][739] fp32 -> xh[N][768] fp16, zero-padded.
__global__ __launch_bounds__(256)
void convert_x(const float* __restrict__ x, _Float16* __restrict__ xh) {
    int n = blockIdx.x;
    int k = blockIdx.y * 256 + threadIdx.x;
    xh[(size_t)n * KPAD_DENSE + k] = (k < IN_DIMV) ? (_Float16)x[(size_t)n * IN_DIMV + k]
                                                   : (_Float16)0.f;
}

// Transpose+convert W[K][256] fp32 -> Wt[256][Kpad] fp16 (zero-padded k>=K).
__global__ __launch_bounds__(256)
void prep_weight(const float* __restrict__ W, _Float16* __restrict__ Wt, int K, int Kpad) {
    __shared__ float T[32][33];
    int kt = blockIdx.x, nt = blockIdx.y;
    int tid = threadIdx.x;
    int i = tid >> 5, j = tid & 31;
#pragma unroll
    for (int ii = 0; ii < 4; ii++) {
        int k = kt * 32 + i + ii * 8;
        T[i + ii * 8][j] = (k < K) ? W[(size_t)k * 256 + nt * 32 + j] : 0.f;
    }
    __syncthreads();
#pragma unroll
    for (int ii = 0; ii < 4; ii++) {
        int n = nt * 32 + i + ii * 8;
        Wt[(size_t)n * Kpad + kt * 32 + j] = (_Float16)T[j][i + ii * 8];
    }
}

// Same, batched over the 8 square layer weights (z<4: d1_w[z], else d2_w[z-4]).
__global__ __launch_bounds__(256)
void prep_weight_sq(const float* __restrict__ d1_w, const float* __restrict__ d2_w,
                    _Float16* __restrict__ Wt) {
    __shared__ float T[32][33];
    int kt = blockIdx.x, nt = blockIdx.y, z = blockIdx.z;
    const float* W = (z < 4) ? d1_w + (size_t)z * 65536 : d2_w + (size_t)(z - 4) * 65536;
    _Float16* O = Wt + (size_t)z * 65536;
    int tid = threadIdx.x;
    int i = tid >> 5, j = tid & 31;
#pragma unroll
    for (int ii = 0; ii < 4; ii++)
        T[i + ii * 8][j] = W[(size_t)(kt * 32 + i + ii * 8) * 256 + nt * 32 + j];
    __syncthreads();
#pragma unroll
    for (int ii = 0; ii < 4; ii++)
        O[(size_t)(nt * 32 + i + ii * 8) * 256 + kt * 32 + j] = (_Float16)T[j][i + ii * 8];
}

// C[M,256] = act(A @ W + bias), A fp16 [M][Kpad], Wt fp16 [256][Kpad], C fp16.
// Tile BM=32, BN=128, BK=64; 256 thr / 4 waves. Grid (625, 2).
template <bool GELU>
__global__ __launch_bounds__(256)
void gemm_mfma(const _Float16* __restrict__ A, const _Float16* __restrict__ Bt,
               const float* __restrict__ bias, _Float16* __restrict__ C,
               int Kpad) {
    __shared__ __align__(16) _Float16 As[32 * 72];
    __shared__ __align__(16) _Float16 Bs[128 * 72];
    int tid = threadIdx.x;
    int row0 = blockIdx.x * 32;
    int col0 = blockIdx.y * 128;
    int wave = tid >> 6, lane = tid & 63;
    int quad = lane >> 4, lrow = lane & 15;
    int wrow = wave >> 1, wcol = wave & 1;

    int ar = tid >> 3, ak8 = (tid & 7) * 8;
    int br = tid >> 1, bh = (tid & 1) * 32;

    const _Float16* Arow = &A[(size_t)(row0 + ar) * Kpad];
    const _Float16* Brow = &Bt[(size_t)(col0 + br) * Kpad];

    int ntiles = Kpad >> 6;
    uint4 a_raw = *(const uint4*)&Arow[ak8];
    uint4 b_raw0 = *(const uint4*)&Brow[bh];
    uint4 b_raw1 = *(const uint4*)&Brow[bh + 8];
    uint4 b_raw2 = *(const uint4*)&Brow[bh + 16];
    uint4 b_raw3 = *(const uint4*)&Brow[bh + 24];

    f32x4 acc[4];
#pragma unroll
    for (int t = 0; t < 4; t++) acc[t] = (f32x4){0.f, 0.f, 0.f, 0.f};

    for (int kt = 0; kt < ntiles; ++kt) {
        *(uint4*)&As[ar * 72 + ak8] = a_raw;
        *(uint4*)&Bs[br * 72 + bh] = b_raw0;
        *(uint4*)&Bs[br * 72 + bh + 8] = b_raw1;
        *(uint4*)&Bs[br * 72 + bh + 16] = b_raw2;
        *(uint4*)&Bs[br * 72 + bh + 24] = b_raw3;
        __syncthreads();

        if (kt + 1 < ntiles) {
            int k0 = (kt + 1) << 6;
            a_raw = *(const uint4*)&Arow[k0 + ak8];
            b_raw0 = *(const uint4*)&Brow[k0 + bh];
            b_raw1 = *(const uint4*)&Brow[k0 + bh + 8];
            b_raw2 = *(const uint4*)&Brow[k0 + bh + 16];
            b_raw3 = *(const uint4*)&Brow[k0 + bh + 24];
        }

#pragma unroll
        for (int h = 0; h < 2; h++) {
            f16x8 af = *(const f16x8*)&As[(wrow * 16 + lrow) * 72 + h * 32 + quad * 8];
#pragma unroll
            for (int t = 0; t < 4; t++) {
                f16x8 bf = *(const f16x8*)&Bs[((wcol * 4 + t) * 16 + lrow) * 72 + h * 32 + quad * 8];
                acc[t] = __builtin_amdgcn_mfma_f32_16x16x32_f16(af, bf, acc[t], 0, 0, 0);
            }
        }
        __syncthreads();
    }

    int orow = row0 + wrow * 16 + quad * 4;
#pragma unroll
    for (int t = 0; t < 4; t++) {
        int col = col0 + (wcol * 4 + t) * 16 + lrow;
        float bv = bias[col];
#pragma unroll
        for (int r = 0; r < 4; r++) {
            float v = acc[t][r] + bv;
            C[(size_t)(orow + r) * 256 + col] = (_Float16)(GELU ? gelu_exact(v) : v);
        }
    }
}

// Per-node summaries from fp16 m: P1, P2, Q1, Q2 (12 floats/node)
__global__ __launch_bounds__(256)
void node_summary_kernel(const _Float16* __restrict__ m, const float* __restrict__ cw,
                         float* __restrict__ ns) {
    __shared__ __align__(16) float4 s_cw[512];
    int tid = threadIdx.x;
    for (int i = tid; i < 512; i += 256) s_cw[i] = *(const float4*)&cw[(size_t)i * 4];
    __syncthreads();
    int n = blockIdx.x * 4 + (tid >> 6);
    if (n >= N_NODES) return;
    int lane = tid & 63;
    f16x4 a4 = *(const f16x4*)&m[(size_t)n * CDIM + lane * 4];
    float av[4] = {(float)a4[0], (float)a4[1], (float)a4[2], (float)a4[3]};
    float Q1 = 0.f, Q2 = 0.f, P1[4] = {0, 0, 0, 0}, P2[4] = {0, 0, 0, 0};
#pragma unroll
    for (int j = 0; j < 4; j++) {
        Q1 += av[j];
        Q2 += av[j] * av[j];
        float4 c0 = s_cw[lane * 4 + j];
        float4 c1 = s_cw[256 + lane * 4 + j];
        P1[0] += av[j] * c0.x; P1[1] += av[j] * c0.y; P1[2] += av[j] * c0.z; P1[3] += av[j] * c0.w;
        P2[0] += av[j] * c1.x; P2[1] += av[j] * c1.y; P2[2] += av[j] * c1.z; P2[3] += av[j] * c1.w;
    }
#pragma unroll
    for (int off = 1; off < 64; off <<= 1) {
        Q1 += __shfl_xor(Q1, off, 64);
        Q2 += __shfl_xor(Q2, off, 64);
        P1[0] += __shfl_xor(P1[0], off, 64);
        P1[1] += __shfl_xor(P1[1], off, 64);
        P1[2] += __shfl_xor(P1[2], off, 64);
        P1[3] += __shfl_xor(P1[3], off, 64);
        P2[0] += __shfl_xor(P2[0], off, 64);
        P2[1] += __shfl_xor(P2[1], off, 64);
        P2[2] += __shfl_xor(P2[2], off, 64);
        P2[3] += __shfl_xor(P2[3], off, 64);
    }
    if (lane == 0) {
        float* p = &ns[(size_t)n * 12];
        *(float4*)p = make_float4(P1[0], P1[1], P1[2], P1[3]);
        *(float4*)(p + 4) = make_float4(P2[0], P2[1], P2[2], P2[3]);
        p[8] = Q1;
        p[9] = Q2;
    }
}

// One thread per edge: edge MLP from node summaries; writes w into CSR slot.
__global__ __launch_bounds__(256)
void edge_weight_kernel(const float* __restrict__ ns, const float* __restrict__ x_pos,
                        const int* __restrict__ ei, const float* __restrict__ cw,
                        const float* __restrict__ SgSb, const float* __restrict__ w1_b,
                        const float* __restrict__ ln2_g, const float* __restrict__ ln2_b,
                        const float* __restrict__ w2_w, const float* __restrict__ w2_b,
                        const int* __restrict__ slot, float* __restrict__ w_csr) {
    int e = blockIdx.x * 256 + threadIdx.x;
    if (e >= N_EDGES) return;
    int s = ei[e], d = ei[N_EDGES + e];
    const float* nss = &ns[(size_t)s * 12];
    const float* nsd = &ns[(size_t)d * 12];
    float4 p1 = *(const float4*)nss;
    float4 p2 = *(const float4*)(nsd + 4);
    float S1 = nss[8] + nsd[8];
    float S2 = nss[9] + nsd[9];
    float D[4] = {p1.x + p2.x, p1.y + p2.y, p1.z + p2.z, p1.w + p2.w};
    float ps[6];
    ps[0] = x_pos[(size_t)s * 3 + 0];
    ps[1] = x_pos[(size_t)s * 3 + 1];
    ps[2] = x_pos[(size_t)s * 3 + 2];
    ps[3] = x_pos[(size_t)d * 3 + 0];
    ps[4] = x_pos[(size_t)d * 3 + 1];
    ps[5] = x_pos[(size_t)d * 3 + 2];
#pragma unroll
    for (int k = 0; k < 6; k++) {
        S1 += ps[k];
        S2 += ps[k] * ps[k];
        float4 c = *(const float4*)&cw[(size_t)(512 + k) * 4];
        D[0] += ps[k] * c.x; D[1] += ps[k] * c.y; D[2] += ps[k] * c.z; D[3] += ps[k] * c.w;
    }
    const float inv = 1.f / 518.f;
    float mu = S1 * inv;
    float var = fmaf(-mu, mu, S2 * inv);
    float rstd = rsqrtf(var + LN_EPS);
    float t[4];
#pragma unroll
    for (int c = 0; c < 4; c++)
        t[c] = gelu_exact(rstd * (D[c] - mu * SgSb[c]) + SgSb[4 + c] + w1_b[c]);
    float mu2 = 0.25f * (t[0] + t[1] + t[2] + t[3]);
    float var2 = 0.25f * ((t[0] - mu2) * (t[0] - mu2) + (t[1] - mu2) * (t[1] - mu2) +
                          (t[2] - mu2) * (t[2] - mu2) + (t[3] - mu2) * (t[3] - mu2));
    float r2 = rsqrtf(var2 + LN_EPS);
    float z = w2_b[0];
#pragma unroll
    for (int c = 0; c < 4; c++)
        z += ((t[c] - mu2) * r2 * ln2_g[c] + ln2_b[c]) * w2_w[c];
    w_csr[slot[e]] = 1.f / (1.f + expf(-z));
}

// CSR SpMM over fp16 m: agg[n] = sum_j w_csr[j] * m[csr_src[j]], fp32 acc, fp16 out.
__global__ __launch_bounds__(256)
void agg_kernel(const _Float16* __restrict__ m, const int* __restrict__ csr_src,
                const float* __restrict__ w_csr, const int* __restrict__ row_start,
                _Float16* __restrict__ agg) {
    int n = blockIdx.x * 4 + (threadIdx.x >> 6);
    if (n >= N_NODES) return;
    int lane = threadIdx.x & 63;
    int beg = row_start[n], end = row_start[n + 1];
    float a0 = 0.f, a1 = 0.f, a2 = 0.f, a3 = 0.f;
    for (int j = beg; j < end; j++) {
        int s = csr_src[j];
        float w = w_csr[j];
        f16x4 v = *(const f16x4*)&m[(size_t)s * CDIM + lane * 4];
        a0 = fmaf(w, (float)v[0], a0);
        a1 = fmaf(w, (float)v[1], a1);
        a2 = fmaf(w, (float)v[2], a2);
        a3 = fmaf(w, (float)v[3], a3);
    }
    f16x4 o;
    o[0] = (_Float16)a0; o[1] = (_Float16)a1; o[2] = (_Float16)a2; o[3] = (_Float16)a3;
    *(f16x4*)&agg[(size_t)n * CDIM + lane * 4] = o;
}

__global__ __launch_bounds__(256)
void node_dot_kernel(const _Float16* __restrict__ h, const float* __restrict__ head_w,
                     float* __restrict__ sdot) {
    int n = blockIdx.x * 4 + (threadIdx.x >> 6);
    if (n >= N_NODES) return;
    int lane = threadIdx.x & 63;
    f16x4 v = *(const f16x4*)&h[(size_t)n * CDIM + lane * 4];
    float4 w = *(const float4*)&head_w[lane * 4];
    float p = (float)v[0] * w.x + (float)v[1] * w.y + (float)v[2] * w.z + (float)v[3] * w.w;
#pragma unroll
    for (int off = 1; off < 64; off <<= 1) p += __shfl_xor(p, off, 64);
    if (lane == 0) sdot[n] = p;
}

__global__ __launch_bounds__(256)
void final_head_kernel(const float* __restrict__ sdot, const int* __restrict__ gstart,
                       const float* __restrict__ head_b, float* __restrict__ out) {
    int g = blockIdx.x;
    int t = threadIdx.x;
    int beg = gstart[g], end = gstart[g + 1];
    float s = 0.f;
    for (int i = beg + t; i < end; i += 256) s += sdot[i];
    __shared__ float red[256];
    red[t] = s;
    __syncthreads();
    for (int k = 128; k > 0; k >>= 1) {
        if (t < k) red[t] += red[t + k];
        __syncthreads();
    }
    if (t == 0) out[g] = red[0] / fmaxf((float)(end - beg), 1.f) + head_b[0];
}

extern "C" void kernel_launch(void* const* d_in, const int* in_sizes, int n_in,
                              void* d_out, int out_size, void* d_ws, size_t ws_size,
                              hipStream_t stream) {
    const float* x       = (const float*)d_in[0];
    const float* x_pos   = (const float*)d_in[1];
    const int*   ei      = (const int*)d_in[2];
    const int*   batch   = (const int*)d_in[3];
    const float* dense_w = (const float*)d_in[4];
    const float* dense_b = (const float*)d_in[5];
    const float* d1_w    = (const float*)d_in[6];
    const float* d1_b    = (const float*)d_in[7];
    const float* ln1_g   = (const float*)d_in[8];
    const float* ln1_b   = (const float*)d_in[9];
    const float* w1_w    = (const float*)d_in[10];
    const float* w1_b    = (const float*)d_in[11];
    const float* ln2_g   = (const float*)d_in[12];
    const float* ln2_b   = (const float*)d_in[13];
    const float* w2_w    = (const float*)d_in[14];
    const float* w2_b    = (const float*)d_in[15];
    const float* d2_w    = (const float*)d_in[16];
    const float* d2_b    = (const float*)d_in[17];
    const float* head_w  = (const float*)d_in[18];
    const float* head_b  = (const float*)d_in[19];
    float* out = (float*)d_out;

    _Float16* hbuf0 = (_Float16*)d_ws;                          // [N][256] fp16
    _Float16* hbuf1 = hbuf0 + (size_t)N_NODES * CDIM;           // [N][256] fp16
    _Float16* xh    = hbuf1 + (size_t)N_NODES * CDIM;           // [N][768] fp16
    _Float16* wt_dense = xh + (size_t)N_NODES * KPAD_DENSE;     // [256][768] fp16
    _Float16* wt_sq    = wt_dense + (size_t)256 * KPAD_DENSE;   // [8][256][256] fp16
    float* cw    = (float*)(wt_sq + (size_t)8 * 256 * 256);     // [L][518][4]
    float* SgSb  = cw + (size_t)NLAYERS * ED_DIM * 4;           // [L][8]
    float* ns    = SgSb + NLAYERS * 8;                          // [N][12]
    float* sdot  = ns + (size_t)N_NODES * 12;                   // [N]
    float* w_csr = sdot + N_NODES;                              // [E]
    int* gstart    = (int*)(w_csr + N_EDGES);                   // [33]
    int* deg       = gstart + N_GRAPHS + 1;                     // [N]
    int* row_start = deg + N_NODES;                             // [N+1]
    int* cursor    = row_start + N_NODES + 1;                   // [N]
    int* csr_src   = cursor + N_NODES;                          // [E]
    int* slot      = csr_src + N_EDGES;                         // [E]
    int* bsum      = slot + N_EDGES;                            // [SCAN_BLOCKS]
    int* boff      = bsum + SCAN_BLOCKS;                        // [SCAN_BLOCKS]

    precompute_kernel<<<NLAYERS, 256, 0, stream>>>(ln1_g, ln1_b, w1_w, cw, SgSb);

    zero_kernel<<<80, 256, 0, stream>>>((float*)deg, N_NODES);
    hist_kernel<<<(N_EDGES + 255) / 256, 256, 0, stream>>>(ei, deg);
    scan1_kernel<<<SCAN_BLOCKS, 256, 0, stream>>>(deg, bsum);
    scan2_kernel<<<1, 128, 0, stream>>>(bsum, boff);
    scan3_kernel<<<SCAN_BLOCKS, 256, 0, stream>>>(deg, boff, row_start, cursor);
    scatter_kernel<<<(N_EDGES + 255) / 256, 256, 0, stream>>>(ei, cursor, csr_src, slot);
    gstart_kernel<<<(N_NODES + 255) / 256, 256, 0, stream>>>(batch, gstart);

    convert_x<<<dim3(N_NODES, 3), 256, 0, stream>>>(x, xh);
    prep_weight<<<dim3(24, 8), 256, 0, stream>>>(dense_w, wt_dense, IN_DIMV, KPAD_DENSE);
    prep_weight_sq<<<dim3(8, 8, 8), 256, 0, stream>>>(d1_w, d2_w, wt_sq);

    const dim3 GGRID(N_NODES / 32, 2);  // (625, 2) = 1250 blocks
    gemm_mfma<false><<<GGRID, 256, 0, stream>>>(xh, wt_dense, dense_b, hbuf0, KPAD_DENSE);

    _Float16* h = hbuf0;
    _Float16* other = hbuf1;
    for (int l = 0; l < NLAYERS; l++) {
        gemm_mfma<true><<<GGRID, 256, 0, stream>>>(
            h, wt_sq + (size_t)l * 65536, d1_b + l * CDIM, other, CDIM);
        node_summary_kernel<<<(N_NODES + 3) / 4, 256, 0, stream>>>(
            other, cw + (size_t)l * ED_DIM * 4, ns);
        edge_weight_kernel<<<(N_EDGES + 255) / 256, 256, 0, stream>>>(
            ns, x_pos, ei, cw + (size_t)l * ED_DIM * 4, SgSb + l * 8, w1_b + l * 4,
            ln2_g + l * 4, ln2_b + l * 4, w2_w + l * 4, w2_b + l, slot, w_csr);
        agg_kernel<<<(N_NODES + 3) / 4, 256, 0, stream>>>(other, csr_src, w_csr, row_start, h);
        gemm_mfma<true><<<GGRID, 256, 0, stream>>>(
            h, wt_sq + (size_t)(4 + l) * 65536, d2_b + l * CDIM, other, CDIM);
        _Float16* tmp = h; h = other; other = tmp;
    }

    node_dot_kernel<<<(N_NODES + 3) / 4, 256, 0, stream>>>(h, head_w, sdot);
    final_head_kernel<<<N_GRAPHS, 256, 0, stream>>>(sdot, gstart, head_b, out);
}

// Round 10
// 549.155 us; speedup vs baseline: 9.9916x; 1.1243x over previous
//
#include <hip/hip_runtime.h>
#include <math.h>

#define N_NODES 20000
#define N_EDGES 320000
#define N_GRAPHS 32
#define CDIM 256
#define IN_DIMV 739
#define KPAD_DENSE 768
#define ED_DIM 518
#define NLAYERS 4
#define LN_EPS 1e-5f
#define SCAN_BLOCKS ((N_NODES + 255) / 256)  // 79

typedef _Float16 f16x8 __attribute__((ext_vector_type(8)));
typedef _Float16 f16x4 __attribute__((ext_vector_type(4)));
typedef float f32x4 __attribute__((ext_vector_type(4)));

__device__ __forceinline__ float gelu_exact(float x) {
    return 0.5f * x * (1.f + erff(x * 0.7071067811865475f));
}

__global__ void zero_kernel(float* __restrict__ p, int n) {
    int i = blockIdx.x * blockDim.x + threadIdx.x;
    int stride = gridDim.x * blockDim.x;
    for (; i < n; i += stride) p[i] = 0.f;
}

// Precompute per-layer: cw[i][c] = ln1_g[i] * w1_w[i][c]
__global__ void precompute_kernel(const float* __restrict__ ln1_g, const float* __restrict__ ln1_b,
                                  const float* __restrict__ w1_w,
                                  float* __restrict__ cw, float* __restrict__ SgSb) {
    int l = blockIdx.x, tid = threadIdx.x;
    float sg[4] = {0, 0, 0, 0}, sb[4] = {0, 0, 0, 0};
    for (int i = tid; i < ED_DIM; i += 256) {
        float g = ln1_g[l * ED_DIM + i];
        float b = ln1_b[l * ED_DIM + i];
        float4 w = *(const float4*)&w1_w[(size_t)(l * ED_DIM + i) * 4];
        float4 c = make_float4(g * w.x, g * w.y, g * w.z, g * w.w);
        *(float4*)&cw[(size_t)(l * ED_DIM + i) * 4] = c;
        sg[0] += c.x; sg[1] += c.y; sg[2] += c.z; sg[3] += c.w;
        sb[0] += b * w.x; sb[1] += b * w.y; sb[2] += b * w.z; sb[3] += b * w.w;
    }
    __shared__ float red[256][8];
    for (int c = 0; c < 4; c++) { red[tid][c] = sg[c]; red[tid][4 + c] = sb[c]; }
    __syncthreads();
    for (int s = 128; s > 0; s >>= 1) {
        if (tid < s)
            for (int c = 0; c < 8; c++) red[tid][c] += red[tid + s][c];
        __syncthreads();
    }
    if (tid < 8) SgSb[l * 8 + tid] = red[0][tid];
}

// ---- CSR build ----
__global__ void hist_kernel(const int* __restrict__ ei, int* __restrict__ deg) {
    int e = blockIdx.x * 256 + threadIdx.x;
    if (e < N_EDGES) atomicAdd(&deg[ei[N_EDGES + e]], 1);
}

__global__ __launch_bounds__(256)
void scan1_kernel(const int* __restrict__ deg, int* __restrict__ bsum) {
    __shared__ int red[256];
    int t = threadIdx.x;
    int i = blockIdx.x * 256 + t;
    red[t] = (i < N_NODES) ? deg[i] : 0;
    __syncthreads();
    for (int s = 128; s > 0; s >>= 1) {
        if (t < s) red[t] += red[t + s];
        __syncthreads();
    }
    if (t == 0) bsum[blockIdx.x] = red[0];
}

__global__ __launch_bounds__(128)
void scan2_kernel(const int* __restrict__ bsum, int* __restrict__ boff) {
    __shared__ int s[128];
    int t = threadIdx.x;
    int v = (t < SCAN_BLOCKS) ? bsum[t] : 0;
    s[t] = v;
    __syncthreads();
    for (int off = 1; off < 128; off <<= 1) {
        int o = (t >= off) ? s[t - off] : 0;
        __syncthreads();
        s[t] += o;
        __syncthreads();
    }
    if (t < SCAN_BLOCKS) boff[t] = s[t] - v;  // exclusive
}

__global__ __launch_bounds__(256)
void scan3_kernel(const int* __restrict__ deg, const int* __restrict__ boff,
                  int* __restrict__ row_start, int* __restrict__ cursor) {
    __shared__ int s[256];
    int t = threadIdx.x;
    int i = blockIdx.x * 256 + t;
    int v = (i < N_NODES) ? deg[i] : 0;
    s[t] = v;
    __syncthreads();
    for (int off = 1; off < 256; off <<= 1) {
        int o = (t >= off) ? s[t - off] : 0;
        __syncthreads();
        s[t] += o;
        __syncthreads();
    }
    int base = boff[blockIdx.x];
    int excl = base + s[t] - v;
    if (i < N_NODES) {
        row_start[i] = excl;
        cursor[i] = excl;
    }
    if (i == N_NODES - 1) row_start[N_NODES] = base + s[t];
}

__global__ void scatter_kernel(const int* __restrict__ ei, int* __restrict__ cursor,
                               int* __restrict__ csr_src, int* __restrict__ slot) {
    int e = blockIdx.x * 256 + threadIdx.x;
    if (e < N_EDGES) {
        int d = ei[N_EDGES + e];
        int pos = atomicAdd(&cursor[d], 1);
        csr_src[pos] = ei[e];
        slot[e] = pos;
    }
}

__global__ void gstart_kernel(const int* __restrict__ batch, int* __restrict__ gstart) {
    int n = blockIdx.x * 256 + threadIdx.x;
    if (n >= N_NODES) return;
    int b = batch[n];
    int bprev = (n == 0) ? -1 : batch[n - 1];
    for (int g = bprev + 1; g <= b; g++) gstart[g] = n;
    if (n == N_NODES - 1)
        for (int g = b + 1; g <= N_GRAPHS; g++) gstart[g] = N_NODES;
}

// x[N][739] fp32 -> xh[N][768] fp16, zero-padded.
__global__ __launch_bounds__(256)
void convert_x(const float* __restrict__ x, _Float16* __restrict__ xh) {
    int n = blockIdx.x;
    int k = blockIdx.y * 256 + threadIdx.x;
    xh[(size_t)n * KPAD_DENSE + k] = (k < IN_DIMV) ? (_Float16)x[(size_t)n * IN_DIMV + k]
                                                   : (_Float16)0.f;
}

// Transpose+convert W[K][256] fp32 -> Wt[256][Kpad] fp16 (zero-padded k>=K).
__global__ __launch_bounds__(256)
void prep_weight(const float* __restrict__ W, _Float16* __restrict__ Wt, int K, int Kpad) {
    __shared__ float T[32][33];
    int kt = blockIdx.x, nt = blockIdx.y;
    int tid = threadIdx.x;
    int i = tid >> 5, j = tid & 31;
#pragma unroll
    for (int ii = 0; ii < 4; ii++) {
        int k = kt * 32 + i + ii * 8;
        T[i + ii * 8][j] = (k < K) ? W[(size_t)k * 256 + nt * 32 + j] : 0.f;
    }
    __syncthreads();
#pragma unroll
    for (int ii = 0; ii < 4; ii++) {
        int n = nt * 32 + i + ii * 8;
        Wt[(size_t)n * Kpad + kt * 32 + j] = (_Float16)T[j][i + ii * 8];
    }
}

__global__ __launch_bounds__(256)
void prep_weight_sq(const float* __restrict__ d1_w, const float* __restrict__ d2_w,
                    _Float16* __restrict__ Wt) {
    __shared__ float T[32][33];
    int kt = blockIdx.x, nt = blockIdx.y, z = blockIdx.z;
    const float* W = (z < 4) ? d1_w + (size_t)z * 65536 : d2_w + (size_t)(z - 4) * 65536;
    _Float16* O = Wt + (size_t)z * 65536;
    int tid = threadIdx.x;
    int i = tid >> 5, j = tid & 31;
#pragma unroll
    for (int ii = 0; ii < 4; ii++)
        T[i + ii * 8][j] = W[(size_t)(kt * 32 + i + ii * 8) * 256 + nt * 32 + j];
    __syncthreads();
#pragma unroll
    for (int ii = 0; ii < 4; ii++)
        O[(size_t)(nt * 32 + i + ii * 8) * 256 + kt * 32 + j] = (_Float16)T[j][i + ii * 8];
}

// C[M,256] = act(A @ W + bias), A fp16 [M][Kpad], Wt fp16 [256][Kpad], C fp16.
// Tile BM=32, BN=128, BK=64; 256 thr / 4 waves. Grid (625, 2).
template <bool GELU>
__global__ __launch_bounds__(256)
void gemm_mfma(const _Float16* __restrict__ A, const _Float16* __restrict__ Bt,
               const float* __restrict__ bias, _Float16* __restrict__ C,
               int Kpad) {
    __shared__ __align__(16) _Float16 As[32 * 72];
    __shared__ __align__(16) _Float16 Bs[128 * 72];
    int tid = threadIdx.x;
    int row0 = blockIdx.x * 32;
    int col0 = blockIdx.y * 128;
    int wave = tid >> 6, lane = tid & 63;
    int quad = lane >> 4, lrow = lane & 15;
    int wrow = wave >> 1, wcol = wave & 1;

    int ar = tid >> 3, ak8 = (tid & 7) * 8;
    int br = tid >> 1, bh = (tid & 1) * 32;

    const _Float16* Arow = &A[(size_t)(row0 + ar) * Kpad];
    const _Float16* Brow = &Bt[(size_t)(col0 + br) * Kpad];

    int ntiles = Kpad >> 6;
    uint4 a_raw = *(const uint4*)&Arow[ak8];
    uint4 b_raw0 = *(const uint4*)&Brow[bh];
    uint4 b_raw1 = *(const uint4*)&Brow[bh + 8];
    uint4 b_raw2 = *(const uint4*)&Brow[bh + 16];
    uint4 b_raw3 = *(const uint4*)&Brow[bh + 24];

    f32x4 acc[4];
#pragma unroll
    for (int t = 0; t < 4; t++) acc[t] = (f32x4){0.f, 0.f, 0.f, 0.f};

    for (int kt = 0; kt < ntiles; ++kt) {
        *(uint4*)&As[ar * 72 + ak8] = a_raw;
        *(uint4*)&Bs[br * 72 + bh] = b_raw0;
        *(uint4*)&Bs[br * 72 + bh + 8] = b_raw1;
        *(uint4*)&Bs[br * 72 + bh + 16] = b_raw2;
        *(uint4*)&Bs[br * 72 + bh + 24] = b_raw3;
        __syncthreads();

        if (kt + 1 < ntiles) {
            int k0 = (kt + 1) << 6;
            a_raw = *(const uint4*)&Arow[k0 + ak8];
            b_raw0 = *(const uint4*)&Brow[k0 + bh];
            b_raw1 = *(const uint4*)&Brow[k0 + bh + 8];
            b_raw2 = *(const uint4*)&Brow[k0 + bh + 16];
            b_raw3 = *(const uint4*)&Brow[k0 + bh + 24];
        }

#pragma unroll
        for (int h = 0; h < 2; h++) {
            f16x8 af = *(const f16x8*)&As[(wrow * 16 + lrow) * 72 + h * 32 + quad * 8];
#pragma unroll
            for (int t = 0; t < 4; t++) {
                f16x8 bf = *(const f16x8*)&Bs[((wcol * 4 + t) * 16 + lrow) * 72 + h * 32 + quad * 8];
                acc[t] = __builtin_amdgcn_mfma_f32_16x16x32_f16(af, bf, acc[t], 0, 0, 0);
            }
        }
        __syncthreads();
    }

    int orow = row0 + wrow * 16 + quad * 4;
#pragma unroll
    for (int t = 0; t < 4; t++) {
        int col = col0 + (wcol * 4 + t) * 16 + lrow;
        float bv = bias[col];
#pragma unroll
        for (int r = 0; r < 4; r++) {
            float v = acc[t][r] + bv;
            C[(size_t)(orow + r) * 256 + col] = (_Float16)(GELU ? gelu_exact(v) : v);
        }
    }
}

// Per-node summaries from fp16 m: P1, P2, Q1, Q2 (12 floats/node)
__global__ __launch_bounds__(256)
void node_summary_kernel(const _Float16* __restrict__ m, const float* __restrict__ cw,
                         float* __restrict__ ns) {
    __shared__ __align__(16) float4 s_cw[512];
    int tid = threadIdx.x;
    for (int i = tid; i < 512; i += 256) s_cw[i] = *(const float4*)&cw[(size_t)i * 4];
    __syncthreads();
    int n = blockIdx.x * 4 + (tid >> 6);
    if (n >= N_NODES) return;
    int lane = tid & 63;
    f16x4 a4 = *(const f16x4*)&m[(size_t)n * CDIM + lane * 4];
    float av[4] = {(float)a4[0], (float)a4[1], (float)a4[2], (float)a4[3]};
    float Q1 = 0.f, Q2 = 0.f, P1[4] = {0, 0, 0, 0}, P2[4] = {0, 0, 0, 0};
#pragma unroll
    for (int j = 0; j < 4; j++) {
        Q1 += av[j];
        Q2 += av[j] * av[j];
        float4 c0 = s_cw[lane * 4 + j];
        float4 c1 = s_cw[256 + lane * 4 + j];
        P1[0] += av[j] * c0.x; P1[1] += av[j] * c0.y; P1[2] += av[j] * c0.z; P1[3] += av[j] * c0.w;
        P2[0] += av[j] * c1.x; P2[1] += av[j] * c1.y; P2[2] += av[j] * c1.z; P2[3] += av[j] * c1.w;
    }
#pragma unroll
    for (int off = 1; off < 64; off <<= 1) {
        Q1 += __shfl_xor(Q1, off, 64);
        Q2 += __shfl_xor(Q2, off, 64);
        P1[0] += __shfl_xor(P1[0], off, 64);
        P1[1] += __shfl_xor(P1[1], off, 64);
        P1[2] += __shfl_xor(P1[2], off, 64);
        P1[3] += __shfl_xor(P1[3], off, 64);
        P2[0] += __shfl_xor(P2[0], off, 64);
        P2[1] += __shfl_xor(P2[1], off, 64);
        P2[2] += __shfl_xor(P2[2], off, 64);
        P2[3] += __shfl_xor(P2[3], off, 64);
    }
    if (lane == 0) {
        float* p = &ns[(size_t)n * 12];
        *(float4*)p = make_float4(P1[0], P1[1], P1[2], P1[3]);
        *(float4*)(p + 4) = make_float4(P2[0], P2[1], P2[2], P2[3]);
        p[8] = Q1;
        p[9] = Q2;
    }
}

// One thread per edge: edge MLP from node summaries; writes w into CSR slot.
__global__ __launch_bounds__(256)
void edge_weight_kernel(const float* __restrict__ ns, const float* __restrict__ x_pos,
                        const int* __restrict__ ei, const float* __restrict__ cw,
                        const float* __restrict__ SgSb, const float* __restrict__ w1_b,
                        const float* __restrict__ ln2_g, const float* __restrict__ ln2_b,
                        const float* __restrict__ w2_w, const float* __restrict__ w2_b,
                        const int* __restrict__ slot, float* __restrict__ w_csr) {
    int e = blockIdx.x * 256 + threadIdx.x;
    if (e >= N_EDGES) return;
    int s = ei[e], d = ei[N_EDGES + e];
    const float* nss = &ns[(size_t)s * 12];
    const float* nsd = &ns[(size_t)d * 12];
    float4 p1 = *(const float4*)nss;
    float4 p2 = *(const float4*)(nsd + 4);
    float S1 = nss[8] + nsd[8];
    float S2 = nss[9] + nsd[9];
    float D[4] = {p1.x + p2.x, p1.y + p2.y, p1.z + p2.z, p1.w + p2.w};
    float ps[6];
    ps[0] = x_pos[(size_t)s * 3 + 0];
    ps[1] = x_pos[(size_t)s * 3 + 1];
    ps[2] = x_pos[(size_t)s * 3 + 2];
    ps[3] = x_pos[(size_t)d * 3 + 0];
    ps[4] = x_pos[(size_t)d * 3 + 1];
    ps[5] = x_pos[(size_t)d * 3 + 2];
#pragma unroll
    for (int k = 0; k < 6; k++) {
        S1 += ps[k];
        S2 += ps[k] * ps[k];
        float4 c = *(const float4*)&cw[(size_t)(512 + k) * 4];
        D[0] += ps[k] * c.x; D[1] += ps[k] * c.y; D[2] += ps[k] * c.z; D[3] += ps[k] * c.w;
    }
    const float inv = 1.f / 518.f;
    float mu = S1 * inv;
    float var = fmaf(-mu, mu, S2 * inv);
    float rstd = rsqrtf(var + LN_EPS);
    float t[4];
#pragma unroll
    for (int c = 0; c < 4; c++)
        t[c] = gelu_exact(rstd * (D[c] - mu * SgSb[c]) + SgSb[4 + c] + w1_b[c]);
    float mu2 = 0.25f * (t[0] + t[1] + t[2] + t[3]);
    float var2 = 0.25f * ((t[0] - mu2) * (t[0] - mu2) + (t[1] - mu2) * (t[1] - mu2) +
                          (t[2] - mu2) * (t[2] - mu2) + (t[3] - mu2) * (t[3] - mu2));
    float r2 = rsqrtf(var2 + LN_EPS);
    float z = w2_b[0];
#pragma unroll
    for (int c = 0; c < 4; c++)
        z += ((t[c] - mu2) * r2 * ln2_g[c] + ln2_b[c]) * w2_w[c];
    w_csr[slot[e]] = 1.f / (1.f + expf(-z));
}

// CSR SpMM over fp16 m, unrolled x4 for memory-level parallelism:
// preload 4 edge indices+weights, issue 4 independent row loads, then FMA.
__global__ __launch_bounds__(256)
void agg_kernel(const _Float16* __restrict__ m, const int* __restrict__ csr_src,
                const float* __restrict__ w_csr, const int* __restrict__ row_start,
                _Float16* __restrict__ agg) {
    int n = blockIdx.x * 4 + (threadIdx.x >> 6);
    if (n >= N_NODES) return;
    int lane = threadIdx.x & 63;
    int beg = row_start[n], end = row_start[n + 1];
    float a0 = 0.f, a1 = 0.f, a2 = 0.f, a3 = 0.f;
    int j = beg;
    for (; j + 4 <= end; j += 4) {
        int s0 = csr_src[j + 0], s1 = csr_src[j + 1];
        int s2 = csr_src[j + 2], s3 = csr_src[j + 3];
        float w0 = w_csr[j + 0], w1 = w_csr[j + 1];
        float w2 = w_csr[j + 2], w3 = w_csr[j + 3];
        f16x4 v0 = *(const f16x4*)&m[(size_t)s0 * CDIM + lane * 4];
        f16x4 v1 = *(const f16x4*)&m[(size_t)s1 * CDIM + lane * 4];
        f16x4 v2 = *(const f16x4*)&m[(size_t)s2 * CDIM + lane * 4];
        f16x4 v3 = *(const f16x4*)&m[(size_t)s3 * CDIM + lane * 4];
        a0 = fmaf(w0, (float)v0[0], a0); a1 = fmaf(w0, (float)v0[1], a1);
        a2 = fmaf(w0, (float)v0[2], a2); a3 = fmaf(w0, (float)v0[3], a3);
        a0 = fmaf(w1, (float)v1[0], a0); a1 = fmaf(w1, (float)v1[1], a1);
        a2 = fmaf(w1, (float)v1[2], a2); a3 = fmaf(w1, (float)v1[3], a3);
        a0 = fmaf(w2, (float)v2[0], a0); a1 = fmaf(w2, (float)v2[1], a1);
        a2 = fmaf(w2, (float)v2[2], a2); a3 = fmaf(w2, (float)v2[3], a3);
        a0 = fmaf(w3, (float)v3[0], a0); a1 = fmaf(w3, (float)v3[1], a1);
        a2 = fmaf(w3, (float)v3[2], a2); a3 = fmaf(w3, (float)v3[3], a3);
    }
    for (; j < end; j++) {
        int s = csr_src[j];
        float w = w_csr[j];
        f16x4 v = *(const f16x4*)&m[(size_t)s * CDIM + lane * 4];
        a0 = fmaf(w, (float)v[0], a0);
        a1 = fmaf(w, (float)v[1], a1);
        a2 = fmaf(w, (float)v[2], a2);
        a3 = fmaf(w, (float)v[3], a3);
    }
    f16x4 o;
    o[0] = (_Float16)a0; o[1] = (_Float16)a1; o[2] = (_Float16)a2; o[3] = (_Float16)a3;
    *(f16x4*)&agg[(size_t)n * CDIM + lane * 4] = o;
}

__global__ __launch_bounds__(256)
void node_dot_kernel(const _Float16* __restrict__ h, const float* __restrict__ head_w,
                     float* __restrict__ sdot) {
    int n = blockIdx.x * 4 + (threadIdx.x >> 6);
    if (n >= N_NODES) return;
    int lane = threadIdx.x & 63;
    f16x4 v = *(const f16x4*)&h[(size_t)n * CDIM + lane * 4];
    float4 w = *(const float4*)&head_w[lane * 4];
    float p = (float)v[0] * w.x + (float)v[1] * w.y + (float)v[2] * w.z + (float)v[3] * w.w;
#pragma unroll
    for (int off = 1; off < 64; off <<= 1) p += __shfl_xor(p, off, 64);
    if (lane == 0) sdot[n] = p;
}

__global__ __launch_bounds__(256)
void final_head_kernel(const float* __restrict__ sdot, const int* __restrict__ gstart,
                       const float* __restrict__ head_b, float* __restrict__ out) {
    int g = blockIdx.x;
    int t = threadIdx.x;
    int beg = gstart[g], end = gstart[g + 1];
    float s = 0.f;
    for (int i = beg + t; i < end; i += 256) s += sdot[i];
    __shared__ float red[256];
    red[t] = s;
    __syncthreads();
    for (int k = 128; k > 0; k >>= 1) {
        if (t < k) red[t] += red[t + k];
        __syncthreads();
    }
    if (t == 0) out[g] = red[0] / fmaxf((float)(end - beg), 1.f) + head_b[0];
}

extern "C" void kernel_launch(void* const* d_in, const int* in_sizes, int n_in,
                              void* d_out, int out_size, void* d_ws, size_t ws_size,
                              hipStream_t stream) {
    const float* x       = (const float*)d_in[0];
    const float* x_pos   = (const float*)d_in[1];
    const int*   ei      = (const int*)d_in[2];
    const int*   batch   = (const int*)d_in[3];
    const float* dense_w = (const float*)d_in[4];
    const float* dense_b = (const float*)d_in[5];
    const float* d1_w    = (const float*)d_in[6];
    const float* d1_b    = (const float*)d_in[7];
    const float* ln1_g   = (const float*)d_in[8];
    const float* ln1_b   = (const float*)d_in[9];
    const float* w1_w    = (const float*)d_in[10];
    const float* w1_b    = (const float*)d_in[11];
    const float* ln2_g   = (const float*)d_in[12];
    const float* ln2_b   = (const float*)d_in[13];
    const float* w2_w    = (const float*)d_in[14];
    const float* w2_b    = (const float*)d_in[15];
    const float* d2_w    = (const float*)d_in[16];
    const float* d2_b    = (const float*)d_in[17];
    const float* head_w  = (const float*)d_in[18];
    const float* head_b  = (const float*)d_in[19];
    float* out = (float*)d_out;

    _Float16* hbuf0 = (_Float16*)d_ws;                          // [N][256] fp16
    _Float16* hbuf1 = hbuf0 + (size_t)N_NODES * CDIM;           // [N][256] fp16
    _Float16* xh    = hbuf1 + (size_t)N_NODES * CDIM;           // [N][768] fp16
    _Float16* wt_dense = xh + (size_t)N_NODES * KPAD_DENSE;     // [256][768] fp16
    _Float16* wt_sq    = wt_dense + (size_t)256 * KPAD_DENSE;   // [8][256][256] fp16
    float* cw    = (float*)(wt_sq + (size_t)8 * 256 * 256);     // [L][518][4]
    float* SgSb  = cw + (size_t)NLAYERS * ED_DIM * 4;           // [L][8]
    float* ns    = SgSb + NLAYERS * 8;                          // [N][12]
    float* sdot  = ns + (size_t)N_NODES * 12;                   // [N]
    float* w_csr = sdot + N_NODES;                              // [E]
    int* gstart    = (int*)(w_csr + N_EDGES);                   // [33]
    int* deg       = gstart + N_GRAPHS + 1;                     // [N]
    int* row_start = deg + N_NODES;                             // [N+1]
    int* cursor    = row_start + N_NODES + 1;                   // [N]
    int* csr_src   = cursor + N_NODES;                          // [E]
    int* slot      = csr_src + N_EDGES;                         // [E]
    int* bsum      = slot + N_EDGES;                            // [SCAN_BLOCKS]
    int* boff      = bsum + SCAN_BLOCKS;                        // [SCAN_BLOCKS]

    precompute_kernel<<<NLAYERS, 256, 0, stream>>>(ln1_g, ln1_b, w1_w, cw, SgSb);

    zero_kernel<<<80, 256, 0, stream>>>((float*)deg, N_NODES);
    hist_kernel<<<(N_EDGES + 255) / 256, 256, 0, stream>>>(ei, deg);
    scan1_kernel<<<SCAN_BLOCKS, 256, 0, stream>>>(deg, bsum);
    scan2_kernel<<<1, 128, 0, stream>>>(bsum, boff);
    scan3_kernel<<<SCAN_BLOCKS, 256, 0, stream>>>(deg, boff, row_start, cursor);
    scatter_kernel<<<(N_EDGES + 255) / 256, 256, 0, stream>>>(ei, cursor, csr_src, slot);
    gstart_kernel<<<(N_NODES + 255) / 256, 256, 0, stream>>>(batch, gstart);

    convert_x<<<dim3(N_NODES, 3), 256, 0, stream>>>(x, xh);
    prep_weight<<<dim3(24, 8), 256, 0, stream>>>(dense_w, wt_dense, IN_DIMV, KPAD_DENSE);
    prep_weight_sq<<<dim3(8, 8, 8), 256, 0, stream>>>(d1_w, d2_w, wt_sq);

    const dim3 GGRID(N_NODES / 32, 2);  // (625, 2) = 1250 blocks
    gemm_mfma<false><<<GGRID, 256, 0, stream>>>(xh, wt_dense, dense_b, hbuf0, KPAD_DENSE);

    _Float16* h = hbuf0;
    _Float16* other = hbuf1;
    for (int l = 0; l < NLAYERS; l++) {
        gemm_mfma<true><<<GGRID, 256, 0, stream>>>(
            h, wt_sq + (size_t)l * 65536, d1_b + l * CDIM, other, CDIM);
        node_summary_kernel<<<(N_NODES + 3) / 4, 256, 0, stream>>>(
            other, cw + (size_t)l * ED_DIM * 4, ns);
        edge_weight_kernel<<<(N_EDGES + 255) / 256, 256, 0, stream>>>(
            ns, x_pos, ei, cw + (size_t)l * ED_DIM * 4, SgSb + l * 8, w1_b + l * 4,
            ln2_g + l * 4, ln2_b + l * 4, w2_w + l * 4, w2_b + l, slot, w_csr);
        agg_kernel<<<(N_NODES + 3) / 4, 256, 0, stream>>>(other, csr_src, w_csr, row_start, h);
        gemm_mfma<true><<<GGRID, 256, 0, stream>>>(
            h, wt_sq + (size_t)(4 + l) * 65536, d2_b + l * CDIM, other, CDIM);
        _Float16* tmp = h; h = other; other = tmp;
    }

    node_dot_kernel<<<(N_NODES + 3) / 4, 256, 0, stream>>>(h, head_w, sdot);
    final_head_kernel<<<N_GRAPHS, 256, 0, stream>>>(sdot, gstart, head_b, out);
}

// Round 11
// 538.539 us; speedup vs baseline: 10.1886x; 1.0197x over previous
//
#include <hip/hip_runtime.h>
#include <math.h>

#define N_NODES 20000
#define N_EDGES 320000
#define N_GRAPHS 32
#define CDIM 256
#define IN_DIMV 739
#define KPAD_DENSE 768
#define ED_DIM 518
#define NLAYERS 4
#define LN_EPS 1e-5f
#define SCAN_BLOCKS ((N_NODES + 255) / 256)  // 79

typedef _Float16 f16x8 __attribute__((ext_vector_type(8)));
typedef _Float16 f16x4 __attribute__((ext_vector_type(4)));
typedef float f32x4 __attribute__((ext_vector_type(4)));

__device__ __forceinline__ float gelu_exact(float x) {
    return 0.5f * x * (1.f + erff(x * 0.7071067811865475f));
}

// ---- merged setup: zero deg | precompute cw/SgSb | prep dense W | prep sq W | convert x ----
// block ranges: [0,79) zero deg; [79,83) precompute l=b-79; [83,275) dense W;
// [275,787) square W; [787,2835) convert_x grid-stride.
__global__ __launch_bounds__(256)
void prep_all(const float* __restrict__ ln1_g, const float* __restrict__ ln1_b,
              const float* __restrict__ w1_w, float* __restrict__ cw,
              float* __restrict__ SgSb,
              const float* __restrict__ x, _Float16* __restrict__ xh,
              const float* __restrict__ dense_w, _Float16* __restrict__ wt_dense,
              const float* __restrict__ d1_w, const float* __restrict__ d2_w,
              _Float16* __restrict__ wt_sq, int* __restrict__ deg) {
    __shared__ float smem[2048 + 64];
    int b = blockIdx.x, tid = threadIdx.x;
    if (b < 79) {
        int i = b * 256 + tid;
        if (i < N_NODES) deg[i] = 0;
    } else if (b < 83) {
        int l = b - 79;
        float sg[4] = {0, 0, 0, 0}, sb[4] = {0, 0, 0, 0};
        for (int i = tid; i < ED_DIM; i += 256) {
            float g = ln1_g[l * ED_DIM + i];
            float bb = ln1_b[l * ED_DIM + i];
            float4 w = *(const float4*)&w1_w[(size_t)(l * ED_DIM + i) * 4];
            float4 c = make_float4(g * w.x, g * w.y, g * w.z, g * w.w);
            *(float4*)&cw[(size_t)(l * ED_DIM + i) * 4] = c;
            sg[0] += c.x; sg[1] += c.y; sg[2] += c.z; sg[3] += c.w;
            sb[0] += bb * w.x; sb[1] += bb * w.y; sb[2] += bb * w.z; sb[3] += bb * w.w;
        }
        for (int c = 0; c < 4; c++) { smem[tid * 8 + c] = sg[c]; smem[tid * 8 + 4 + c] = sb[c]; }
        __syncthreads();
        for (int s = 128; s > 0; s >>= 1) {
            if (tid < s)
                for (int c = 0; c < 8; c++) smem[tid * 8 + c] += smem[(tid + s) * 8 + c];
            __syncthreads();
        }
        if (tid < 8) SgSb[l * 8 + tid] = smem[tid];
    } else if (b < 275) {
        int q = b - 83;
        int kt = q >> 3, nt = q & 7;
        int i = tid >> 5, j = tid & 31;
        float* T = smem;  // [32][33]
#pragma unroll
        for (int ii = 0; ii < 4; ii++) {
            int k = kt * 32 + i + ii * 8;
            T[(i + ii * 8) * 33 + j] = (k < IN_DIMV) ? dense_w[(size_t)k * 256 + nt * 32 + j] : 0.f;
        }
        __syncthreads();
#pragma unroll
        for (int ii = 0; ii < 4; ii++) {
            int n = nt * 32 + i + ii * 8;
            wt_dense[(size_t)n * KPAD_DENSE + kt * 32 + j] = (_Float16)T[j * 33 + i + ii * 8];
        }
    } else if (b < 787) {
        int q = b - 275;
        int z = q >> 6, kt = (q >> 3) & 7, nt = q & 7;
        const float* W = (z < 4) ? d1_w + (size_t)z * 65536 : d2_w + (size_t)(z - 4) * 65536;
        _Float16* O = wt_sq + (size_t)z * 65536;
        int i = tid >> 5, j = tid & 31;
        float* T = smem;
#pragma unroll
        for (int ii = 0; ii < 4; ii++)
            T[(i + ii * 8) * 33 + j] = W[(size_t)(kt * 32 + i + ii * 8) * 256 + nt * 32 + j];
        __syncthreads();
#pragma unroll
        for (int ii = 0; ii < 4; ii++)
            O[(size_t)(nt * 32 + i + ii * 8) * 256 + kt * 32 + j] = (_Float16)T[j * 33 + i + ii * 8];
    } else {
        const int TOT = N_NODES * KPAD_DENSE;
        const int STRIDE = 2048 * 256;
        for (int idx = (b - 787) * 256 + tid; idx < TOT; idx += STRIDE) {
            int n = idx / KPAD_DENSE, k = idx - n * KPAD_DENSE;
            xh[idx] = (k < IN_DIMV) ? (_Float16)x[(size_t)n * IN_DIMV + k] : (_Float16)0.f;
        }
    }
}

// ---- CSR build ----
__global__ void hist_gstart_kernel(const int* __restrict__ ei, const int* __restrict__ batch,
                                   int* __restrict__ deg, int* __restrict__ gstart) {
    int e = blockIdx.x * 256 + threadIdx.x;
    if (e < N_EDGES) atomicAdd(&deg[ei[N_EDGES + e]], 1);
    if (e < N_NODES) {
        int b = batch[e];
        int bprev = (e == 0) ? -1 : batch[e - 1];
        for (int g = bprev + 1; g <= b; g++) gstart[g] = e;
        if (e == N_NODES - 1)
            for (int g = b + 1; g <= N_GRAPHS; g++) gstart[g] = N_NODES;
    }
}

__global__ __launch_bounds__(256)
void scan1_kernel(const int* __restrict__ deg, int* __restrict__ bsum) {
    __shared__ int red[256];
    int t = threadIdx.x;
    int i = blockIdx.x * 256 + t;
    red[t] = (i < N_NODES) ? deg[i] : 0;
    __syncthreads();
    for (int s = 128; s > 0; s >>= 1) {
        if (t < s) red[t] += red[t + s];
        __syncthreads();
    }
    if (t == 0) bsum[blockIdx.x] = red[0];
}

__global__ __launch_bounds__(128)
void scan2_kernel(const int* __restrict__ bsum, int* __restrict__ boff) {
    __shared__ int s[128];
    int t = threadIdx.x;
    int v = (t < SCAN_BLOCKS) ? bsum[t] : 0;
    s[t] = v;
    __syncthreads();
    for (int off = 1; off < 128; off <<= 1) {
        int o = (t >= off) ? s[t - off] : 0;
        __syncthreads();
        s[t] += o;
        __syncthreads();
    }
    if (t < SCAN_BLOCKS) boff[t] = s[t] - v;  // exclusive
}

__global__ __launch_bounds__(256)
void scan3_kernel(const int* __restrict__ deg, const int* __restrict__ boff,
                  int* __restrict__ row_start, int* __restrict__ cursor) {
    __shared__ int s[256];
    int t = threadIdx.x;
    int i = blockIdx.x * 256 + t;
    int v = (i < N_NODES) ? deg[i] : 0;
    s[t] = v;
    __syncthreads();
    for (int off = 1; off < 256; off <<= 1) {
        int o = (t >= off) ? s[t - off] : 0;
        __syncthreads();
        s[t] += o;
        __syncthreads();
    }
    int base = boff[blockIdx.x];
    int excl = base + s[t] - v;
    if (i < N_NODES) {
        row_start[i] = excl;
        cursor[i] = excl;
    }
    if (i == N_NODES - 1) row_start[N_NODES] = base + s[t];
}

__global__ void scatter_kernel(const int* __restrict__ ei, int* __restrict__ cursor,
                               int* __restrict__ csr_src, int* __restrict__ slot) {
    int e = blockIdx.x * 256 + threadIdx.x;
    if (e < N_EDGES) {
        int d = ei[N_EDGES + e];
        int pos = atomicAdd(&cursor[d], 1);
        csr_src[pos] = ei[e];
        slot[e] = pos;
    }
}

// C[M,256] = act(A @ W + bias), A fp16 [M][Kpad], Wt fp16 [256][Kpad], C fp16.
// Tile BM=32, BN=128, BK=64; 256 thr / 4 waves. Grid (625, 2).
template <bool GELU>
__global__ __launch_bounds__(256)
void gemm_mfma(const _Float16* __restrict__ A, const _Float16* __restrict__ Bt,
               const float* __restrict__ bias, _Float16* __restrict__ C,
               int Kpad) {
    __shared__ __align__(16) _Float16 As[32 * 72];
    __shared__ __align__(16) _Float16 Bs[128 * 72];
    int tid = threadIdx.x;
    int row0 = blockIdx.x * 32;
    int col0 = blockIdx.y * 128;
    int wave = tid >> 6, lane = tid & 63;
    int quad = lane >> 4, lrow = lane & 15;
    int wrow = wave >> 1, wcol = wave & 1;

    int ar = tid >> 3, ak8 = (tid & 7) * 8;
    int br = tid >> 1, bh = (tid & 1) * 32;

    const _Float16* Arow = &A[(size_t)(row0 + ar) * Kpad];
    const _Float16* Brow = &Bt[(size_t)(col0 + br) * Kpad];

    int ntiles = Kpad >> 6;
    uint4 a_raw = *(const uint4*)&Arow[ak8];
    uint4 b_raw0 = *(const uint4*)&Brow[bh];
    uint4 b_raw1 = *(const uint4*)&Brow[bh + 8];
    uint4 b_raw2 = *(const uint4*)&Brow[bh + 16];
    uint4 b_raw3 = *(const uint4*)&Brow[bh + 24];

    f32x4 acc[4];
#pragma unroll
    for (int t = 0; t < 4; t++) acc[t] = (f32x4){0.f, 0.f, 0.f, 0.f};

    for (int kt = 0; kt < ntiles; ++kt) {
        *(uint4*)&As[ar * 72 + ak8] = a_raw;
        *(uint4*)&Bs[br * 72 + bh] = b_raw0;
        *(uint4*)&Bs[br * 72 + bh + 8] = b_raw1;
        *(uint4*)&Bs[br * 72 + bh + 16] = b_raw2;
        *(uint4*)&Bs[br * 72 + bh + 24] = b_raw3;
        __syncthreads();

        if (kt + 1 < ntiles) {
            int k0 = (kt + 1) << 6;
            a_raw = *(const uint4*)&Arow[k0 + ak8];
            b_raw0 = *(const uint4*)&Brow[k0 + bh];
            b_raw1 = *(const uint4*)&Brow[k0 + bh + 8];
            b_raw2 = *(const uint4*)&Brow[k0 + bh + 16];
            b_raw3 = *(const uint4*)&Brow[k0 + bh + 24];
        }

#pragma unroll
        for (int h = 0; h < 2; h++) {
            f16x8 af = *(const f16x8*)&As[(wrow * 16 + lrow) * 72 + h * 32 + quad * 8];
#pragma unroll
            for (int t = 0; t < 4; t++) {
                f16x8 bf = *(const f16x8*)&Bs[((wcol * 4 + t) * 16 + lrow) * 72 + h * 32 + quad * 8];
                acc[t] = __builtin_amdgcn_mfma_f32_16x16x32_f16(af, bf, acc[t], 0, 0, 0);
            }
        }
        __syncthreads();
    }

    int orow = row0 + wrow * 16 + quad * 4;
#pragma unroll
    for (int t = 0; t < 4; t++) {
        int col = col0 + (wcol * 4 + t) * 16 + lrow;
        float bv = bias[col];
#pragma unroll
        for (int r = 0; r < 4; r++) {
            float v = acc[t][r] + bv;
            C[(size_t)(orow + r) * 256 + col] = (_Float16)(GELU ? gelu_exact(v) : v);
        }
    }
}

// Per-node summaries from fp16 m: P1, P2, Q1, Q2 (12 floats/node)
__global__ __launch_bounds__(256)
void node_summary_kernel(const _Float16* __restrict__ m, const float* __restrict__ cw,
                         float* __restrict__ ns) {
    __shared__ __align__(16) float4 s_cw[512];
    int tid = threadIdx.x;
    for (int i = tid; i < 512; i += 256) s_cw[i] = *(const float4*)&cw[(size_t)i * 4];
    __syncthreads();
    int n = blockIdx.x * 4 + (tid >> 6);
    if (n >= N_NODES) return;
    int lane = tid & 63;
    f16x4 a4 = *(const f16x4*)&m[(size_t)n * CDIM + lane * 4];
    float av[4] = {(float)a4[0], (float)a4[1], (float)a4[2], (float)a4[3]};
    float Q1 = 0.f, Q2 = 0.f, P1[4] = {0, 0, 0, 0}, P2[4] = {0, 0, 0, 0};
#pragma unroll
    for (int j = 0; j < 4; j++) {
        Q1 += av[j];
        Q2 += av[j] * av[j];
        float4 c0 = s_cw[lane * 4 + j];
        float4 c1 = s_cw[256 + lane * 4 + j];
        P1[0] += av[j] * c0.x; P1[1] += av[j] * c0.y; P1[2] += av[j] * c0.z; P1[3] += av[j] * c0.w;
        P2[0] += av[j] * c1.x; P2[1] += av[j] * c1.y; P2[2] += av[j] * c1.z; P2[3] += av[j] * c1.w;
    }
#pragma unroll
    for (int off = 1; off < 64; off <<= 1) {
        Q1 += __shfl_xor(Q1, off, 64);
        Q2 += __shfl_xor(Q2, off, 64);
        P1[0] += __shfl_xor(P1[0], off, 64);
        P1[1] += __shfl_xor(P1[1], off, 64);
        P1[2] += __shfl_xor(P1[2], off, 64);
        P1[3] += __shfl_xor(P1[3], off, 64);
        P2[0] += __shfl_xor(P2[0], off, 64);
        P2[1] += __shfl_xor(P2[1], off, 64);
        P2[2] += __shfl_xor(P2[2], off, 64);
        P2[3] += __shfl_xor(P2[3], off, 64);
    }
    if (lane == 0) {
        float* p = &ns[(size_t)n * 12];
        *(float4*)p = make_float4(P1[0], P1[1], P1[2], P1[3]);
        *(float4*)(p + 4) = make_float4(P2[0], P2[1], P2[2], P2[3]);
        p[8] = Q1;
        p[9] = Q2;
    }
}

// One thread per edge: edge MLP from node summaries; writes w into CSR slot.
__global__ __launch_bounds__(256)
void edge_weight_kernel(const float* __restrict__ ns, const float* __restrict__ x_pos,
                        const int* __restrict__ ei, const float* __restrict__ cw,
                        const float* __restrict__ SgSb, const float* __restrict__ w1_b,
                        const float* __restrict__ ln2_g, const float* __restrict__ ln2_b,
                        const float* __restrict__ w2_w, const float* __restrict__ w2_b,
                        const int* __restrict__ slot, float* __restrict__ w_csr) {
    int e = blockIdx.x * 256 + threadIdx.x;
    if (e >= N_EDGES) return;
    int s = ei[e], d = ei[N_EDGES + e];
    const float* nss = &ns[(size_t)s * 12];
    const float* nsd = &ns[(size_t)d * 12];
    float4 p1 = *(const float4*)nss;
    float4 p2 = *(const float4*)(nsd + 4);
    float S1 = nss[8] + nsd[8];
    float S2 = nss[9] + nsd[9];
    float D[4] = {p1.x + p2.x, p1.y + p2.y, p1.z + p2.z, p1.w + p2.w};
    float ps[6];
    ps[0] = x_pos[(size_t)s * 3 + 0];
    ps[1] = x_pos[(size_t)s * 3 + 1];
    ps[2] = x_pos[(size_t)s * 3 + 2];
    ps[3] = x_pos[(size_t)d * 3 + 0];
    ps[4] = x_pos[(size_t)d * 3 + 1];
    ps[5] = x_pos[(size_t)d * 3 + 2];
#pragma unroll
    for (int k = 0; k < 6; k++) {
        S1 += ps[k];
        S2 += ps[k] * ps[k];
        float4 c = *(const float4*)&cw[(size_t)(512 + k) * 4];
        D[0] += ps[k] * c.x; D[1] += ps[k] * c.y; D[2] += ps[k] * c.z; D[3] += ps[k] * c.w;
    }
    const float inv = 1.f / 518.f;
    float mu = S1 * inv;
    float var = fmaf(-mu, mu, S2 * inv);
    float rstd = rsqrtf(var + LN_EPS);
    float t[4];
#pragma unroll
    for (int c = 0; c < 4; c++)
        t[c] = gelu_exact(rstd * (D[c] - mu * SgSb[c]) + SgSb[4 + c] + w1_b[c]);
    float mu2 = 0.25f * (t[0] + t[1] + t[2] + t[3]);
    float var2 = 0.25f * ((t[0] - mu2) * (t[0] - mu2) + (t[1] - mu2) * (t[1] - mu2) +
                          (t[2] - mu2) * (t[2] - mu2) + (t[3] - mu2) * (t[3] - mu2));
    float r2 = rsqrtf(var2 + LN_EPS);
    float z = w2_b[0];
#pragma unroll
    for (int c = 0; c < 4; c++)
        z += ((t[c] - mu2) * r2 * ln2_g[c] + ln2_b[c]) * w2_w[c];
    w_csr[slot[e]] = 1.f / (1.f + expf(-z));
}

// CSR SpMM over fp16 m, unrolled x8 for memory-level parallelism.
__global__ __launch_bounds__(256)
void agg_kernel(const _Float16* __restrict__ m, const int* __restrict__ csr_src,
                const float* __restrict__ w_csr, const int* __restrict__ row_start,
                _Float16* __restrict__ agg) {
    int n = blockIdx.x * 4 + (threadIdx.x >> 6);
    if (n >= N_NODES) return;
    int lane = threadIdx.x & 63;
    int beg = row_start[n], end = row_start[n + 1];
    float a0 = 0.f, a1 = 0.f, a2 = 0.f, a3 = 0.f;
    int j = beg;
    for (; j + 8 <= end; j += 8) {
        int si[8];
        float wi[8];
#pragma unroll
        for (int u = 0; u < 8; u++) { si[u] = csr_src[j + u]; wi[u] = w_csr[j + u]; }
        f16x4 v[8];
#pragma unroll
        for (int u = 0; u < 8; u++) v[u] = *(const f16x4*)&m[(size_t)si[u] * CDIM + lane * 4];
#pragma unroll
        for (int u = 0; u < 8; u++) {
            a0 = fmaf(wi[u], (float)v[u][0], a0);
            a1 = fmaf(wi[u], (float)v[u][1], a1);
            a2 = fmaf(wi[u], (float)v[u][2], a2);
            a3 = fmaf(wi[u], (float)v[u][3], a3);
        }
    }
    for (; j < end; j++) {
        int s = csr_src[j];
        float w = w_csr[j];
        f16x4 v = *(const f16x4*)&m[(size_t)s * CDIM + lane * 4];
        a0 = fmaf(w, (float)v[0], a0);
        a1 = fmaf(w, (float)v[1], a1);
        a2 = fmaf(w, (float)v[2], a2);
        a3 = fmaf(w, (float)v[3], a3);
    }
    f16x4 o;
    o[0] = (_Float16)a0; o[1] = (_Float16)a1; o[2] = (_Float16)a2; o[3] = (_Float16)a3;
    *(f16x4*)&agg[(size_t)n * CDIM + lane * 4] = o;
}

__global__ __launch_bounds__(256)
void node_dot_kernel(const _Float16* __restrict__ h, const float* __restrict__ head_w,
                     float* __restrict__ sdot) {
    int n = blockIdx.x * 4 + (threadIdx.x >> 6);
    if (n >= N_NODES) return;
    int lane = threadIdx.x & 63;
    f16x4 v = *(const f16x4*)&h[(size_t)n * CDIM + lane * 4];
    float4 w = *(const float4*)&head_w[lane * 4];
    float p = (float)v[0] * w.x + (float)v[1] * w.y + (float)v[2] * w.z + (float)v[3] * w.w;
#pragma unroll
    for (int off = 1; off < 64; off <<= 1) p += __shfl_xor(p, off, 64);
    if (lane == 0) sdot[n] = p;
}

__global__ __launch_bounds__(256)
void final_head_kernel(const float* __restrict__ sdot, const int* __restrict__ gstart,
                       const float* __restrict__ head_b, float* __restrict__ out) {
    int g = blockIdx.x;
    int t = threadIdx.x;
    int beg = gstart[g], end = gstart[g + 1];
    float s = 0.f;
    for (int i = beg + t; i < end; i += 256) s += sdot[i];
    __shared__ float red[256];
    red[t] = s;
    __syncthreads();
    for (int k = 128; k > 0; k >>= 1) {
        if (t < k) red[t] += red[t + k];
        __syncthreads();
    }
    if (t == 0) out[g] = red[0] / fmaxf((float)(end - beg), 1.f) + head_b[0];
}

extern "C" void kernel_launch(void* const* d_in, const int* in_sizes, int n_in,
                              void* d_out, int out_size, void* d_ws, size_t ws_size,
                              hipStream_t stream) {
    const float* x       = (const float*)d_in[0];
    const float* x_pos   = (const float*)d_in[1];
    const int*   ei      = (const int*)d_in[2];
    const int*   batch   = (const int*)d_in[3];
    const float* dense_w = (const float*)d_in[4];
    const float* dense_b = (const float*)d_in[5];
    const float* d1_w    = (const float*)d_in[6];
    const float* d1_b    = (const float*)d_in[7];
    const float* ln1_g   = (const float*)d_in[8];
    const float* ln1_b   = (const float*)d_in[9];
    const float* w1_w    = (const float*)d_in[10];
    const float* w1_b    = (const float*)d_in[11];
    const float* ln2_g   = (const float*)d_in[12];
    const float* ln2_b   = (const float*)d_in[13];
    const float* w2_w    = (const float*)d_in[14];
    const float* w2_b    = (const float*)d_in[15];
    const float* d2_w    = (const float*)d_in[16];
    const float* d2_b    = (const float*)d_in[17];
    const float* head_w  = (const float*)d_in[18];
    const float* head_b  = (const float*)d_in[19];
    float* out = (float*)d_out;

    _Float16* hbuf0 = (_Float16*)d_ws;                          // [N][256] fp16
    _Float16* hbuf1 = hbuf0 + (size_t)N_NODES * CDIM;           // [N][256] fp16
    _Float16* xh    = hbuf1 + (size_t)N_NODES * CDIM;           // [N][768] fp16
    _Float16* wt_dense = xh + (size_t)N_NODES * KPAD_DENSE;     // [256][768] fp16
    _Float16* wt_sq    = wt_dense + (size_t)256 * KPAD_DENSE;   // [8][256][256] fp16
    float* cw    = (float*)(wt_sq + (size_t)8 * 256 * 256);     // [L][518][4]
    float* SgSb  = cw + (size_t)NLAYERS * ED_DIM * 4;           // [L][8]
    float* ns    = SgSb + NLAYERS * 8;                          // [N][12]
    float* sdot  = ns + (size_t)N_NODES * 12;                   // [N]
    float* w_csr = sdot + N_NODES;                              // [E]
    int* gstart    = (int*)(w_csr + N_EDGES);                   // [33]
    int* deg       = gstart + N_GRAPHS + 1;                     // [N]
    int* row_start = deg + N_NODES;                             // [N+1]
    int* cursor    = row_start + N_NODES + 1;                   // [N]
    int* csr_src   = cursor + N_NODES;                          // [E]
    int* slot      = csr_src + N_EDGES;                         // [E]
    int* bsum      = slot + N_EDGES;                            // [SCAN_BLOCKS]
    int* boff      = bsum + SCAN_BLOCKS;                        // [SCAN_BLOCKS]

    // one merged setup dispatch (zero deg + precompute + weight preps + convert_x)
    prep_all<<<2835, 256, 0, stream>>>(ln1_g, ln1_b, w1_w, cw, SgSb,
                                       x, xh, dense_w, wt_dense, d1_w, d2_w, wt_sq, deg);

    hist_gstart_kernel<<<(N_EDGES + 255) / 256, 256, 0, stream>>>(ei, batch, deg, gstart);
    scan1_kernel<<<SCAN_BLOCKS, 256, 0, stream>>>(deg, bsum);
    scan2_kernel<<<1, 128, 0, stream>>>(bsum, boff);
    scan3_kernel<<<SCAN_BLOCKS, 256, 0, stream>>>(deg, boff, row_start, cursor);
    scatter_kernel<<<(N_EDGES + 255) / 256, 256, 0, stream>>>(ei, cursor, csr_src, slot);

    const dim3 GGRID(N_NODES / 32, 2);  // (625, 2) = 1250 blocks
    gemm_mfma<false><<<GGRID, 256, 0, stream>>>(xh, wt_dense, dense_b, hbuf0, KPAD_DENSE);

    _Float16* h = hbuf0;
    _Float16* other = hbuf1;
    for (int l = 0; l < NLAYERS; l++) {
        gemm_mfma<true><<<GGRID, 256, 0, stream>>>(
            h, wt_sq + (size_t)l * 65536, d1_b + l * CDIM, other, CDIM);
        node_summary_kernel<<<(N_NODES + 3) / 4, 256, 0, stream>>>(
            other, cw + (size_t)l * ED_DIM * 4, ns);
        edge_weight_kernel<<<(N_EDGES + 255) / 256, 256, 0, stream>>>(
            ns, x_pos, ei, cw + (size_t)l * ED_DIM * 4, SgSb + l * 8, w1_b + l * 4,
            ln2_g + l * 4, ln2_b + l * 4, w2_w + l * 4, w2_b + l, slot, w_csr);
        agg_kernel<<<(N_NODES + 3) / 4, 256, 0, stream>>>(other, csr_src, w_csr, row_start, h);
        gemm_mfma<true><<<GGRID, 256, 0, stream>>>(
            h, wt_sq + (size_t)(4 + l) * 65536, d2_b + l * CDIM, other, CDIM);
        _Float16* tmp = h; h = other; other = tmp;
    }

    node_dot_kernel<<<(N_NODES + 3) / 4, 256, 0, stream>>>(h, head_w, sdot);
    final_head_kernel<<<N_GRAPHS, 256, 0, stream>>>(sdot, gstart, head_b, out);
}

// Round 12
// 529.302 us; speedup vs baseline: 10.3664x; 1.0175x over previous
//
#include <hip/hip_runtime.h>
#include <math.h>

#define N_NODES 20000
#define N_EDGES 320000
#define N_GRAPHS 32
#define CDIM 256
#define IN_DIMV 739
#define KPAD_DENSE 768
#define ED_DIM 518
#define NLAYERS 4
#define LN_EPS 1e-5f
#define SCAN_BLOCKS ((N_NODES + 255) / 256)  // 79

typedef _Float16 f16x8 __attribute__((ext_vector_type(8)));
typedef _Float16 f16x4 __attribute__((ext_vector_type(4)));
typedef float f32x4 __attribute__((ext_vector_type(4)));

__device__ __forceinline__ float gelu_exact(float x) {
    return 0.5f * x * (1.f + erff(x * 0.7071067811865475f));
}

// ---- merged setup: zero deg | precompute cw/SgSb | prep dense W | prep sq W | zero sdot ----
// block ranges: [0,79) zero deg; [79,83) precompute l=b-79; [83,275) dense W;
// [275,787) square W; [787,866) zero sdot.
__global__ __launch_bounds__(256)
void prep_all(const float* __restrict__ ln1_g, const float* __restrict__ ln1_b,
              const float* __restrict__ w1_w, float* __restrict__ cw,
              float* __restrict__ SgSb,
              const float* __restrict__ dense_w, _Float16* __restrict__ wt_dense,
              const float* __restrict__ d1_w, const float* __restrict__ d2_w,
              _Float16* __restrict__ wt_sq, int* __restrict__ deg,
              float* __restrict__ sdot) {
    __shared__ float smem[2048 + 64];
    int b = blockIdx.x, tid = threadIdx.x;
    if (b < 79) {
        int i = b * 256 + tid;
        if (i < N_NODES) deg[i] = 0;
    } else if (b < 83) {
        int l = b - 79;
        float sg[4] = {0, 0, 0, 0}, sb[4] = {0, 0, 0, 0};
        for (int i = tid; i < ED_DIM; i += 256) {
            float g = ln1_g[l * ED_DIM + i];
            float bb = ln1_b[l * ED_DIM + i];
            float4 w = *(const float4*)&w1_w[(size_t)(l * ED_DIM + i) * 4];
            float4 c = make_float4(g * w.x, g * w.y, g * w.z, g * w.w);
            *(float4*)&cw[(size_t)(l * ED_DIM + i) * 4] = c;
            sg[0] += c.x; sg[1] += c.y; sg[2] += c.z; sg[3] += c.w;
            sb[0] += bb * w.x; sb[1] += bb * w.y; sb[2] += bb * w.z; sb[3] += bb * w.w;
        }
        for (int c = 0; c < 4; c++) { smem[tid * 8 + c] = sg[c]; smem[tid * 8 + 4 + c] = sb[c]; }
        __syncthreads();
        for (int s = 128; s > 0; s >>= 1) {
            if (tid < s)
                for (int c = 0; c < 8; c++) smem[tid * 8 + c] += smem[(tid + s) * 8 + c];
            __syncthreads();
        }
        if (tid < 8) SgSb[l * 8 + tid] = smem[tid];
    } else if (b < 275) {
        int q = b - 83;
        int kt = q >> 3, nt = q & 7;
        int i = tid >> 5, j = tid & 31;
        float* T = smem;  // [32][33]
#pragma unroll
        for (int ii = 0; ii < 4; ii++) {
            int k = kt * 32 + i + ii * 8;
            T[(i + ii * 8) * 33 + j] = (k < IN_DIMV) ? dense_w[(size_t)k * 256 + nt * 32 + j] : 0.f;
        }
        __syncthreads();
#pragma unroll
        for (int ii = 0; ii < 4; ii++) {
            int n = nt * 32 + i + ii * 8;
            wt_dense[(size_t)n * KPAD_DENSE + kt * 32 + j] = (_Float16)T[j * 33 + i + ii * 8];
        }
    } else if (b < 787) {
        int q = b - 275;
        int z = q >> 6, kt = (q >> 3) & 7, nt = q & 7;
        const float* W = (z < 4) ? d1_w + (size_t)z * 65536 : d2_w + (size_t)(z - 4) * 65536;
        _Float16* O = wt_sq + (size_t)z * 65536;
        int i = tid >> 5, j = tid & 31;
        float* T = smem;
#pragma unroll
        for (int ii = 0; ii < 4; ii++)
            T[(i + ii * 8) * 33 + j] = W[(size_t)(kt * 32 + i + ii * 8) * 256 + nt * 32 + j];
        __syncthreads();
#pragma unroll
        for (int ii = 0; ii < 4; ii++)
            O[(size_t)(nt * 32 + i + ii * 8) * 256 + kt * 32 + j] = (_Float16)T[j * 33 + i + ii * 8];
    } else {
        int i = (b - 787) * 256 + tid;
        if (i < N_NODES) sdot[i] = 0.f;
    }
}

// ---- CSR build ----
__global__ void hist_gstart_kernel(const int* __restrict__ ei, const int* __restrict__ batch,
                                   int* __restrict__ deg, int* __restrict__ gstart) {
    int e = blockIdx.x * 256 + threadIdx.x;
    if (e < N_EDGES) atomicAdd(&deg[ei[N_EDGES + e]], 1);
    if (e < N_NODES) {
        int b = batch[e];
        int bprev = (e == 0) ? -1 : batch[e - 1];
        for (int g = bprev + 1; g <= b; g++) gstart[g] = e;
        if (e == N_NODES - 1)
            for (int g = b + 1; g <= N_GRAPHS; g++) gstart[g] = N_NODES;
    }
}

__global__ __launch_bounds__(256)
void scan1_kernel(const int* __restrict__ deg, int* __restrict__ bsum) {
    __shared__ int red[256];
    int t = threadIdx.x;
    int i = blockIdx.x * 256 + t;
    red[t] = (i < N_NODES) ? deg[i] : 0;
    __syncthreads();
    for (int s = 128; s > 0; s >>= 1) {
        if (t < s) red[t] += red[t + s];
        __syncthreads();
    }
    if (t == 0) bsum[blockIdx.x] = red[0];
}

__global__ __launch_bounds__(128)
void scan2_kernel(const int* __restrict__ bsum, int* __restrict__ boff) {
    __shared__ int s[128];
    int t = threadIdx.x;
    int v = (t < SCAN_BLOCKS) ? bsum[t] : 0;
    s[t] = v;
    __syncthreads();
    for (int off = 1; off < 128; off <<= 1) {
        int o = (t >= off) ? s[t - off] : 0;
        __syncthreads();
        s[t] += o;
        __syncthreads();
    }
    if (t < SCAN_BLOCKS) boff[t] = s[t] - v;  // exclusive
}

__global__ __launch_bounds__(256)
void scan3_kernel(const int* __restrict__ deg, const int* __restrict__ boff,
                  int* __restrict__ row_start, int* __restrict__ cursor) {
    __shared__ int s[256];
    int t = threadIdx.x;
    int i = blockIdx.x * 256 + t;
    int v = (i < N_NODES) ? deg[i] : 0;
    s[t] = v;
    __syncthreads();
    for (int off = 1; off < 256; off <<= 1) {
        int o = (t >= off) ? s[t - off] : 0;
        __syncthreads();
        s[t] += o;
        __syncthreads();
    }
    int base = boff[blockIdx.x];
    int excl = base + s[t] - v;
    if (i < N_NODES) {
        row_start[i] = excl;
        cursor[i] = excl;
    }
    if (i == N_NODES - 1) row_start[N_NODES] = base + s[t];
}

__global__ void scatter_kernel(const int* __restrict__ ei, int* __restrict__ cursor,
                               int* __restrict__ csr_src, int* __restrict__ slot) {
    int e = blockIdx.x * 256 + threadIdx.x;
    if (e < N_EDGES) {
        int d = ei[N_EDGES + e];
        int pos = atomicAdd(&cursor[d], 1);
        csr_src[pos] = ei[e];
        slot[e] = pos;
    }
}

// Dense GEMM: C[M,256] = A[M,739]fp32 @ Wt^T + bias, A converted fp16 during staging.
// Tile BM=32, BN=128, BK=64; grid (625, 2).
__global__ __launch_bounds__(256)
void gemm_dense(const float* __restrict__ A, const _Float16* __restrict__ Bt,
                const float* __restrict__ bias, _Float16* __restrict__ C) {
    __shared__ __align__(16) _Float16 As[32 * 72];
    __shared__ __align__(16) _Float16 Bs[128 * 72];
    int tid = threadIdx.x;
    int row0 = blockIdx.x * 32;
    int col0 = blockIdx.y * 128;
    int wave = tid >> 6, lane = tid & 63;
    int quad = lane >> 4, lrow = lane & 15;
    int wrow = wave >> 1, wcol = wave & 1;

    int ar = tid >> 3, ak8 = (tid & 7) * 8;
    int br = tid >> 1, bh = (tid & 1) * 32;

    const float* Arow = &A[(size_t)(row0 + ar) * IN_DIMV];
    const _Float16* Brow = &Bt[(size_t)(col0 + br) * KPAD_DENSE];

    const int ntiles = KPAD_DENSE >> 6;  // 12
    float a_f[8];
#pragma unroll
    for (int j = 0; j < 8; j++) {
        int gk = ak8 + j;
        a_f[j] = (gk < IN_DIMV) ? Arow[gk] : 0.f;
    }
    uint4 b_raw0 = *(const uint4*)&Brow[bh];
    uint4 b_raw1 = *(const uint4*)&Brow[bh + 8];
    uint4 b_raw2 = *(const uint4*)&Brow[bh + 16];
    uint4 b_raw3 = *(const uint4*)&Brow[bh + 24];

    f32x4 acc[4];
#pragma unroll
    for (int t = 0; t < 4; t++) acc[t] = (f32x4){0.f, 0.f, 0.f, 0.f};

    for (int kt = 0; kt < ntiles; ++kt) {
        f16x8 ah;
#pragma unroll
        for (int j = 0; j < 8; j++) ah[j] = (_Float16)a_f[j];
        *(f16x8*)&As[ar * 72 + ak8] = ah;
        *(uint4*)&Bs[br * 72 + bh] = b_raw0;
        *(uint4*)&Bs[br * 72 + bh + 8] = b_raw1;
        *(uint4*)&Bs[br * 72 + bh + 16] = b_raw2;
        *(uint4*)&Bs[br * 72 + bh + 24] = b_raw3;
        __syncthreads();

        if (kt + 1 < ntiles) {
            int k0 = (kt + 1) << 6;
#pragma unroll
            for (int j = 0; j < 8; j++) {
                int gk = k0 + ak8 + j;
                a_f[j] = (gk < IN_DIMV) ? Arow[gk] : 0.f;
            }
            b_raw0 = *(const uint4*)&Brow[k0 + bh];
            b_raw1 = *(const uint4*)&Brow[k0 + bh + 8];
            b_raw2 = *(const uint4*)&Brow[k0 + bh + 16];
            b_raw3 = *(const uint4*)&Brow[k0 + bh + 24];
        }

#pragma unroll
        for (int h = 0; h < 2; h++) {
            f16x8 af = *(const f16x8*)&As[(wrow * 16 + lrow) * 72 + h * 32 + quad * 8];
#pragma unroll
            for (int t = 0; t < 4; t++) {
                f16x8 bf = *(const f16x8*)&Bs[((wcol * 4 + t) * 16 + lrow) * 72 + h * 32 + quad * 8];
                acc[t] = __builtin_amdgcn_mfma_f32_16x16x32_f16(af, bf, acc[t], 0, 0, 0);
            }
        }
        __syncthreads();
    }

    int orow = row0 + wrow * 16 + quad * 4;
#pragma unroll
    for (int t = 0; t < 4; t++) {
        int col = col0 + (wcol * 4 + t) * 16 + lrow;
        float bv = bias[col];
#pragma unroll
        for (int r = 0; r < 4; r++)
            C[(size_t)(orow + r) * 256 + col] = (_Float16)(acc[t][r] + bv);
    }
}

// Square GEMM: C[M,256] = act(A fp16 @ W + bias). DOT: skip C-write, accumulate
// sdot[row] += gelu(v)·head_w[col] via quad-shuffle reduce + atomicAdd.
template <bool GELU, bool DOT>
__global__ __launch_bounds__(256)
void gemm_mfma(const _Float16* __restrict__ A, const _Float16* __restrict__ Bt,
               const float* __restrict__ bias, _Float16* __restrict__ C,
               const float* __restrict__ head_w, float* __restrict__ sdot) {
    __shared__ __align__(16) _Float16 As[32 * 72];
    __shared__ __align__(16) _Float16 Bs[128 * 72];
    int tid = threadIdx.x;
    int row0 = blockIdx.x * 32;
    int col0 = blockIdx.y * 128;
    int wave = tid >> 6, lane = tid & 63;
    int quad = lane >> 4, lrow = lane & 15;
    int wrow = wave >> 1, wcol = wave & 1;

    int ar = tid >> 3, ak8 = (tid & 7) * 8;
    int br = tid >> 1, bh = (tid & 1) * 32;

    const _Float16* Arow = &A[(size_t)(row0 + ar) * CDIM];
    const _Float16* Brow = &Bt[(size_t)(col0 + br) * CDIM];

    const int ntiles = CDIM >> 6;  // 4
    uint4 a_raw = *(const uint4*)&Arow[ak8];
    uint4 b_raw0 = *(const uint4*)&Brow[bh];
    uint4 b_raw1 = *(const uint4*)&Brow[bh + 8];
    uint4 b_raw2 = *(const uint4*)&Brow[bh + 16];
    uint4 b_raw3 = *(const uint4*)&Brow[bh + 24];

    f32x4 acc[4];
#pragma unroll
    for (int t = 0; t < 4; t++) acc[t] = (f32x4){0.f, 0.f, 0.f, 0.f};

    for (int kt = 0; kt < ntiles; ++kt) {
        *(uint4*)&As[ar * 72 + ak8] = a_raw;
        *(uint4*)&Bs[br * 72 + bh] = b_raw0;
        *(uint4*)&Bs[br * 72 + bh + 8] = b_raw1;
        *(uint4*)&Bs[br * 72 + bh + 16] = b_raw2;
        *(uint4*)&Bs[br * 72 + bh + 24] = b_raw3;
        __syncthreads();

        if (kt + 1 < ntiles) {
            int k0 = (kt + 1) << 6;
            a_raw = *(const uint4*)&Arow[k0 + ak8];
            b_raw0 = *(const uint4*)&Brow[k0 + bh];
            b_raw1 = *(const uint4*)&Brow[k0 + bh + 8];
            b_raw2 = *(const uint4*)&Brow[k0 + bh + 16];
            b_raw3 = *(const uint4*)&Brow[k0 + bh + 24];
        }

#pragma unroll
        for (int h = 0; h < 2; h++) {
            f16x8 af = *(const f16x8*)&As[(wrow * 16 + lrow) * 72 + h * 32 + quad * 8];
#pragma unroll
            for (int t = 0; t < 4; t++) {
                f16x8 bf = *(const f16x8*)&Bs[((wcol * 4 + t) * 16 + lrow) * 72 + h * 32 + quad * 8];
                acc[t] = __builtin_amdgcn_mfma_f32_16x16x32_f16(af, bf, acc[t], 0, 0, 0);
            }
        }
        __syncthreads();
    }

    int orow = row0 + wrow * 16 + quad * 4;
    if (DOT) {
        float dp[4] = {0.f, 0.f, 0.f, 0.f};
#pragma unroll
        for (int t = 0; t < 4; t++) {
            int col = col0 + (wcol * 4 + t) * 16 + lrow;
            float hw = head_w[col];
            float bv = bias[col];
#pragma unroll
            for (int r = 0; r < 4; r++)
                dp[r] += gelu_exact(acc[t][r] + bv) * hw;
        }
#pragma unroll
        for (int r = 0; r < 4; r++) {
#pragma unroll
            for (int off = 1; off < 16; off <<= 1)
                dp[r] += __shfl_xor(dp[r], off, 64);
        }
        if (lrow == 0) {
#pragma unroll
            for (int r = 0; r < 4; r++) atomicAdd(&sdot[orow + r], dp[r]);
        }
    } else {
#pragma unroll
        for (int t = 0; t < 4; t++) {
            int col = col0 + (wcol * 4 + t) * 16 + lrow;
            float bv = bias[col];
#pragma unroll
            for (int r = 0; r < 4; r++) {
                float v = acc[t][r] + bv;
                C[(size_t)(orow + r) * 256 + col] = (_Float16)(GELU ? gelu_exact(v) : v);
            }
        }
    }
}

// Per-node summaries from fp16 m: P1, P2, Q1, Q2 (12 floats/node)
__global__ __launch_bounds__(256)
void node_summary_kernel(const _Float16* __restrict__ m, const float* __restrict__ cw,
                         float* __restrict__ ns) {
    __shared__ __align__(16) float4 s_cw[512];
    int tid = threadIdx.x;
    for (int i = tid; i < 512; i += 256) s_cw[i] = *(const float4*)&cw[(size_t)i * 4];
    __syncthreads();
    int n = blockIdx.x * 4 + (tid >> 6);
    if (n >= N_NODES) return;
    int lane = tid & 63;
    f16x4 a4 = *(const f16x4*)&m[(size_t)n * CDIM + lane * 4];
    float av[4] = {(float)a4[0], (float)a4[1], (float)a4[2], (float)a4[3]};
    float Q1 = 0.f, Q2 = 0.f, P1[4] = {0, 0, 0, 0}, P2[4] = {0, 0, 0, 0};
#pragma unroll
    for (int j = 0; j < 4; j++) {
        Q1 += av[j];
        Q2 += av[j] * av[j];
        float4 c0 = s_cw[lane * 4 + j];
        float4 c1 = s_cw[256 + lane * 4 + j];
        P1[0] += av[j] * c0.x; P1[1] += av[j] * c0.y; P1[2] += av[j] * c0.z; P1[3] += av[j] * c0.w;
        P2[0] += av[j] * c1.x; P2[1] += av[j] * c1.y; P2[2] += av[j] * c1.z; P2[3] += av[j] * c1.w;
    }
#pragma unroll
    for (int off = 1; off < 64; off <<= 1) {
        Q1 += __shfl_xor(Q1, off, 64);
        Q2 += __shfl_xor(Q2, off, 64);
        P1[0] += __shfl_xor(P1[0], off, 64);
        P1[1] += __shfl_xor(P1[1], off, 64);
        P1[2] += __shfl_xor(P1[2], off, 64);
        P1[3] += __shfl_xor(P1[3], off, 64);
        P2[0] += __shfl_xor(P2[0], off, 64);
        P2[1] += __shfl_xor(P2[1], off, 64);
        P2[2] += __shfl_xor(P2[2], off, 64);
        P2[3] += __shfl_xor(P2[3], off, 64);
    }
    if (lane == 0) {
        float* p = &ns[(size_t)n * 12];
        *(float4*)p = make_float4(P1[0], P1[1], P1[2], P1[3]);
        *(float4*)(p + 4) = make_float4(P2[0], P2[1], P2[2], P2[3]);
        p[8] = Q1;
        p[9] = Q2;
    }
}

// One thread per edge: edge MLP from node summaries; writes w into CSR slot.
__global__ __launch_bounds__(256)
void edge_weight_kernel(const float* __restrict__ ns, const float* __restrict__ x_pos,
                        const int* __restrict__ ei, const float* __restrict__ cw,
                        const float* __restrict__ SgSb, const float* __restrict__ w1_b,
                        const float* __restrict__ ln2_g, const float* __restrict__ ln2_b,
                        const float* __restrict__ w2_w, const float* __restrict__ w2_b,
                        const int* __restrict__ slot, float* __restrict__ w_csr) {
    int e = blockIdx.x * 256 + threadIdx.x;
    if (e >= N_EDGES) return;
    int s = ei[e], d = ei[N_EDGES + e];
    const float* nss = &ns[(size_t)s * 12];
    const float* nsd = &ns[(size_t)d * 12];
    float4 p1 = *(const float4*)nss;
    float4 p2 = *(const float4*)(nsd + 4);
    float S1 = nss[8] + nsd[8];
    float S2 = nss[9] + nsd[9];
    float D[4] = {p1.x + p2.x, p1.y + p2.y, p1.z + p2.z, p1.w + p2.w};
    float ps[6];
    ps[0] = x_pos[(size_t)s * 3 + 0];
    ps[1] = x_pos[(size_t)s * 3 + 1];
    ps[2] = x_pos[(size_t)s * 3 + 2];
    ps[3] = x_pos[(size_t)d * 3 + 0];
    ps[4] = x_pos[(size_t)d * 3 + 1];
    ps[5] = x_pos[(size_t)d * 3 + 2];
#pragma unroll
    for (int k = 0; k < 6; k++) {
        S1 += ps[k];
        S2 += ps[k] * ps[k];
        float4 c = *(const float4*)&cw[(size_t)(512 + k) * 4];
        D[0] += ps[k] * c.x; D[1] += ps[k] * c.y; D[2] += ps[k] * c.z; D[3] += ps[k] * c.w;
    }
    const float inv = 1.f / 518.f;
    float mu = S1 * inv;
    float var = fmaf(-mu, mu, S2 * inv);
    float rstd = rsqrtf(var + LN_EPS);
    float t[4];
#pragma unroll
    for (int c = 0; c < 4; c++)
        t[c] = gelu_exact(rstd * (D[c] - mu * SgSb[c]) + SgSb[4 + c] + w1_b[c]);
    float mu2 = 0.25f * (t[0] + t[1] + t[2] + t[3]);
    float var2 = 0.25f * ((t[0] - mu2) * (t[0] - mu2) + (t[1] - mu2) * (t[1] - mu2) +
                          (t[2] - mu2) * (t[2] - mu2) + (t[3] - mu2) * (t[3] - mu2));
    float r2 = rsqrtf(var2 + LN_EPS);
    float z = w2_b[0];
#pragma unroll
    for (int c = 0; c < 4; c++)
        z += ((t[c] - mu2) * r2 * ln2_g[c] + ln2_b[c]) * w2_w[c];
    w_csr[slot[e]] = 1.f / (1.f + expf(-z));
}

// CSR SpMM over fp16 m, unrolled x8 for memory-level parallelism.
__global__ __launch_bounds__(256)
void agg_kernel(const _Float16* __restrict__ m, const int* __restrict__ csr_src,
                const float* __restrict__ w_csr, const int* __restrict__ row_start,
                _Float16* __restrict__ agg) {
    int n = blockIdx.x * 4 + (threadIdx.x >> 6);
    if (n >= N_NODES) return;
    int lane = threadIdx.x & 63;
    int beg = row_start[n], end = row_start[n + 1];
    float a0 = 0.f, a1 = 0.f, a2 = 0.f, a3 = 0.f;
    int j = beg;
    for (; j + 8 <= end; j += 8) {
        int si[8];
        float wi[8];
#pragma unroll
        for (int u = 0; u < 8; u++) { si[u] = csr_src[j + u]; wi[u] = w_csr[j + u]; }
        f16x4 v[8];
#pragma unroll
        for (int u = 0; u < 8; u++) v[u] = *(const f16x4*)&m[(size_t)si[u] * CDIM + lane * 4];
#pragma unroll
        for (int u = 0; u < 8; u++) {
            a0 = fmaf(wi[u], (float)v[u][0], a0);
            a1 = fmaf(wi[u], (float)v[u][1], a1);
            a2 = fmaf(wi[u], (float)v[u][2], a2);
            a3 = fmaf(wi[u], (float)v[u][3], a3);
        }
    }
    for (; j < end; j++) {
        int s = csr_src[j];
        float w = w_csr[j];
        f16x4 v = *(const f16x4*)&m[(size_t)s * CDIM + lane * 4];
        a0 = fmaf(w, (float)v[0], a0);
        a1 = fmaf(w, (float)v[1], a1);
        a2 = fmaf(w, (float)v[2], a2);
        a3 = fmaf(w, (float)v[3], a3);
    }
    f16x4 o;
    o[0] = (_Float16)a0; o[1] = (_Float16)a1; o[2] = (_Float16)a2; o[3] = (_Float16)a3;
    *(f16x4*)&agg[(size_t)n * CDIM + lane * 4] = o;
}

__global__ __launch_bounds__(256)
void final_head_kernel(const float* __restrict__ sdot, const int* __restrict__ gstart,
                       const float* __restrict__ head_b, float* __restrict__ out) {
    int g = blockIdx.x;
    int t = threadIdx.x;
    int beg = gstart[g], end = gstart[g + 1];
    float s = 0.f;
    for (int i = beg + t; i < end; i += 256) s += sdot[i];
    __shared__ float red[256];
    red[t] = s;
    __syncthreads();
    for (int k = 128; k > 0; k >>= 1) {
        if (t < k) red[t] += red[t + k];
        __syncthreads();
    }
    if (t == 0) out[g] = red[0] / fmaxf((float)(end - beg), 1.f) + head_b[0];
}

extern "C" void kernel_launch(void* const* d_in, const int* in_sizes, int n_in,
                              void* d_out, int out_size, void* d_ws, size_t ws_size,
                              hipStream_t stream) {
    const float* x       = (const float*)d_in[0];
    const float* x_pos   = (const float*)d_in[1];
    const int*   ei      = (const int*)d_in[2];
    const int*   batch   = (const int*)d_in[3];
    const float* dense_w = (const float*)d_in[4];
    const float* dense_b = (const float*)d_in[5];
    const float* d1_w    = (const float*)d_in[6];
    const float* d1_b    = (const float*)d_in[7];
    const float* ln1_g   = (const float*)d_in[8];
    const float* ln1_b   = (const float*)d_in[9];
    const float* w1_w    = (const float*)d_in[10];
    const float* w1_b    = (const float*)d_in[11];
    const float* ln2_g   = (const float*)d_in[12];
    const float* ln2_b   = (const float*)d_in[13];
    const float* w2_w    = (const float*)d_in[14];
    const float* w2_b    = (const float*)d_in[15];
    const float* d2_w    = (const float*)d_in[16];
    const float* d2_b    = (const float*)d_in[17];
    const float* head_w  = (const float*)d_in[18];
    const float* head_b  = (const float*)d_in[19];
    float* out = (float*)d_out;

    _Float16* hbuf0 = (_Float16*)d_ws;                          // [N][256] fp16
    _Float16* hbuf1 = hbuf0 + (size_t)N_NODES * CDIM;           // [N][256] fp16
    _Float16* wt_dense = hbuf1 + (size_t)N_NODES * CDIM;        // [256][768] fp16
    _Float16* wt_sq    = wt_dense + (size_t)256 * KPAD_DENSE;   // [8][256][256] fp16
    float* cw    = (float*)(wt_sq + (size_t)8 * 256 * 256);     // [L][518][4]
    float* SgSb  = cw + (size_t)NLAYERS * ED_DIM * 4;           // [L][8]
    float* ns    = SgSb + NLAYERS * 8;                          // [N][12]
    float* sdot  = ns + (size_t)N_NODES * 12;                   // [N]
    float* w_csr = sdot + N_NODES;                              // [E]
    int* gstart    = (int*)(w_csr + N_EDGES);                   // [33]
    int* deg       = gstart + N_GRAPHS + 1;                     // [N]
    int* row_start = deg + N_NODES;                             // [N+1]
    int* cursor    = row_start + N_NODES + 1;                   // [N]
    int* csr_src   = cursor + N_NODES;                          // [E]
    int* slot      = csr_src + N_EDGES;                         // [E]
    int* bsum      = slot + N_EDGES;                            // [SCAN_BLOCKS]
    int* boff      = bsum + SCAN_BLOCKS;                        // [SCAN_BLOCKS]

    prep_all<<<866, 256, 0, stream>>>(ln1_g, ln1_b, w1_w, cw, SgSb,
                                      dense_w, wt_dense, d1_w, d2_w, wt_sq, deg, sdot);

    hist_gstart_kernel<<<(N_EDGES + 255) / 256, 256, 0, stream>>>(ei, batch, deg, gstart);
    scan1_kernel<<<SCAN_BLOCKS, 256, 0, stream>>>(deg, bsum);
    scan2_kernel<<<1, 128, 0, stream>>>(bsum, boff);
    scan3_kernel<<<SCAN_BLOCKS, 256, 0, stream>>>(deg, boff, row_start, cursor);
    scatter_kernel<<<(N_EDGES + 255) / 256, 256, 0, stream>>>(ei, cursor, csr_src, slot);

    const dim3 GGRID(N_NODES / 32, 2);  // (625, 2) = 1250 blocks
    gemm_dense<<<GGRID, 256, 0, stream>>>(x, wt_dense, dense_b, hbuf0);

    _Float16* h = hbuf0;
    _Float16* other = hbuf1;
    for (int l = 0; l < NLAYERS; l++) {
        gemm_mfma<true, false><<<GGRID, 256, 0, stream>>>(
            h, wt_sq + (size_t)l * 65536, d1_b + l * CDIM, other, nullptr, nullptr);
        node_summary_kernel<<<(N_NODES + 3) / 4, 256, 0, stream>>>(
            other, cw + (size_t)l * ED_DIM * 4, ns);
        edge_weight_kernel<<<(N_EDGES + 255) / 256, 256, 0, stream>>>(
            ns, x_pos, ei, cw + (size_t)l * ED_DIM * 4, SgSb + l * 8, w1_b + l * 4,
            ln2_g + l * 4, ln2_b + l * 4, w2_w + l * 4, w2_b + l, slot, w_csr);
        agg_kernel<<<(N_NODES + 3) / 4, 256, 0, stream>>>(other, csr_src, w_csr, row_start, h);
        if (l < NLAYERS - 1) {
            gemm_mfma<true, false><<<GGRID, 256, 0, stream>>>(
                h, wt_sq + (size_t)(4 + l) * 65536, d2_b + l * CDIM, other, nullptr, nullptr);
        } else {
            // final layer: fuse node_dot into the epilogue, skip C-write
            gemm_mfma<true, true><<<GGRID, 256, 0, stream>>>(
                h, wt_sq + (size_t)(4 + l) * 65536, d2_b + l * CDIM, other, head_w, sdot);
        }
        _Float16* tmp = h; h = other; other = tmp;
    }

    final_head_kernel<<<N_GRAPHS, 256, 0, stream>>>(sdot, gstart, head_b, out);
}